// Round 3
// baseline (565.669 us; speedup 1.0000x reference)
//
#include <hip/hip_runtime.h>
#include <cstdint>
#include <cstddef>

// DiagonalLSTM B=32,C=64,H=64,W=64,h=64,4h=256,NW=127 — scan v7.
// v7 = v4 (known-pass, 554us) + ONE change: the two in-loop __syncthreads()
// replaced by barrier_lgkm (s_waitcnt lgkmcnt(0) + raw s_barrier, pinned with
// sched_barrier(0)). All cross-wave hazards in the loop are LDS-only; the
// vmcnt(0)/expcnt(0) drain of __syncthreads only waited on hh16 store-acks
// and i2s loads that no wave consumes across the barrier.
// Everything else (in-loop IV loads, post-MFMA i2s add, pack2/f2bf, pointer
// parity XOR toggles, launch bounds) is byte-identical to v4 as a bisect.

typedef unsigned int u32;
typedef unsigned short u16;
typedef __bf16 bf16x8 __attribute__((ext_vector_type(8)));
typedef float f32x4 __attribute__((ext_vector_type(4)));

#define NSTEP 127
#define MFMA(a, b, c) __builtin_amdgcn_mfma_f32_16x16x32_bf16(a, b, c, 0, 0, 0)
#define LOG2E 1.4426950408889634f
#define SCL (-1.4426950408889634f)
#define T2L 2.8853900817779268f
#define RHO(r) ((((r) ^ ((r) >> 3))) & 7)

static __device__ __forceinline__ u16 f2bf(float f) {
    u32 u = __builtin_bit_cast(u32, f);
    u32 r = u + 0x7FFFu + ((u >> 16) & 1u);
    return (u16)(r >> 16);
}
static __device__ __forceinline__ u32 pack2(float a, float b) {
    return (u32)f2bf(a) | ((u32)f2bf(b) << 16);
}
static __device__ __forceinline__ float lo2f(u32 u) {
    return __builtin_bit_cast(float, u << 16);
}
static __device__ __forceinline__ float hi2f(u32 u) {
    return __builtin_bit_cast(float, u & 0xFFFF0000u);
}
static __device__ __forceinline__ void barrier_lgkm() {
    // __syncthreads minus the vmcnt(0)/expcnt(0) drain: only LDS ops must be
    // visible across this barrier. sched_barrier(0) pins machine scheduling
    // (rule #18); asm memory clobbers pin IR-level movement.
    asm volatile("s_waitcnt lgkmcnt(0)" ::: "memory");
    __builtin_amdgcn_sched_barrier(0);
    __builtin_amdgcn_s_barrier();
    __builtin_amdgcn_sched_barrier(0);
    asm volatile("" ::: "memory");
}
static __device__ __forceinline__ float sigm2(float y) {  // y pre-scaled by -log2e
    return __builtin_amdgcn_rcpf(1.f + __builtin_amdgcn_exp2f(y));
}
static __device__ __forceinline__ float tanh_fast(float x) {
    float r = __builtin_amdgcn_rcpf(1.f + __builtin_amdgcn_exp2f(x * T2L));
    return __builtin_fmaf(-2.f, r, 1.f);
}

// ---------------- K0: weight repack ----------------
// Wg[o][128] = -log2e * [Ws0_row | Ws1_row]; Wc[o][128] = [Wc0 | Wc1] (unscaled)
// biasRow u16[256] (o''-layout) = bf(-log2e*(bi+bs)); w_upB u16[128*64] = bf(w_up)
__global__ __launch_bounds__(256) void repack_w(
    const float* __restrict__ w_s2s, const float* __restrict__ w_c2c,
    const float* __restrict__ bi, const float* __restrict__ bs,
    const float* __restrict__ w_up, float* __restrict__ Wg,
    float* __restrict__ Wc, u16* __restrict__ biasRow,
    u16* __restrict__ w_upB) {
    int idx = blockIdx.x * 256 + threadIdx.x;
    if (idx < 32768) {
        int o = idx >> 7, kk = idx & 127, half = kk >> 6, k = kk & 63;
        Wg[idx] = SCL * w_s2s[(o * 64 + k) * 2 + half];
        return;
    }
    int j = idx - 32768;
    if (j < 8192) {
        int o = j >> 7, kk = j & 127, half = kk >> 6, k = kk & 63;
        Wc[j] = w_c2c[(o * 64 + k) * 2 + half];
        return;
    }
    j -= 8192;
    if (j < 256) {
        int m15 = j >> 4, nq = (j >> 2) & 3, nb = j & 3;
        int o = 64 * nq + 16 * nb + m15;
        biasRow[j] = f2bf(SCL * (bi[o] + bs[o]));
        return;
    }
    j -= 256;
    if (j < 8192) w_upB[j] = f2bf(w_up[j]);
}

// ---------------- K1: i2s conv, scaled by -log2e, o''-permuted, bias-padded --
// slot (b,p,w): ((b*64+p)*66 + (w+1)) * 512 bytes; w=-1 and w=64 slots = biasRow
__global__ __launch_bounds__(256) void i2s_kernel(
    const float* __restrict__ in, const float* __restrict__ w_i2s,
    const float* __restrict__ bi, const float* __restrict__ bs,
    const u32* __restrict__ biasU32, u32* __restrict__ out_u32) {
    const int bid = blockIdx.x;
    const int b = bid >> 6, r = bid & 63;
    const int lane = threadIdx.x & 63;
    const int wv = threadIdx.x >> 6;
    const int wvu = __builtin_amdgcn_readfirstlane(wv);

    __shared__ __align__(16) u32 sT[64 * 129];  // u16 [w 64][o'' 256], stride 258

    float vIn[64];
    const float* inp = in + ((size_t)b * 262144) + r * 64 + lane;
#pragma unroll
    for (int c = 0; c < 64; c++) vIn[c] = inp[(size_t)c * 4096];

    for (int ob = 0; ob < 4; ob++) {
        float acc[16];
#pragma unroll
        for (int i = 0; i < 16; i++) {
            const int o = wvu * 64 + ob * 16 + i;
            float a = bi[o] + bs[o];
            const float* wr = w_i2s + o * 64;
#pragma unroll
            for (int c = 0; c < 64; c++) a += wr[c] * vIn[c];
            acc[i] = a;
        }
#pragma unroll
        for (int i = 0; i < 16; i++)
            ((u16*)sT)[lane * 258 + i * 16 + wvu * 4 + ob] = f2bf(SCL * acc[i]);
    }
    __syncthreads();
    const size_t base = ((size_t)(b * 64 + r) * 66 + 1) * 128;  // u32 units
#pragma unroll
    for (int loop = 0; loop < 32; loop++) {
        int idx = loop * 256 + threadIdx.x;
        int w = idx >> 7, cu = idx & 127;
        out_u32[base + idx] = sT[w * 129 + cu];
    }
    if (threadIdx.x < 128) {
        u32 v = biasU32[threadIdx.x];
        out_u32[base - 128 + threadIdx.x] = v;       // w = -1 slot
        out_u32[base + 8192 + threadIdx.x] = v;      // w = 64 slot
    }
}

// ---------------- K2: MFMA scan v7 ----------------
// 32 blocks x 512 threads (8 waves). wave wv: mh=wv>>2, nq=wv&3 => mt=2mh+mi.
// c2c: mtc=wv>>1, ktc0=(wv&1)*2.
// LDS sM bytes: [0,8192) H par0 rows0..63x128B; [8192,16384) H par1;
// [16384,32768) C par0/par1; ZH0@32768 ZC0@32896 ZH1@40960 ZC1@41088 (zeros).
// All H/C addrs XOR 8192 per step. Row chunks (16B) swizzled by RHO(row).
__global__ __launch_bounds__(512, 2) void scan_kernel(
    const u16* __restrict__ i2sP, const float* __restrict__ Wg,
    const float* __restrict__ Wc, const float* __restrict__ b_c2c,
    u16* __restrict__ hh16) {
    const int b = blockIdx.x;
    const int tid = threadIdx.x;
    const int lane = tid & 63;
    const int wv = __builtin_amdgcn_readfirstlane(tid >> 6);
    const int mh = wv >> 2, nq = wv & 3;
    const int mtc = wv >> 1, ktc0 = (wv & 1) * 2;
    const int m15 = lane & 15, g4 = lane >> 4;

    __shared__ __align__(16) u32 sM[10304];   // 41216 B
    __shared__ __align__(16) u32 sCCm[2048];  // 8192 B
    char* smB = (char*)sM;
    char* ccB = (char*)sCCm;

    for (int i = tid; i < 10304; i += 512) sM[i] = 0;

    // ---- VGPR-resident weights ----
    bf16x8 BW[4][4];
    float bcc[4];
#pragma unroll
    for (int nb = 0; nb < 4; nb++) {
        int o = 64 * nq + 16 * nb + m15;
        bcc[nb] = b_c2c[16 * nb + m15];
#pragma unroll
        for (int kt = 0; kt < 4; kt++) {
            const float* p = Wg + o * 128 + kt * 32 + g4 * 8;
            bf16x8 f;
#pragma unroll
            for (int j = 0; j < 8; j++) f[j] = (__bf16)p[j];
            BW[nb][kt] = f;
        }
    }
    bf16x8 BC[2][4];
#pragma unroll
    for (int i = 0; i < 2; i++) {
        int o2 = 16 * (ktc0 + i) + m15;
#pragma unroll
        for (int kt = 0; kt < 4; kt++) {
            const float* p = Wc + o2 * 128 + kt * 32 + g4 * 8;
            bf16x8 f;
#pragma unroll
            for (int j = 0; j < 8; j++) f[j] = (__bf16)p[j];
            BC[i][kt] = f;
        }
    }

    // ---- precomputed addresses ----
    int aG[2][4], aC[4], wOff[2][4], ccR[2][4], ccP[4], bOffB[2][4];
#pragma unroll
    for (int mi = 0; mi < 2; mi++) {
        int mt = 2 * mh + mi;
#pragma unroll
        for (int kt = 0; kt < 4; kt++) {
            int P = 16 * (m15 & 3) + 4 * mt + (m15 >> 2);
            int phys = P + (kt >> 1) - 1;
            int chunk = (kt & 1) * 4 + g4;
            aG[mi][kt] = (phys < 0) ? (32768 + chunk * 16)
                                    : (phys * 128 + ((chunk ^ RHO(phys)) * 16));
        }
        int p2 = 16 * mt + 4 * g4 + nq;
#pragma unroll
        for (int nb = 0; nb < 4; nb++) {
            int k = 16 * nb + m15;
            wOff[mi][nb] =
                8192 + p2 * 128 + (((k >> 3) ^ RHO(p2)) * 16) + (k & 7) * 2;
            int rp = p2 >> 1;
            ccR[mi][nb] = (rp * 64 + ((k + 8 * rp) & 63)) * 4;
            int prerow = 16 * nb + 4 * mt + g4;  // nb doubles as gate idx r here
            bOffB[mi][nb] = (prerow * 66 + 1) * 512 + 32 * m15 + 8 * nq;
        }
    }
#pragma unroll
    for (int kt = 0; kt < 4; kt++) {
        int crow = 16 * mtc + m15;
        int phys = crow + (kt >> 1) - 1;
        int chunk = (kt & 1) * 4 + g4;
        aC[kt] = (phys < 0) ? (32896 + chunk * 16)
                            : (16384 + phys * 128 + ((chunk ^ RHO(phys)) * 16));
    }
#pragma unroll
    for (int i = 0; i < 2; i++) {
        int k = 16 * (ktc0 + i) + m15;
        int rp0 = 8 * mtc + 2 * g4, rp1 = rp0 + 1;
        ccP[2 * i] = (rp0 * 64 + ((k + 8 * rp0) & 63)) * 4;
        ccP[2 * i + 1] = (rp1 * 64 + ((k + 8 * rp1) & 63)) * 4;
    }

    const char* i2sB = (const char*)i2sP + (size_t)b * (64 * 66 * 512);
    u16* hp16[2];
    int p2s[2];
#pragma unroll
    for (int mi = 0; mi < 2; mi++) {
        int p2 = 16 * (2 * mh + mi) + 4 * g4 + nq;
        p2s[mi] = p2;
        hp16[mi] = hh16 + (size_t)b * 262144 + p2 * 4032 + m15;
    }

    __syncthreads();

    for (int t = 0; t < NSTEP; t++) {
        // ---- i2s prefetch: one 8B load = 4 gate values (bias-padded) ----
        uint2 IV[2][4];
#pragma unroll
        for (int mi = 0; mi < 2; mi++) {
            int mt = 2 * mh + mi;
#pragma unroll
            for (int r = 0; r < 4; r++) {
                int prerow = 16 * r + 4 * mt + g4;
                int w = min(max(t - prerow, -1), 64);
                IV[mi][r] =
                    *(const uint2*)(i2sB + (bOffB[mi][r] + (w << 9)));
            }
        }

        // ---- gate MFMAs (permuted A rows) ----
        f32x4 accG[2][4] = {};
#pragma unroll
        for (int mi = 0; mi < 2; mi++) {
            bf16x8 Ag[4];
#pragma unroll
            for (int kt = 0; kt < 4; kt++)
                Ag[kt] = __builtin_bit_cast(bf16x8,
                                            *(const uint4*)(smB + aG[mi][kt]));
#pragma unroll
            for (int nb = 0; nb < 4; nb++)
#pragma unroll
                for (int kt = 0; kt < 4; kt++)
                    accG[mi][nb] = MFMA(Ag[kt], BW[nb][kt], accG[mi][nb]);
        }
        // ---- c2c MFMAs ----
        f32x4 accC[2] = {};
        {
            bf16x8 Ac[4];
#pragma unroll
            for (int kt = 0; kt < 4; kt++)
                Ac[kt] =
                    __builtin_bit_cast(bf16x8, *(const uint4*)(smB + aC[kt]));
#pragma unroll
            for (int i = 0; i < 2; i++)
#pragma unroll
                for (int kt = 0; kt < 4; kt++)
                    accC[i] = MFMA(Ac[kt], BC[i][kt], accC[i]);
        }

        // ---- add i2s (bias-padded: unconditional) ----
#pragma unroll
        for (int mi = 0; mi < 2; mi++)
#pragma unroll
            for (int r = 0; r < 4; r++) {
                u32 w0 = IV[mi][r].x, w1 = IV[mi][r].y;
                accG[mi][0][r] += lo2f(w0);
                accG[mi][1][r] += hi2f(w0);
                accG[mi][2][r] += lo2f(w1);
                accG[mi][3][r] += hi2f(w1);
            }

        // ---- publish c2c ----
#pragma unroll
        for (int i = 0; i < 2; i++) {
            *(u32*)(ccB + ccP[2 * i]) = pack2(accC[i][0], accC[i][1]);
            *(u32*)(ccB + ccP[2 * i + 1]) = pack2(accC[i][2], accC[i][3]);
        }
        barrier_lgkm();

        // ---- stage B: LSTM update ----
#pragma unroll
        for (int mi = 0; mi < 2; mi++) {
            int p2 = p2s[mi];
            bool vst = (u32)(t - p2) < 64u;
            u16* hp = hp16[mi];
#pragma unroll
            for (int nb = 0; nb < 4; nb++) {
                u32 cw = *(const u32*)(ccB + ccR[mi][nb]);
                float cc = ((nq & 1) ? hi2f(cw) : lo2f(cw)) + bcc[nb];
                float si = sigm2(accG[mi][nb][0]);
                float sg = sigm2(accG[mi][nb][1]);
                float sf = sigm2(accG[mi][nb][2]);
                float so = sigm2(accG[mi][nb][3]);
                float c1 = __builtin_fmaf(sf, cc, si * sg);
                float h1 = so * tanh_fast(c1);
                u16 hb = f2bf(h1);
                *(u16*)(smB + wOff[mi][nb]) = hb;
                *(u16*)(smB + wOff[mi][nb] + 16384) = f2bf(c1);
                if (vst) hp[nb * 16] = hb;
            }
            hp16[mi] += 64;
        }
        barrier_lgkm();

        // ---- toggle parity ----
#pragma unroll
        for (int mi = 0; mi < 2; mi++) {
#pragma unroll
            for (int kt = 0; kt < 4; kt++) aG[mi][kt] ^= 8192;
#pragma unroll
            for (int nb = 0; nb < 4; nb++) wOff[mi][nb] ^= 8192;
        }
#pragma unroll
        for (int kt = 0; kt < 4; kt++) aC[kt] ^= 8192;
    }
}

// ---------------- K3: up-projection via MFMA ----------------
// per (b,r) block, 256 thr = 4 waves, wave = w-tile. A=w_upB, B=hh bf16.
__global__ __launch_bounds__(256) void up_kernel(
    const u16* __restrict__ hh16, const u16* __restrict__ w_upB,
    const float* __restrict__ b_up, float* __restrict__ out) {
    const int bid = blockIdx.x;
    const int b = bid >> 6, r = bid & 63;
    const int lane = threadIdx.x & 63;
    const int wt = __builtin_amdgcn_readfirstlane(threadIdx.x >> 6);
    const int m15 = lane & 15, g4 = lane >> 4;

    const u16* hh_b = hh16 + (size_t)b * 262144;
    const int w = 16 * wt + m15;

    bf16x8 Bf[2];
#pragma unroll
    for (int kt = 0; kt < 2; kt++)
        Bf[kt] = __builtin_bit_cast(
            bf16x8,
            *(const uint4*)(hh_b + (r * 4096 + w * 64 + kt * 32 + g4 * 8)));

    f32x4 acc[8] = {};
#pragma unroll
    for (int nt = 0; nt < 8; nt++) {
#pragma unroll
        for (int kt = 0; kt < 2; kt++) {
            bf16x8 Af = __builtin_bit_cast(
                bf16x8, *(const uint4*)(w_upB + ((16 * nt + m15) * 64 +
                                                 kt * 32 + g4 * 8)));
            acc[nt] = MFMA(Af, Bf[kt], acc[nt]);
        }
    }
    float* outb = out + (size_t)b * 524288;
#pragma unroll
    for (int nt = 0; nt < 8; nt++) {
#pragma unroll
        for (int rr = 0; rr < 4; rr++) {
            int o2 = 16 * nt + 4 * g4 + rr;
            outb[(size_t)o2 * 4096 + r * 64 + w] = acc[nt][rr] + b_up[o2];
        }
    }
}

extern "C" void kernel_launch(void* const* d_in, const int* in_sizes, int n_in,
                              void* d_out, int out_size, void* d_ws,
                              size_t ws_size, hipStream_t stream) {
    (void)in_sizes; (void)n_in; (void)out_size; (void)ws_size;
    const float* inputs = (const float*)d_in[0];
    const float* w_i2s = (const float*)d_in[1];
    const float* b_i2s = (const float*)d_in[2];
    const float* w_s2s = (const float*)d_in[3];
    const float* b_s2s = (const float*)d_in[4];
    const float* w_c2c = (const float*)d_in[5];
    const float* b_c2c = (const float*)d_in[6];
    const float* w_up = (const float*)d_in[7];
    const float* b_up = (const float*)d_in[8];
    float* out = (float*)d_out;
    char* ws = (char*)d_ws;

    // workspace layout (bytes):
    // [0, 69206016)             i2sP u16 (32*64*66*256, bias-padded slots)
    // [69206016, 85983232)      hh16 u16 (32*64*64*64)
    // [85983232, 86114304)      Wg fp32 (256*128, scaled -log2e)
    // [86114304, 86147072)      Wc fp32 (64*128)
    // [86147072, 86147584)      biasRow u16[256]
    // [86147584, 86163968)      w_upB u16 (128*64)
    u16* i2sP = (u16*)ws;
    u16* hh16 = (u16*)(ws + 69206016);
    float* Wg = (float*)(ws + 85983232);
    float* Wc = (float*)(ws + 86114304);
    u16* biasRow = (u16*)(ws + 86147072);
    u16* w_upB = (u16*)(ws + 86147584);

    hipLaunchKernelGGL(repack_w, dim3(193), dim3(256), 0, stream, w_s2s, w_c2c,
                       b_i2s, b_s2s, w_up, Wg, Wc, biasRow, w_upB);
    hipLaunchKernelGGL(i2s_kernel, dim3(2048), dim3(256), 0, stream, inputs,
                       w_i2s, b_i2s, b_s2s, (const u32*)biasRow, (u32*)i2sP);
    hipLaunchKernelGGL(scan_kernel, dim3(32), dim3(512), 0, stream, i2sP, Wg,
                       Wc, b_c2c, hh16);
    hipLaunchKernelGGL(up_kernel, dim3(2048), dim3(256), 0, stream, hh16,
                       w_upB, b_up, out);
}

// Round 4
// 495.939 us; speedup vs baseline: 1.1406x; 1.1406x over previous
//
#include <hip/hip_runtime.h>
#include <cstdint>
#include <cstddef>

// DiagonalLSTM B=32,C=64,H=64,W=64,h=64,4h=256,NW=127 — v8.
// v8 = scan reverted to exact v4 (known-pass 359us; v7's relaxed barrier
// REGRESSED: loads/stores share vmcnt in issue order, so removing the
// barrier drain pushed hh16 store-ack waits into the compute phase).
// NEW: i2s_kernel rewritten as MFMA GEMM (was a VALU matmul: 2048 blocks
// x 4096 FMA/thread ~ 8.6 GFLOP on vector ALU). X staged to LDS bf16
// [w][c] with 16B-chunk XOR swizzle; W as bf16 A-frags from L2; 32 MFMAs
// per wave; bias+SCL epilogue; output goes through the identical sT /
// 512B-slot path (downstream format unchanged).

typedef unsigned int u32;
typedef unsigned short u16;
typedef __bf16 bf16x8 __attribute__((ext_vector_type(8)));
typedef float f32x4 __attribute__((ext_vector_type(4)));

#define NSTEP 127
#define MFMA(a, b, c) __builtin_amdgcn_mfma_f32_16x16x32_bf16(a, b, c, 0, 0, 0)
#define LOG2E 1.4426950408889634f
#define SCL (-1.4426950408889634f)
#define T2L 2.8853900817779268f
#define RHO(r) ((((r) ^ ((r) >> 3))) & 7)

static __device__ __forceinline__ u16 f2bf(float f) {
    u32 u = __builtin_bit_cast(u32, f);
    u32 r = u + 0x7FFFu + ((u >> 16) & 1u);
    return (u16)(r >> 16);
}
static __device__ __forceinline__ u32 pack2(float a, float b) {
    return (u32)f2bf(a) | ((u32)f2bf(b) << 16);
}
static __device__ __forceinline__ float lo2f(u32 u) {
    return __builtin_bit_cast(float, u << 16);
}
static __device__ __forceinline__ float hi2f(u32 u) {
    return __builtin_bit_cast(float, u & 0xFFFF0000u);
}
static __device__ __forceinline__ float sigm2(float y) {  // y pre-scaled by -log2e
    return __builtin_amdgcn_rcpf(1.f + __builtin_amdgcn_exp2f(y));
}
static __device__ __forceinline__ float tanh_fast(float x) {
    float r = __builtin_amdgcn_rcpf(1.f + __builtin_amdgcn_exp2f(x * T2L));
    return __builtin_fmaf(-2.f, r, 1.f);
}

// ---------------- K0: weight repack ----------------
// Wg[o][128] = -log2e * [Ws0_row | Ws1_row]; Wc[o][128] = [Wc0 | Wc1] (unscaled)
// biasRow u16[256] (o''-layout) = bf(-log2e*(bi+bs)); w_upB u16[128*64] = bf(w_up)
__global__ __launch_bounds__(256) void repack_w(
    const float* __restrict__ w_s2s, const float* __restrict__ w_c2c,
    const float* __restrict__ bi, const float* __restrict__ bs,
    const float* __restrict__ w_up, float* __restrict__ Wg,
    float* __restrict__ Wc, u16* __restrict__ biasRow,
    u16* __restrict__ w_upB) {
    int idx = blockIdx.x * 256 + threadIdx.x;
    if (idx < 32768) {
        int o = idx >> 7, kk = idx & 127, half = kk >> 6, k = kk & 63;
        Wg[idx] = SCL * w_s2s[(o * 64 + k) * 2 + half];
        return;
    }
    int j = idx - 32768;
    if (j < 8192) {
        int o = j >> 7, kk = j & 127, half = kk >> 6, k = kk & 63;
        Wc[j] = w_c2c[(o * 64 + k) * 2 + half];
        return;
    }
    j -= 8192;
    if (j < 256) {
        int m15 = j >> 4, nq = (j >> 2) & 3, nb = j & 3;
        int o = 64 * nq + 16 * nb + m15;
        biasRow[j] = f2bf(SCL * (bi[o] + bs[o]));
        return;
    }
    j -= 256;
    if (j < 8192) w_upB[j] = f2bf(w_up[j]);
}

// ---------------- K1: i2s conv via MFMA, o''-permuted, bias-padded ----------
// per (b,r) block, 256 thr = 4 waves. GEMM: [o=256] x [w=64], K = c = 64.
// A = w_i2s (bf16, converted in-reg from L2-hot f32), B = X staged in LDS as
// bf16 [w][c] with 16B-chunk XOR swizzle (byte ^= (w&7)<<4).
// Output staged via sT u16[w 64][o'' 256] (u32 stride 129) -> 512B slots.
// slot (b,p,w): ((b*64+p)*66 + (w+1)) * 512 bytes; w=-1 and w=64 slots = biasRow
__global__ __launch_bounds__(256, 2) void i2s_kernel(
    const float* __restrict__ in, const float* __restrict__ w_i2s,
    const float* __restrict__ bi, const float* __restrict__ bs,
    const u32* __restrict__ biasU32, u32* __restrict__ out_u32) {
    const int bid = blockIdx.x;
    const int b = bid >> 6, r = bid & 63;
    const int tid = threadIdx.x;
    const int lane = tid & 63;
    const int wv = __builtin_amdgcn_readfirstlane(tid >> 6);
    const int m15 = lane & 15, g4 = lane >> 4;

    __shared__ __align__(16) u32 sT[64 * 129];  // u16 [w 64][o'' 256], stride 258
    __shared__ __align__(16) u32 Xt[64 * 32];   // bf16 [w 64][c 64], swizzled
    char* XtB = (char*)Xt;

    // ---- stage X = in[b][:][r][:] to LDS bf16 [w][c] (XOR-swizzled chunks) ----
    {
        const int w = tid & 63, cp = tid >> 6;  // cp in 0..3
        const float* xp = in + (size_t)b * 262144 + r * 64 + w;
#pragma unroll
        for (int pass = 0; pass < 8; pass++) {
            int c = pass * 8 + cp * 2;
            float x0 = xp[(size_t)c * 4096];
            float x1 = xp[(size_t)(c + 1) * 4096];
            *(u32*)(XtB + ((w * 128 + c * 2) ^ ((w & 7) << 4))) = pack2(x0, x1);
        }
    }

    // ---- A fragments: rows o = wv*64 + m*16 + m15, k = c = kt*32+g4*8+j ----
    bf16x8 Af[4][2];
#pragma unroll
    for (int m = 0; m < 4; m++)
#pragma unroll
        for (int kt = 0; kt < 2; kt++) {
            const float* p =
                w_i2s + (wv * 64 + m * 16 + m15) * 64 + kt * 32 + g4 * 8;
            bf16x8 f;
#pragma unroll
            for (int j = 0; j < 8; j++) f[j] = (__bf16)p[j];
            Af[m][kt] = f;
        }
    // ---- bias for epilogue: o = wv*64 + m*16 + 4*g4 + reg ----
    float bias[4][4];
#pragma unroll
    for (int m = 0; m < 4; m++)
#pragma unroll
        for (int reg = 0; reg < 4; reg++) {
            int o = wv * 64 + m * 16 + 4 * g4 + reg;
            bias[m][reg] = bi[o] + bs[o];
        }

    __syncthreads();

    // ---- MFMA: acc[m][nt], B col = w = nt*16+m15, k = kt*32+g4*8+j ----
    f32x4 acc[4][4] = {};
#pragma unroll
    for (int nt = 0; nt < 4; nt++) {
        const int w = nt * 16 + m15;
        bf16x8 Bf[2];
#pragma unroll
        for (int kt = 0; kt < 2; kt++)
            Bf[kt] = __builtin_bit_cast(
                bf16x8, *(const uint4*)(XtB + ((w * 128 + kt * 64 + g4 * 16) ^
                                               ((w & 7) << 4))));
#pragma unroll
        for (int m = 0; m < 4; m++)
#pragma unroll
            for (int kt = 0; kt < 2; kt++)
                acc[m][nt] = MFMA(Af[m][kt], Bf[kt], acc[m][nt]);
    }

    // ---- epilogue: SCL*(acc+bias) -> bf16 pairs into sT ----
    // out elem (o,w): o = wv*64 + m*16 + 4*g4 + reg;
    // o'' = (o&15)*16 + (o>>6)*4 + ((o>>4)&3) = (4*g4+reg)*16 + wv*4 + m.
    // adjacent o'' pairs differ in m (m, m+1) -> one u32 write.
#pragma unroll
    for (int nt = 0; nt < 4; nt++) {
        const int w = nt * 16 + m15;
#pragma unroll
        for (int reg = 0; reg < 4; reg++)
#pragma unroll
            for (int mp = 0; mp < 2; mp++) {
                float v0 = SCL * (acc[2 * mp][nt][reg] + bias[2 * mp][reg]);
                float v1 =
                    SCL * (acc[2 * mp + 1][nt][reg] + bias[2 * mp + 1][reg]);
                sT[w * 129 + (4 * g4 + reg) * 8 + wv * 2 + mp] = pack2(v0, v1);
            }
    }
    __syncthreads();

    const size_t base = ((size_t)(b * 64 + r) * 66 + 1) * 128;  // u32 units
#pragma unroll
    for (int loop = 0; loop < 32; loop++) {
        int idx = loop * 256 + tid;
        int w = idx >> 7, cu = idx & 127;
        out_u32[base + idx] = sT[w * 129 + cu];
    }
    if (tid < 128) {
        u32 v = biasU32[tid];
        out_u32[base - 128 + tid] = v;       // w = -1 slot
        out_u32[base + 8192 + tid] = v;      // w = 64 slot
    }
}

// ---------------- K2: MFMA scan (v4, known-pass) ----------------
// 32 blocks x 512 threads (8 waves). wave wv: mh=wv>>2, nq=wv&3 => mt=2mh+mi.
// c2c: mtc=wv>>1, ktc0=(wv&1)*2.
// LDS sM bytes: [0,8192) H par0 rows0..63x128B; [8192,16384) H par1;
// [16384,32768) C par0/par1; ZH0@32768 ZC0@32896 ZH1@40960 ZC1@41088 (zeros).
// All H/C addrs XOR 8192 per step. Row chunks (16B) swizzled by RHO(row).
__global__ __launch_bounds__(512, 2) void scan_kernel(
    const u16* __restrict__ i2sP, const float* __restrict__ Wg,
    const float* __restrict__ Wc, const float* __restrict__ b_c2c,
    u16* __restrict__ hh16) {
    const int b = blockIdx.x;
    const int tid = threadIdx.x;
    const int lane = tid & 63;
    const int wv = __builtin_amdgcn_readfirstlane(tid >> 6);
    const int mh = wv >> 2, nq = wv & 3;
    const int mtc = wv >> 1, ktc0 = (wv & 1) * 2;
    const int m15 = lane & 15, g4 = lane >> 4;

    __shared__ __align__(16) u32 sM[10304];   // 41216 B
    __shared__ __align__(16) u32 sCCm[2048];  // 8192 B
    char* smB = (char*)sM;
    char* ccB = (char*)sCCm;

    for (int i = tid; i < 10304; i += 512) sM[i] = 0;

    // ---- VGPR-resident weights ----
    bf16x8 BW[4][4];
    float bcc[4];
#pragma unroll
    for (int nb = 0; nb < 4; nb++) {
        int o = 64 * nq + 16 * nb + m15;
        bcc[nb] = b_c2c[16 * nb + m15];
#pragma unroll
        for (int kt = 0; kt < 4; kt++) {
            const float* p = Wg + o * 128 + kt * 32 + g4 * 8;
            bf16x8 f;
#pragma unroll
            for (int j = 0; j < 8; j++) f[j] = (__bf16)p[j];
            BW[nb][kt] = f;
        }
    }
    bf16x8 BC[2][4];
#pragma unroll
    for (int i = 0; i < 2; i++) {
        int o2 = 16 * (ktc0 + i) + m15;
#pragma unroll
        for (int kt = 0; kt < 4; kt++) {
            const float* p = Wc + o2 * 128 + kt * 32 + g4 * 8;
            bf16x8 f;
#pragma unroll
            for (int j = 0; j < 8; j++) f[j] = (__bf16)p[j];
            BC[i][kt] = f;
        }
    }

    // ---- precomputed addresses ----
    int aG[2][4], aC[4], wOff[2][4], ccR[2][4], ccP[4], bOffB[2][4];
#pragma unroll
    for (int mi = 0; mi < 2; mi++) {
        int mt = 2 * mh + mi;
#pragma unroll
        for (int kt = 0; kt < 4; kt++) {
            int P = 16 * (m15 & 3) + 4 * mt + (m15 >> 2);
            int phys = P + (kt >> 1) - 1;
            int chunk = (kt & 1) * 4 + g4;
            aG[mi][kt] = (phys < 0) ? (32768 + chunk * 16)
                                    : (phys * 128 + ((chunk ^ RHO(phys)) * 16));
        }
        int p2 = 16 * mt + 4 * g4 + nq;
#pragma unroll
        for (int nb = 0; nb < 4; nb++) {
            int k = 16 * nb + m15;
            wOff[mi][nb] =
                8192 + p2 * 128 + (((k >> 3) ^ RHO(p2)) * 16) + (k & 7) * 2;
            int rp = p2 >> 1;
            ccR[mi][nb] = (rp * 64 + ((k + 8 * rp) & 63)) * 4;
            int prerow = 16 * nb + 4 * mt + g4;  // nb doubles as gate idx r here
            bOffB[mi][nb] = (prerow * 66 + 1) * 512 + 32 * m15 + 8 * nq;
        }
    }
#pragma unroll
    for (int kt = 0; kt < 4; kt++) {
        int crow = 16 * mtc + m15;
        int phys = crow + (kt >> 1) - 1;
        int chunk = (kt & 1) * 4 + g4;
        aC[kt] = (phys < 0) ? (32896 + chunk * 16)
                            : (16384 + phys * 128 + ((chunk ^ RHO(phys)) * 16));
    }
#pragma unroll
    for (int i = 0; i < 2; i++) {
        int k = 16 * (ktc0 + i) + m15;
        int rp0 = 8 * mtc + 2 * g4, rp1 = rp0 + 1;
        ccP[2 * i] = (rp0 * 64 + ((k + 8 * rp0) & 63)) * 4;
        ccP[2 * i + 1] = (rp1 * 64 + ((k + 8 * rp1) & 63)) * 4;
    }

    const char* i2sB = (const char*)i2sP + (size_t)b * (64 * 66 * 512);
    u16* hp16[2];
    int p2s[2];
#pragma unroll
    for (int mi = 0; mi < 2; mi++) {
        int p2 = 16 * (2 * mh + mi) + 4 * g4 + nq;
        p2s[mi] = p2;
        hp16[mi] = hh16 + (size_t)b * 262144 + p2 * 4032 + m15;
    }

    __syncthreads();

    for (int t = 0; t < NSTEP; t++) {
        // ---- i2s prefetch: one 8B load = 4 gate values (bias-padded) ----
        uint2 IV[2][4];
#pragma unroll
        for (int mi = 0; mi < 2; mi++) {
            int mt = 2 * mh + mi;
#pragma unroll
            for (int r = 0; r < 4; r++) {
                int prerow = 16 * r + 4 * mt + g4;
                int w = min(max(t - prerow, -1), 64);
                IV[mi][r] =
                    *(const uint2*)(i2sB + (bOffB[mi][r] + (w << 9)));
            }
        }

        // ---- gate MFMAs (permuted A rows) ----
        f32x4 accG[2][4] = {};
#pragma unroll
        for (int mi = 0; mi < 2; mi++) {
            bf16x8 Ag[4];
#pragma unroll
            for (int kt = 0; kt < 4; kt++)
                Ag[kt] = __builtin_bit_cast(bf16x8,
                                            *(const uint4*)(smB + aG[mi][kt]));
#pragma unroll
            for (int nb = 0; nb < 4; nb++)
#pragma unroll
                for (int kt = 0; kt < 4; kt++)
                    accG[mi][nb] = MFMA(Ag[kt], BW[nb][kt], accG[mi][nb]);
        }
        // ---- c2c MFMAs ----
        f32x4 accC[2] = {};
        {
            bf16x8 Ac[4];
#pragma unroll
            for (int kt = 0; kt < 4; kt++)
                Ac[kt] =
                    __builtin_bit_cast(bf16x8, *(const uint4*)(smB + aC[kt]));
#pragma unroll
            for (int i = 0; i < 2; i++)
#pragma unroll
                for (int kt = 0; kt < 4; kt++)
                    accC[i] = MFMA(Ac[kt], BC[i][kt], accC[i]);
        }

        // ---- add i2s (bias-padded: unconditional) ----
#pragma unroll
        for (int mi = 0; mi < 2; mi++)
#pragma unroll
            for (int r = 0; r < 4; r++) {
                u32 w0 = IV[mi][r].x, w1 = IV[mi][r].y;
                accG[mi][0][r] += lo2f(w0);
                accG[mi][1][r] += hi2f(w0);
                accG[mi][2][r] += lo2f(w1);
                accG[mi][3][r] += hi2f(w1);
            }

        // ---- publish c2c ----
#pragma unroll
        for (int i = 0; i < 2; i++) {
            *(u32*)(ccB + ccP[2 * i]) = pack2(accC[i][0], accC[i][1]);
            *(u32*)(ccB + ccP[2 * i + 1]) = pack2(accC[i][2], accC[i][3]);
        }
        __syncthreads();

        // ---- stage B: LSTM update ----
#pragma unroll
        for (int mi = 0; mi < 2; mi++) {
            int p2 = p2s[mi];
            bool vst = (u32)(t - p2) < 64u;
            u16* hp = hp16[mi];
#pragma unroll
            for (int nb = 0; nb < 4; nb++) {
                u32 cw = *(const u32*)(ccB + ccR[mi][nb]);
                float cc = ((nq & 1) ? hi2f(cw) : lo2f(cw)) + bcc[nb];
                float si = sigm2(accG[mi][nb][0]);
                float sg = sigm2(accG[mi][nb][1]);
                float sf = sigm2(accG[mi][nb][2]);
                float so = sigm2(accG[mi][nb][3]);
                float c1 = __builtin_fmaf(sf, cc, si * sg);
                float h1 = so * tanh_fast(c1);
                u16 hb = f2bf(h1);
                *(u16*)(smB + wOff[mi][nb]) = hb;
                *(u16*)(smB + wOff[mi][nb] + 16384) = f2bf(c1);
                if (vst) hp[nb * 16] = hb;
            }
            hp16[mi] += 64;
        }
        __syncthreads();

        // ---- toggle parity ----
#pragma unroll
        for (int mi = 0; mi < 2; mi++) {
#pragma unroll
            for (int kt = 0; kt < 4; kt++) aG[mi][kt] ^= 8192;
#pragma unroll
            for (int nb = 0; nb < 4; nb++) wOff[mi][nb] ^= 8192;
        }
#pragma unroll
        for (int kt = 0; kt < 4; kt++) aC[kt] ^= 8192;
    }
}

// ---------------- K3: up-projection via MFMA ----------------
// per (b,r) block, 256 thr = 4 waves, wave = w-tile. A=w_upB, B=hh bf16.
__global__ __launch_bounds__(256) void up_kernel(
    const u16* __restrict__ hh16, const u16* __restrict__ w_upB,
    const float* __restrict__ b_up, float* __restrict__ out) {
    const int bid = blockIdx.x;
    const int b = bid >> 6, r = bid & 63;
    const int lane = threadIdx.x & 63;
    const int wt = __builtin_amdgcn_readfirstlane(threadIdx.x >> 6);
    const int m15 = lane & 15, g4 = lane >> 4;

    const u16* hh_b = hh16 + (size_t)b * 262144;
    const int w = 16 * wt + m15;

    bf16x8 Bf[2];
#pragma unroll
    for (int kt = 0; kt < 2; kt++)
        Bf[kt] = __builtin_bit_cast(
            bf16x8,
            *(const uint4*)(hh_b + (r * 4096 + w * 64 + kt * 32 + g4 * 8)));

    f32x4 acc[8] = {};
#pragma unroll
    for (int nt = 0; nt < 8; nt++) {
#pragma unroll
        for (int kt = 0; kt < 2; kt++) {
            bf16x8 Af = __builtin_bit_cast(
                bf16x8, *(const uint4*)(w_upB + ((16 * nt + m15) * 64 +
                                                 kt * 32 + g4 * 8)));
            acc[nt] = MFMA(Af, Bf[kt], acc[nt]);
        }
    }
    float* outb = out + (size_t)b * 524288;
#pragma unroll
    for (int nt = 0; nt < 8; nt++) {
#pragma unroll
        for (int rr = 0; rr < 4; rr++) {
            int o2 = 16 * nt + 4 * g4 + rr;
            outb[(size_t)o2 * 4096 + r * 64 + w] = acc[nt][rr] + b_up[o2];
        }
    }
}

extern "C" void kernel_launch(void* const* d_in, const int* in_sizes, int n_in,
                              void* d_out, int out_size, void* d_ws,
                              size_t ws_size, hipStream_t stream) {
    (void)in_sizes; (void)n_in; (void)out_size; (void)ws_size;
    const float* inputs = (const float*)d_in[0];
    const float* w_i2s = (const float*)d_in[1];
    const float* b_i2s = (const float*)d_in[2];
    const float* w_s2s = (const float*)d_in[3];
    const float* b_s2s = (const float*)d_in[4];
    const float* w_c2c = (const float*)d_in[5];
    const float* b_c2c = (const float*)d_in[6];
    const float* w_up = (const float*)d_in[7];
    const float* b_up = (const float*)d_in[8];
    float* out = (float*)d_out;
    char* ws = (char*)d_ws;

    // workspace layout (bytes):
    // [0, 69206016)             i2sP u16 (32*64*66*256, bias-padded slots)
    // [69206016, 85983232)      hh16 u16 (32*64*64*64)
    // [85983232, 86114304)      Wg fp32 (256*128, scaled -log2e)
    // [86114304, 86147072)      Wc fp32 (64*128)
    // [86147072, 86147584)      biasRow u16[256]
    // [86147584, 86163968)      w_upB u16 (128*64)
    u16* i2sP = (u16*)ws;
    u16* hh16 = (u16*)(ws + 69206016);
    float* Wg = (float*)(ws + 85983232);
    float* Wc = (float*)(ws + 86114304);
    u16* biasRow = (u16*)(ws + 86147072);
    u16* w_upB = (u16*)(ws + 86147584);

    hipLaunchKernelGGL(repack_w, dim3(193), dim3(256), 0, stream, w_s2s, w_c2c,
                       b_i2s, b_s2s, w_up, Wg, Wc, biasRow, w_upB);
    hipLaunchKernelGGL(i2s_kernel, dim3(2048), dim3(256), 0, stream, inputs,
                       w_i2s, b_i2s, b_s2s, (const u32*)biasRow, (u32*)i2sP);
    hipLaunchKernelGGL(scan_kernel, dim3(32), dim3(512), 0, stream, i2sP, Wg,
                       Wc, b_c2c, hh16);
    hipLaunchKernelGGL(up_kernel, dim3(2048), dim3(256), 0, stream, hh16,
                       w_upB, b_up, out);
}

// Round 5
// 444.671 us; speedup vs baseline: 1.2721x; 1.1153x over previous
//
#include <hip/hip_runtime.h>
#include <cstdint>
#include <cstddef>

// DiagonalLSTM B=32,C=64,H=64,W=64,h=64,4h=256,NW=127 — v9.
// v9 = v8 with scan_kernel VMEM re-timed, keeping FULL __syncthreads():
//  - hh16 global stores deferred by half a step (values carried in regs,
//    issued at the TOP of the next step) -> barrier-2's vmcnt(0) drain has
//    nothing outstanding; barrier-1 drains stores issued a full phase ago.
//  - i2s loads prefetched one step ahead (IV(t+1) issued at top of t) and
//    folded into the MFMA accumulator init (saves 32 v_add/thread/step and
//    gives HBM-miss loads ~a full step of slack before any drain).
// No relaxed barriers, no counted vmcnt, no cvt_pk, no unroll-2 (v5-NaN
// suspects excluded). K0/K1(MFMA)/K3 unchanged from v8.

typedef unsigned int u32;
typedef unsigned short u16;
typedef __bf16 bf16x8 __attribute__((ext_vector_type(8)));
typedef float f32x4 __attribute__((ext_vector_type(4)));

#define NSTEP 127
#define MFMA(a, b, c) __builtin_amdgcn_mfma_f32_16x16x32_bf16(a, b, c, 0, 0, 0)
#define LOG2E 1.4426950408889634f
#define SCL (-1.4426950408889634f)
#define T2L 2.8853900817779268f
#define RHO(r) ((((r) ^ ((r) >> 3))) & 7)

static __device__ __forceinline__ u16 f2bf(float f) {
    u32 u = __builtin_bit_cast(u32, f);
    u32 r = u + 0x7FFFu + ((u >> 16) & 1u);
    return (u16)(r >> 16);
}
static __device__ __forceinline__ u32 pack2(float a, float b) {
    return (u32)f2bf(a) | ((u32)f2bf(b) << 16);
}
static __device__ __forceinline__ float lo2f(u32 u) {
    return __builtin_bit_cast(float, u << 16);
}
static __device__ __forceinline__ float hi2f(u32 u) {
    return __builtin_bit_cast(float, u & 0xFFFF0000u);
}
static __device__ __forceinline__ float sigm2(float y) {  // y pre-scaled by -log2e
    return __builtin_amdgcn_rcpf(1.f + __builtin_amdgcn_exp2f(y));
}
static __device__ __forceinline__ float tanh_fast(float x) {
    float r = __builtin_amdgcn_rcpf(1.f + __builtin_amdgcn_exp2f(x * T2L));
    return __builtin_fmaf(-2.f, r, 1.f);
}

// ---------------- K0: weight repack ----------------
// Wg[o][128] = -log2e * [Ws0_row | Ws1_row]; Wc[o][128] = [Wc0 | Wc1] (unscaled)
// biasRow u16[256] (o''-layout) = bf(-log2e*(bi+bs)); w_upB u16[128*64] = bf(w_up)
__global__ __launch_bounds__(256) void repack_w(
    const float* __restrict__ w_s2s, const float* __restrict__ w_c2c,
    const float* __restrict__ bi, const float* __restrict__ bs,
    const float* __restrict__ w_up, float* __restrict__ Wg,
    float* __restrict__ Wc, u16* __restrict__ biasRow,
    u16* __restrict__ w_upB) {
    int idx = blockIdx.x * 256 + threadIdx.x;
    if (idx < 32768) {
        int o = idx >> 7, kk = idx & 127, half = kk >> 6, k = kk & 63;
        Wg[idx] = SCL * w_s2s[(o * 64 + k) * 2 + half];
        return;
    }
    int j = idx - 32768;
    if (j < 8192) {
        int o = j >> 7, kk = j & 127, half = kk >> 6, k = kk & 63;
        Wc[j] = w_c2c[(o * 64 + k) * 2 + half];
        return;
    }
    j -= 8192;
    if (j < 256) {
        int m15 = j >> 4, nq = (j >> 2) & 3, nb = j & 3;
        int o = 64 * nq + 16 * nb + m15;
        biasRow[j] = f2bf(SCL * (bi[o] + bs[o]));
        return;
    }
    j -= 256;
    if (j < 8192) w_upB[j] = f2bf(w_up[j]);
}

// ---------------- K1: i2s conv via MFMA, o''-permuted, bias-padded ----------
// per (b,r) block, 256 thr = 4 waves. GEMM: [o=256] x [w=64], K = c = 64.
// A = w_i2s (bf16, converted in-reg from L2-hot f32), B = X staged in LDS as
// bf16 [w][c] with 16B-chunk XOR swizzle (byte ^= (w&7)<<4).
// Output staged via sT u16[w 64][o'' 256] (u32 stride 129) -> 512B slots.
// slot (b,p,w): ((b*64+p)*66 + (w+1)) * 512 bytes; w=-1 and w=64 slots = biasRow
__global__ __launch_bounds__(256, 2) void i2s_kernel(
    const float* __restrict__ in, const float* __restrict__ w_i2s,
    const float* __restrict__ bi, const float* __restrict__ bs,
    const u32* __restrict__ biasU32, u32* __restrict__ out_u32) {
    const int bid = blockIdx.x;
    const int b = bid >> 6, r = bid & 63;
    const int tid = threadIdx.x;
    const int lane = tid & 63;
    const int wv = __builtin_amdgcn_readfirstlane(tid >> 6);
    const int m15 = lane & 15, g4 = lane >> 4;

    __shared__ __align__(16) u32 sT[64 * 129];  // u16 [w 64][o'' 256], stride 258
    __shared__ __align__(16) u32 Xt[64 * 32];   // bf16 [w 64][c 64], swizzled
    char* XtB = (char*)Xt;

    // ---- stage X = in[b][:][r][:] to LDS bf16 [w][c] (XOR-swizzled chunks) ----
    {
        const int w = tid & 63, cp = tid >> 6;  // cp in 0..3
        const float* xp = in + (size_t)b * 262144 + r * 64 + w;
#pragma unroll
        for (int pass = 0; pass < 8; pass++) {
            int c = pass * 8 + cp * 2;
            float x0 = xp[(size_t)c * 4096];
            float x1 = xp[(size_t)(c + 1) * 4096];
            *(u32*)(XtB + ((w * 128 + c * 2) ^ ((w & 7) << 4))) = pack2(x0, x1);
        }
    }

    // ---- A fragments: rows o = wv*64 + m*16 + m15, k = c = kt*32+g4*8+j ----
    bf16x8 Af[4][2];
#pragma unroll
    for (int m = 0; m < 4; m++)
#pragma unroll
        for (int kt = 0; kt < 2; kt++) {
            const float* p =
                w_i2s + (wv * 64 + m * 16 + m15) * 64 + kt * 32 + g4 * 8;
            bf16x8 f;
#pragma unroll
            for (int j = 0; j < 8; j++) f[j] = (__bf16)p[j];
            Af[m][kt] = f;
        }
    // ---- bias for epilogue: o = wv*64 + m*16 + 4*g4 + reg ----
    float bias[4][4];
#pragma unroll
    for (int m = 0; m < 4; m++)
#pragma unroll
        for (int reg = 0; reg < 4; reg++) {
            int o = wv * 64 + m * 16 + 4 * g4 + reg;
            bias[m][reg] = bi[o] + bs[o];
        }

    __syncthreads();

    // ---- MFMA: acc[m][nt], B col = w = nt*16+m15, k = kt*32+g4*8+j ----
    f32x4 acc[4][4] = {};
#pragma unroll
    for (int nt = 0; nt < 4; nt++) {
        const int w = nt * 16 + m15;
        bf16x8 Bf[2];
#pragma unroll
        for (int kt = 0; kt < 2; kt++)
            Bf[kt] = __builtin_bit_cast(
                bf16x8, *(const uint4*)(XtB + ((w * 128 + kt * 64 + g4 * 16) ^
                                               ((w & 7) << 4))));
#pragma unroll
        for (int m = 0; m < 4; m++)
#pragma unroll
            for (int kt = 0; kt < 2; kt++)
                acc[m][nt] = MFMA(Af[m][kt], Bf[kt], acc[m][nt]);
    }

    // ---- epilogue: SCL*(acc+bias) -> bf16 pairs into sT ----
    // out elem (o,w): o = wv*64 + m*16 + 4*g4 + reg;
    // o'' = (o&15)*16 + (o>>6)*4 + ((o>>4)&3) = (4*g4+reg)*16 + wv*4 + m.
    // adjacent o'' pairs differ in m (m, m+1) -> one u32 write.
#pragma unroll
    for (int nt = 0; nt < 4; nt++) {
        const int w = nt * 16 + m15;
#pragma unroll
        for (int reg = 0; reg < 4; reg++)
#pragma unroll
            for (int mp = 0; mp < 2; mp++) {
                float v0 = SCL * (acc[2 * mp][nt][reg] + bias[2 * mp][reg]);
                float v1 =
                    SCL * (acc[2 * mp + 1][nt][reg] + bias[2 * mp + 1][reg]);
                sT[w * 129 + (4 * g4 + reg) * 8 + wv * 2 + mp] = pack2(v0, v1);
            }
    }
    __syncthreads();

    const size_t base = ((size_t)(b * 64 + r) * 66 + 1) * 128;  // u32 units
#pragma unroll
    for (int loop = 0; loop < 32; loop++) {
        int idx = loop * 256 + tid;
        int w = idx >> 7, cu = idx & 127;
        out_u32[base + idx] = sT[w * 129 + cu];
    }
    if (tid < 128) {
        u32 v = biasU32[tid];
        out_u32[base - 128 + tid] = v;       // w = -1 slot
        out_u32[base + 8192 + tid] = v;      // w = 64 slot
    }
}

// ---------------- K2: MFMA scan v9 ----------------
// 32 blocks x 512 threads (8 waves). wave wv: mh=wv>>2, nq=wv&3 => mt=2mh+mi.
// c2c: mtc=wv>>1, ktc0=(wv&1)*2.
// LDS sM bytes: [0,8192) H par0 rows0..63x128B; [8192,16384) H par1;
// [16384,32768) C par0/par1; ZH0@32768 ZC0@32896 ZH1@40960 ZC1@41088 (zeros).
// All H/C addrs XOR 8192 per step. Row chunks (16B) swizzled by RHO(row).
// v9: IV prefetched one step ahead -> MFMA acc init; hh16 stores deferred to
// the top of the next step (register carry). Full __syncthreads kept.
__global__ __launch_bounds__(512, 2) void scan_kernel(
    const u16* __restrict__ i2sP, const float* __restrict__ Wg,
    const float* __restrict__ Wc, const float* __restrict__ b_c2c,
    u16* __restrict__ hh16) {
    const int b = blockIdx.x;
    const int tid = threadIdx.x;
    const int lane = tid & 63;
    const int wv = __builtin_amdgcn_readfirstlane(tid >> 6);
    const int mh = wv >> 2, nq = wv & 3;
    const int mtc = wv >> 1, ktc0 = (wv & 1) * 2;
    const int m15 = lane & 15, g4 = lane >> 4;

    __shared__ __align__(16) u32 sM[10304];   // 41216 B
    __shared__ __align__(16) u32 sCCm[2048];  // 8192 B
    char* smB = (char*)sM;
    char* ccB = (char*)sCCm;

    for (int i = tid; i < 10304; i += 512) sM[i] = 0;

    // ---- VGPR-resident weights ----
    bf16x8 BW[4][4];
    float bcc[4];
#pragma unroll
    for (int nb = 0; nb < 4; nb++) {
        int o = 64 * nq + 16 * nb + m15;
        bcc[nb] = b_c2c[16 * nb + m15];
#pragma unroll
        for (int kt = 0; kt < 4; kt++) {
            const float* p = Wg + o * 128 + kt * 32 + g4 * 8;
            bf16x8 f;
#pragma unroll
            for (int j = 0; j < 8; j++) f[j] = (__bf16)p[j];
            BW[nb][kt] = f;
        }
    }
    bf16x8 BC[2][4];
#pragma unroll
    for (int i = 0; i < 2; i++) {
        int o2 = 16 * (ktc0 + i) + m15;
#pragma unroll
        for (int kt = 0; kt < 4; kt++) {
            const float* p = Wc + o2 * 128 + kt * 32 + g4 * 8;
            bf16x8 f;
#pragma unroll
            for (int j = 0; j < 8; j++) f[j] = (__bf16)p[j];
            BC[i][kt] = f;
        }
    }

    // ---- precomputed addresses ----
    int aG[2][4], aC[4], wOff[2][4], ccR[2][4], ccP[4], bOffB[2][4];
#pragma unroll
    for (int mi = 0; mi < 2; mi++) {
        int mt = 2 * mh + mi;
#pragma unroll
        for (int kt = 0; kt < 4; kt++) {
            int P = 16 * (m15 & 3) + 4 * mt + (m15 >> 2);
            int phys = P + (kt >> 1) - 1;
            int chunk = (kt & 1) * 4 + g4;
            aG[mi][kt] = (phys < 0) ? (32768 + chunk * 16)
                                    : (phys * 128 + ((chunk ^ RHO(phys)) * 16));
        }
        int p2 = 16 * mt + 4 * g4 + nq;
#pragma unroll
        for (int nb = 0; nb < 4; nb++) {
            int k = 16 * nb + m15;
            wOff[mi][nb] =
                8192 + p2 * 128 + (((k >> 3) ^ RHO(p2)) * 16) + (k & 7) * 2;
            int rp = p2 >> 1;
            ccR[mi][nb] = (rp * 64 + ((k + 8 * rp) & 63)) * 4;
            int prerow = 16 * nb + 4 * mt + g4;  // nb doubles as gate idx r here
            bOffB[mi][nb] = (prerow * 66 + 1) * 512 + 32 * m15 + 8 * nq;
        }
    }
#pragma unroll
    for (int kt = 0; kt < 4; kt++) {
        int crow = 16 * mtc + m15;
        int phys = crow + (kt >> 1) - 1;
        int chunk = (kt & 1) * 4 + g4;
        aC[kt] = (phys < 0) ? (32896 + chunk * 16)
                            : (16384 + phys * 128 + ((chunk ^ RHO(phys)) * 16));
    }
#pragma unroll
    for (int i = 0; i < 2; i++) {
        int k = 16 * (ktc0 + i) + m15;
        int rp0 = 8 * mtc + 2 * g4, rp1 = rp0 + 1;
        ccP[2 * i] = (rp0 * 64 + ((k + 8 * rp0) & 63)) * 4;
        ccP[2 * i + 1] = (rp1 * 64 + ((k + 8 * rp1) & 63)) * 4;
    }

    const char* i2sB = (const char*)i2sP + (size_t)b * (64 * 66 * 512);
    u16* hp16[2];
    int p2s[2];
#pragma unroll
    for (int mi = 0; mi < 2; mi++) {
        int p2 = 16 * (2 * mh + mi) + 4 * g4 + nq;
        p2s[mi] = p2;
        hp16[mi] = hh16 + (size_t)b * 262144 + p2 * 4032 + m15;
    }

    // ---- initial IV load (t=0): w = clamp(0 - prerow) ----
    uint2 IV[2][4];
#pragma unroll
    for (int mi = 0; mi < 2; mi++) {
        int mt = 2 * mh + mi;
#pragma unroll
        for (int r = 0; r < 4; r++) {
            int prerow = 16 * r + 4 * mt + g4;
            int w = min(max(0 - prerow, -1), 64);
            IV[mi][r] = *(const uint2*)(i2sB + (bOffB[mi][r] + (w << 9)));
        }
    }

    // ---- deferred-store carry state ----
    u16 hbKeep[2][4];
    u16* hpPrev[2];
    bool vstPrev[2];
#pragma unroll
    for (int mi = 0; mi < 2; mi++) {
        vstPrev[mi] = false;
        hpPrev[mi] = hp16[mi];
    }

    __syncthreads();

    for (int t = 0; t < NSTEP; t++) {
        // ---- deferred hh16 stores from step t-1 (full phase of slack) ----
#pragma unroll
        for (int mi = 0; mi < 2; mi++)
            if (vstPrev[mi]) {
#pragma unroll
                for (int nb = 0; nb < 4; nb++)
                    hpPrev[mi][nb * 16] = hbKeep[mi][nb];
            }

        // ---- prefetch IV for step t+1 ----
        uint2 IVn[2][4];
#pragma unroll
        for (int mi = 0; mi < 2; mi++) {
            int mt = 2 * mh + mi;
#pragma unroll
            for (int r = 0; r < 4; r++) {
                int prerow = 16 * r + 4 * mt + g4;
                int w = min(max(t + 1 - prerow, -1), 64);
                IVn[mi][r] = *(const uint2*)(i2sB + (bOffB[mi][r] + (w << 9)));
            }
        }

        // ---- gate MFMAs, acc initialized from current IV ----
        f32x4 accG[2][4];
#pragma unroll
        for (int mi = 0; mi < 2; mi++) {
#pragma unroll
            for (int r = 0; r < 4; r++) {
                accG[mi][0][r] = lo2f(IV[mi][r].x);
                accG[mi][1][r] = hi2f(IV[mi][r].x);
                accG[mi][2][r] = lo2f(IV[mi][r].y);
                accG[mi][3][r] = hi2f(IV[mi][r].y);
            }
            bf16x8 Ag[4];
#pragma unroll
            for (int kt = 0; kt < 4; kt++)
                Ag[kt] = __builtin_bit_cast(bf16x8,
                                            *(const uint4*)(smB + aG[mi][kt]));
#pragma unroll
            for (int nb = 0; nb < 4; nb++)
#pragma unroll
                for (int kt = 0; kt < 4; kt++)
                    accG[mi][nb] = MFMA(Ag[kt], BW[nb][kt], accG[mi][nb]);
        }
        // ---- c2c MFMAs ----
        f32x4 accC[2] = {};
        {
            bf16x8 Ac[4];
#pragma unroll
            for (int kt = 0; kt < 4; kt++)
                Ac[kt] =
                    __builtin_bit_cast(bf16x8, *(const uint4*)(smB + aC[kt]));
#pragma unroll
            for (int i = 0; i < 2; i++)
#pragma unroll
                for (int kt = 0; kt < 4; kt++)
                    accC[i] = MFMA(Ac[kt], BC[i][kt], accC[i]);
        }

        // ---- publish c2c ----
#pragma unroll
        for (int i = 0; i < 2; i++) {
            *(u32*)(ccB + ccP[2 * i]) = pack2(accC[i][0], accC[i][1]);
            *(u32*)(ccB + ccP[2 * i + 1]) = pack2(accC[i][2], accC[i][3]);
        }
        __syncthreads();

        // ---- stage B: LSTM update (no global stores here; capture in regs) --
#pragma unroll
        for (int mi = 0; mi < 2; mi++) {
            int p2 = p2s[mi];
            bool vst = (u32)(t - p2) < 64u;
#pragma unroll
            for (int nb = 0; nb < 4; nb++) {
                u32 cw = *(const u32*)(ccB + ccR[mi][nb]);
                float cc = ((nq & 1) ? hi2f(cw) : lo2f(cw)) + bcc[nb];
                float si = sigm2(accG[mi][nb][0]);
                float sg = sigm2(accG[mi][nb][1]);
                float sf = sigm2(accG[mi][nb][2]);
                float so = sigm2(accG[mi][nb][3]);
                float c1 = __builtin_fmaf(sf, cc, si * sg);
                float h1 = so * tanh_fast(c1);
                u16 hb = f2bf(h1);
                *(u16*)(smB + wOff[mi][nb]) = hb;
                *(u16*)(smB + wOff[mi][nb] + 16384) = f2bf(c1);
                hbKeep[mi][nb] = hb;
            }
            vstPrev[mi] = vst;
            hpPrev[mi] = hp16[mi];
            hp16[mi] += 64;
        }
        __syncthreads();

        // ---- rotate prefetched IV; toggle parity ----
#pragma unroll
        for (int mi = 0; mi < 2; mi++) {
#pragma unroll
            for (int r = 0; r < 4; r++) IV[mi][r] = IVn[mi][r];
#pragma unroll
            for (int kt = 0; kt < 4; kt++) aG[mi][kt] ^= 8192;
#pragma unroll
            for (int nb = 0; nb < 4; nb++) wOff[mi][nb] ^= 8192;
        }
#pragma unroll
        for (int kt = 0; kt < 4; kt++) aC[kt] ^= 8192;
    }

    // ---- epilogue: final deferred stores (t = NSTEP-1) ----
#pragma unroll
    for (int mi = 0; mi < 2; mi++)
        if (vstPrev[mi]) {
#pragma unroll
            for (int nb = 0; nb < 4; nb++)
                hpPrev[mi][nb * 16] = hbKeep[mi][nb];
        }
}

// ---------------- K3: up-projection via MFMA ----------------
// per (b,r) block, 256 thr = 4 waves, wave = w-tile. A=w_upB, B=hh bf16.
__global__ __launch_bounds__(256) void up_kernel(
    const u16* __restrict__ hh16, const u16* __restrict__ w_upB,
    const float* __restrict__ b_up, float* __restrict__ out) {
    const int bid = blockIdx.x;
    const int b = bid >> 6, r = bid & 63;
    const int lane = threadIdx.x & 63;
    const int wt = __builtin_amdgcn_readfirstlane(threadIdx.x >> 6);
    const int m15 = lane & 15, g4 = lane >> 4;

    const u16* hh_b = hh16 + (size_t)b * 262144;
    const int w = 16 * wt + m15;

    bf16x8 Bf[2];
#pragma unroll
    for (int kt = 0; kt < 2; kt++)
        Bf[kt] = __builtin_bit_cast(
            bf16x8,
            *(const uint4*)(hh_b + (r * 4096 + w * 64 + kt * 32 + g4 * 8)));

    f32x4 acc[8] = {};
#pragma unroll
    for (int nt = 0; nt < 8; nt++) {
#pragma unroll
        for (int kt = 0; kt < 2; kt++) {
            bf16x8 Af = __builtin_bit_cast(
                bf16x8, *(const uint4*)(w_upB + ((16 * nt + m15) * 64 +
                                                 kt * 32 + g4 * 8)));
            acc[nt] = MFMA(Af, Bf[kt], acc[nt]);
        }
    }
    float* outb = out + (size_t)b * 524288;
#pragma unroll
    for (int nt = 0; nt < 8; nt++) {
#pragma unroll
        for (int rr = 0; rr < 4; rr++) {
            int o2 = 16 * nt + 4 * g4 + rr;
            outb[(size_t)o2 * 4096 + r * 64 + w] = acc[nt][rr] + b_up[o2];
        }
    }
}

extern "C" void kernel_launch(void* const* d_in, const int* in_sizes, int n_in,
                              void* d_out, int out_size, void* d_ws,
                              size_t ws_size, hipStream_t stream) {
    (void)in_sizes; (void)n_in; (void)out_size; (void)ws_size;
    const float* inputs = (const float*)d_in[0];
    const float* w_i2s = (const float*)d_in[1];
    const float* b_i2s = (const float*)d_in[2];
    const float* w_s2s = (const float*)d_in[3];
    const float* b_s2s = (const float*)d_in[4];
    const float* w_c2c = (const float*)d_in[5];
    const float* b_c2c = (const float*)d_in[6];
    const float* w_up = (const float*)d_in[7];
    const float* b_up = (const float*)d_in[8];
    float* out = (float*)d_out;
    char* ws = (char*)d_ws;

    // workspace layout (bytes):
    // [0, 69206016)             i2sP u16 (32*64*66*256, bias-padded slots)
    // [69206016, 85983232)      hh16 u16 (32*64*64*64)
    // [85983232, 86114304)      Wg fp32 (256*128, scaled -log2e)
    // [86114304, 86147072)      Wc fp32 (64*128)
    // [86147072, 86147584)      biasRow u16[256]
    // [86147584, 86163968)      w_upB u16 (128*64)
    u16* i2sP = (u16*)ws;
    u16* hh16 = (u16*)(ws + 69206016);
    float* Wg = (float*)(ws + 85983232);
    float* Wc = (float*)(ws + 86114304);
    u16* biasRow = (u16*)(ws + 86147072);
    u16* w_upB = (u16*)(ws + 86147584);

    hipLaunchKernelGGL(repack_w, dim3(193), dim3(256), 0, stream, w_s2s, w_c2c,
                       b_i2s, b_s2s, w_up, Wg, Wc, biasRow, w_upB);
    hipLaunchKernelGGL(i2s_kernel, dim3(2048), dim3(256), 0, stream, inputs,
                       w_i2s, b_i2s, b_s2s, (const u32*)biasRow, (u32*)i2sP);
    hipLaunchKernelGGL(scan_kernel, dim3(32), dim3(512), 0, stream, i2sP, Wg,
                       Wc, b_c2c, hh16);
    hipLaunchKernelGGL(up_kernel, dim3(2048), dim3(256), 0, stream, hh16,
                       w_upB, b_up, out);
}

// Round 6
// 436.014 us; speedup vs baseline: 1.2974x; 1.0199x over previous
//
#include <hip/hip_runtime.h>
#include <cstdint>
#include <cstddef>

// DiagonalLSTM B=32,C=64,H=64,W=64,h=64,4h=256,NW=127 — v10.
// v10 = v9 with scan's c2c made WAVE-LOCAL (own-tile redundant c2c):
// each wave computes cc for its own rows via 32 MFMAs (4x redundancy across
// nq-waves) with A-rows rotated so the needed value lands in reg 0:
//   crow = 16*mt + ((m15&12) | ((m15+nq)&3))  =>  accC[nb][0] = cc(p2, k)
// (derived from the verified publish-path mapping + linearity in A).
// This removes sCCm, the publish/read exchange, and BARRIER-1 — one
// __syncthreads per step. Step is fused per-mi to halve acc liveness.
// v9 features kept: deferred hh16 stores, IV prefetch -> MFMA acc init.

typedef unsigned int u32;
typedef unsigned short u16;
typedef __bf16 bf16x8 __attribute__((ext_vector_type(8)));
typedef float f32x4 __attribute__((ext_vector_type(4)));

#define NSTEP 127
#define MFMA(a, b, c) __builtin_amdgcn_mfma_f32_16x16x32_bf16(a, b, c, 0, 0, 0)
#define LOG2E 1.4426950408889634f
#define SCL (-1.4426950408889634f)
#define T2L 2.8853900817779268f
#define RHO(r) ((((r) ^ ((r) >> 3))) & 7)

static __device__ __forceinline__ u16 f2bf(float f) {
    u32 u = __builtin_bit_cast(u32, f);
    u32 r = u + 0x7FFFu + ((u >> 16) & 1u);
    return (u16)(r >> 16);
}
static __device__ __forceinline__ u32 pack2(float a, float b) {
    return (u32)f2bf(a) | ((u32)f2bf(b) << 16);
}
static __device__ __forceinline__ float lo2f(u32 u) {
    return __builtin_bit_cast(float, u << 16);
}
static __device__ __forceinline__ float hi2f(u32 u) {
    return __builtin_bit_cast(float, u & 0xFFFF0000u);
}
static __device__ __forceinline__ float sigm2(float y) {  // y pre-scaled by -log2e
    return __builtin_amdgcn_rcpf(1.f + __builtin_amdgcn_exp2f(y));
}
static __device__ __forceinline__ float tanh_fast(float x) {
    float r = __builtin_amdgcn_rcpf(1.f + __builtin_amdgcn_exp2f(x * T2L));
    return __builtin_fmaf(-2.f, r, 1.f);
}

// ---------------- K0: weight repack ----------------
__global__ __launch_bounds__(256) void repack_w(
    const float* __restrict__ w_s2s, const float* __restrict__ w_c2c,
    const float* __restrict__ bi, const float* __restrict__ bs,
    const float* __restrict__ w_up, float* __restrict__ Wg,
    float* __restrict__ Wc, u16* __restrict__ biasRow,
    u16* __restrict__ w_upB) {
    int idx = blockIdx.x * 256 + threadIdx.x;
    if (idx < 32768) {
        int o = idx >> 7, kk = idx & 127, half = kk >> 6, k = kk & 63;
        Wg[idx] = SCL * w_s2s[(o * 64 + k) * 2 + half];
        return;
    }
    int j = idx - 32768;
    if (j < 8192) {
        int o = j >> 7, kk = j & 127, half = kk >> 6, k = kk & 63;
        Wc[j] = w_c2c[(o * 64 + k) * 2 + half];
        return;
    }
    j -= 8192;
    if (j < 256) {
        int m15 = j >> 4, nq = (j >> 2) & 3, nb = j & 3;
        int o = 64 * nq + 16 * nb + m15;
        biasRow[j] = f2bf(SCL * (bi[o] + bs[o]));
        return;
    }
    j -= 256;
    if (j < 8192) w_upB[j] = f2bf(w_up[j]);
}

// ---------------- K1: i2s conv via MFMA (unchanged from v8/v9) ----------
__global__ __launch_bounds__(256, 2) void i2s_kernel(
    const float* __restrict__ in, const float* __restrict__ w_i2s,
    const float* __restrict__ bi, const float* __restrict__ bs,
    const u32* __restrict__ biasU32, u32* __restrict__ out_u32) {
    const int bid = blockIdx.x;
    const int b = bid >> 6, r = bid & 63;
    const int tid = threadIdx.x;
    const int lane = tid & 63;
    const int wv = __builtin_amdgcn_readfirstlane(tid >> 6);
    const int m15 = lane & 15, g4 = lane >> 4;

    __shared__ __align__(16) u32 sT[64 * 129];  // u16 [w 64][o'' 256]
    __shared__ __align__(16) u32 Xt[64 * 32];   // bf16 [w 64][c 64], swizzled
    char* XtB = (char*)Xt;

    {
        const int w = tid & 63, cp = tid >> 6;
        const float* xp = in + (size_t)b * 262144 + r * 64 + w;
#pragma unroll
        for (int pass = 0; pass < 8; pass++) {
            int c = pass * 8 + cp * 2;
            float x0 = xp[(size_t)c * 4096];
            float x1 = xp[(size_t)(c + 1) * 4096];
            *(u32*)(XtB + ((w * 128 + c * 2) ^ ((w & 7) << 4))) = pack2(x0, x1);
        }
    }

    bf16x8 Af[4][2];
#pragma unroll
    for (int m = 0; m < 4; m++)
#pragma unroll
        for (int kt = 0; kt < 2; kt++) {
            const float* p =
                w_i2s + (wv * 64 + m * 16 + m15) * 64 + kt * 32 + g4 * 8;
            bf16x8 f;
#pragma unroll
            for (int j = 0; j < 8; j++) f[j] = (__bf16)p[j];
            Af[m][kt] = f;
        }
    float bias[4][4];
#pragma unroll
    for (int m = 0; m < 4; m++)
#pragma unroll
        for (int reg = 0; reg < 4; reg++) {
            int o = wv * 64 + m * 16 + 4 * g4 + reg;
            bias[m][reg] = bi[o] + bs[o];
        }

    __syncthreads();

    f32x4 acc[4][4] = {};
#pragma unroll
    for (int nt = 0; nt < 4; nt++) {
        const int w = nt * 16 + m15;
        bf16x8 Bf[2];
#pragma unroll
        for (int kt = 0; kt < 2; kt++)
            Bf[kt] = __builtin_bit_cast(
                bf16x8, *(const uint4*)(XtB + ((w * 128 + kt * 64 + g4 * 16) ^
                                               ((w & 7) << 4))));
#pragma unroll
        for (int m = 0; m < 4; m++)
#pragma unroll
            for (int kt = 0; kt < 2; kt++)
                acc[m][nt] = MFMA(Af[m][kt], Bf[kt], acc[m][nt]);
    }

#pragma unroll
    for (int nt = 0; nt < 4; nt++) {
        const int w = nt * 16 + m15;
#pragma unroll
        for (int reg = 0; reg < 4; reg++)
#pragma unroll
            for (int mp = 0; mp < 2; mp++) {
                float v0 = SCL * (acc[2 * mp][nt][reg] + bias[2 * mp][reg]);
                float v1 =
                    SCL * (acc[2 * mp + 1][nt][reg] + bias[2 * mp + 1][reg]);
                sT[w * 129 + (4 * g4 + reg) * 8 + wv * 2 + mp] = pack2(v0, v1);
            }
    }
    __syncthreads();

    const size_t base = ((size_t)(b * 64 + r) * 66 + 1) * 128;
#pragma unroll
    for (int loop = 0; loop < 32; loop++) {
        int idx = loop * 256 + tid;
        int w = idx >> 7, cu = idx & 127;
        out_u32[base + idx] = sT[w * 129 + cu];
    }
    if (tid < 128) {
        u32 v = biasU32[tid];
        out_u32[base - 128 + tid] = v;
        out_u32[base + 8192 + tid] = v;
    }
}

// ---------------- K2: MFMA scan v10 ----------------
// 32 blocks x 512 threads (8 waves). LDS sM bytes: [0,8192) H par0;
// [8192,16384) H par1; [16384,32768) C par0/par1; ZH0@32768 ZC0@32896
// ZH1@40960 ZC1@41088. All addrs XOR 8192 per step; RHO chunk swizzle.
// v10: own-tile c2c (reg0 via rotated A rows), ONE barrier per step.
__global__ __launch_bounds__(512, 2) void scan_kernel(
    const u16* __restrict__ i2sP, const float* __restrict__ Wg,
    const float* __restrict__ Wc, const float* __restrict__ b_c2c,
    u16* __restrict__ hh16) {
    const int b = blockIdx.x;
    const int tid = threadIdx.x;
    const int lane = tid & 63;
    const int wv = __builtin_amdgcn_readfirstlane(tid >> 6);
    const int mh = wv >> 2, nq = wv & 3;
    const int m15 = lane & 15, g4 = lane >> 4;

    __shared__ __align__(16) u32 sM[10304];  // 41216 B
    char* smB = (char*)sM;

    for (int i = tid; i < 10304; i += 512) sM[i] = 0;

    // ---- VGPR-resident weights ----
    bf16x8 BW[4][4];
    float bcc[4];
#pragma unroll
    for (int nb = 0; nb < 4; nb++) {
        int o = 64 * nq + 16 * nb + m15;
        bcc[nb] = b_c2c[16 * nb + m15];
#pragma unroll
        for (int kt = 0; kt < 4; kt++) {
            const float* p = Wg + o * 128 + kt * 32 + g4 * 8;
            bf16x8 f;
#pragma unroll
            for (int j = 0; j < 8; j++) f[j] = (__bf16)p[j];
            BW[nb][kt] = f;
        }
    }
    bf16x8 BC[4][4];  // all 4 chan-tiles (own-tile c2c needs every nb)
#pragma unroll
    for (int nb = 0; nb < 4; nb++) {
        int o2 = 16 * nb + m15;
#pragma unroll
        for (int kt = 0; kt < 4; kt++) {
            const float* p = Wc + o2 * 128 + kt * 32 + g4 * 8;
            bf16x8 f;
#pragma unroll
            for (int j = 0; j < 8; j++) f[j] = (__bf16)p[j];
            BC[nb][kt] = f;
        }
    }

    // ---- precomputed addresses ----
    int aG[2][4], aC[2][4], wOff[2][4], bOffB[2][4];
#pragma unroll
    for (int mi = 0; mi < 2; mi++) {
        int mt = 2 * mh + mi;
#pragma unroll
        for (int kt = 0; kt < 4; kt++) {
            int P = 16 * (m15 & 3) + 4 * mt + (m15 >> 2);
            int phys = P + (kt >> 1) - 1;
            int chunk = (kt & 1) * 4 + g4;
            aG[mi][kt] = (phys < 0) ? (32768 + chunk * 16)
                                    : (phys * 128 + ((chunk ^ RHO(phys)) * 16));
            // own-tile c2c: rotated rows so reg 0 = row 4g4+nq of the tile
            int crow = 16 * mt + ((m15 & 12) | ((m15 + nq) & 3));
            int cphys = crow + (kt >> 1) - 1;
            aC[mi][kt] = (cphys < 0)
                             ? (32896 + chunk * 16)
                             : (16384 + cphys * 128 +
                                ((chunk ^ RHO(cphys)) * 16));
        }
        int p2 = 16 * mt + 4 * g4 + nq;
#pragma unroll
        for (int nb = 0; nb < 4; nb++) {
            int k = 16 * nb + m15;
            wOff[mi][nb] =
                8192 + p2 * 128 + (((k >> 3) ^ RHO(p2)) * 16) + (k & 7) * 2;
            int prerow = 16 * nb + 4 * mt + g4;  // nb doubles as gate idx r
            bOffB[mi][nb] = (prerow * 66 + 1) * 512 + 32 * m15 + 8 * nq;
        }
    }

    const char* i2sB = (const char*)i2sP + (size_t)b * (64 * 66 * 512);
    u16* hp16[2];
    int p2s[2];
#pragma unroll
    for (int mi = 0; mi < 2; mi++) {
        int p2 = 16 * (2 * mh + mi) + 4 * g4 + nq;
        p2s[mi] = p2;
        hp16[mi] = hh16 + (size_t)b * 262144 + p2 * 4032 + m15;
    }

    // ---- initial IV load (t=0) ----
    uint2 IV[2][4];
#pragma unroll
    for (int mi = 0; mi < 2; mi++) {
        int mt = 2 * mh + mi;
#pragma unroll
        for (int r = 0; r < 4; r++) {
            int prerow = 16 * r + 4 * mt + g4;
            int w = min(max(0 - prerow, -1), 64);
            IV[mi][r] = *(const uint2*)(i2sB + (bOffB[mi][r] + (w << 9)));
        }
    }

    // ---- deferred-store carry state ----
    u16 hbKeep[2][4];
    u16* hpPrev[2];
    bool vstPrev[2];
#pragma unroll
    for (int mi = 0; mi < 2; mi++) {
        vstPrev[mi] = false;
        hpPrev[mi] = hp16[mi];
    }

    __syncthreads();

    for (int t = 0; t < NSTEP; t++) {
        // ---- deferred hh16 stores from step t-1 ----
#pragma unroll
        for (int mi = 0; mi < 2; mi++)
            if (vstPrev[mi]) {
#pragma unroll
                for (int nb = 0; nb < 4; nb++)
                    hpPrev[mi][nb * 16] = hbKeep[mi][nb];
            }

        // ---- per-mi fused: prefetch | acc-init+gates | c2c | LSTM+writes ----
#pragma unroll
        for (int mi = 0; mi < 2; mi++) {
            int mt = 2 * mh + mi;

            // prefetch IV for step t+1 into temporaries
            uint2 tn[4];
#pragma unroll
            for (int r = 0; r < 4; r++) {
                int prerow = 16 * r + 4 * mt + g4;
                int w = min(max(t + 1 - prerow, -1), 64);
                tn[r] = *(const uint2*)(i2sB + (bOffB[mi][r] + (w << 9)));
            }

            // gate MFMAs, acc initialized from current IV
            f32x4 accG[4];
#pragma unroll
            for (int r = 0; r < 4; r++) {
                accG[0][r] = lo2f(IV[mi][r].x);
                accG[1][r] = hi2f(IV[mi][r].x);
                accG[2][r] = lo2f(IV[mi][r].y);
                accG[3][r] = hi2f(IV[mi][r].y);
            }
            bf16x8 Ag[4];
#pragma unroll
            for (int kt = 0; kt < 4; kt++)
                Ag[kt] = __builtin_bit_cast(bf16x8,
                                            *(const uint4*)(smB + aG[mi][kt]));
#pragma unroll
            for (int nb = 0; nb < 4; nb++)
#pragma unroll
                for (int kt = 0; kt < 4; kt++)
                    accG[nb] = MFMA(Ag[kt], BW[nb][kt], accG[nb]);

            // own-tile c2c MFMAs (need only reg 0 of each acc)
            f32x4 accC[4] = {};
            {
                bf16x8 Ac[4];
#pragma unroll
                for (int kt = 0; kt < 4; kt++)
                    Ac[kt] = __builtin_bit_cast(
                        bf16x8, *(const uint4*)(smB + aC[mi][kt]));
#pragma unroll
                for (int nb = 0; nb < 4; nb++)
#pragma unroll
                    for (int kt = 0; kt < 4; kt++)
                        accC[nb] = MFMA(Ac[kt], BC[nb][kt], accC[nb]);
            }

            // LSTM update + LDS writes (par^1); capture hb for deferred store
            int p2 = p2s[mi];
            bool vst = (u32)(t - p2) < 64u;
#pragma unroll
            for (int nb = 0; nb < 4; nb++) {
                float cc = accC[nb][0] + bcc[nb];
                float si = sigm2(accG[nb][0]);
                float sg = sigm2(accG[nb][1]);
                float sf = sigm2(accG[nb][2]);
                float so = sigm2(accG[nb][3]);
                float c1 = __builtin_fmaf(sf, cc, si * sg);
                float h1 = so * tanh_fast(c1);
                u16 hb = f2bf(h1);
                *(u16*)(smB + wOff[mi][nb]) = hb;
                *(u16*)(smB + wOff[mi][nb] + 16384) = f2bf(c1);
                hbKeep[mi][nb] = hb;
            }
            vstPrev[mi] = vst;
            hpPrev[mi] = hp16[mi];
            hp16[mi] += 64;

            // rotate prefetched IV
#pragma unroll
            for (int r = 0; r < 4; r++) IV[mi][r] = tn[r];
        }

        __syncthreads();  // single barrier per step

        // ---- toggle parity ----
#pragma unroll
        for (int mi = 0; mi < 2; mi++) {
#pragma unroll
            for (int kt = 0; kt < 4; kt++) {
                aG[mi][kt] ^= 8192;
                aC[mi][kt] ^= 8192;
            }
#pragma unroll
            for (int nb = 0; nb < 4; nb++) wOff[mi][nb] ^= 8192;
        }
    }

    // ---- epilogue: final deferred stores ----
#pragma unroll
    for (int mi = 0; mi < 2; mi++)
        if (vstPrev[mi]) {
#pragma unroll
            for (int nb = 0; nb < 4; nb++)
                hpPrev[mi][nb * 16] = hbKeep[mi][nb];
        }
}

// ---------------- K3: up-projection via MFMA (unchanged) ----------------
__global__ __launch_bounds__(256) void up_kernel(
    const u16* __restrict__ hh16, const u16* __restrict__ w_upB,
    const float* __restrict__ b_up, float* __restrict__ out) {
    const int bid = blockIdx.x;
    const int b = bid >> 6, r = bid & 63;
    const int lane = threadIdx.x & 63;
    const int wt = __builtin_amdgcn_readfirstlane(threadIdx.x >> 6);
    const int m15 = lane & 15, g4 = lane >> 4;

    const u16* hh_b = hh16 + (size_t)b * 262144;
    const int w = 16 * wt + m15;

    bf16x8 Bf[2];
#pragma unroll
    for (int kt = 0; kt < 2; kt++)
        Bf[kt] = __builtin_bit_cast(
            bf16x8,
            *(const uint4*)(hh_b + (r * 4096 + w * 64 + kt * 32 + g4 * 8)));

    f32x4 acc[8] = {};
#pragma unroll
    for (int nt = 0; nt < 8; nt++) {
#pragma unroll
        for (int kt = 0; kt < 2; kt++) {
            bf16x8 Af = __builtin_bit_cast(
                bf16x8, *(const uint4*)(w_upB + ((16 * nt + m15) * 64 +
                                                 kt * 32 + g4 * 8)));
            acc[nt] = MFMA(Af, Bf[kt], acc[nt]);
        }
    }
    float* outb = out + (size_t)b * 524288;
#pragma unroll
    for (int nt = 0; nt < 8; nt++) {
#pragma unroll
        for (int rr = 0; rr < 4; rr++) {
            int o2 = 16 * nt + 4 * g4 + rr;
            outb[(size_t)o2 * 4096 + r * 64 + w] = acc[nt][rr] + b_up[o2];
        }
    }
}

extern "C" void kernel_launch(void* const* d_in, const int* in_sizes, int n_in,
                              void* d_out, int out_size, void* d_ws,
                              size_t ws_size, hipStream_t stream) {
    (void)in_sizes; (void)n_in; (void)out_size; (void)ws_size;
    const float* inputs = (const float*)d_in[0];
    const float* w_i2s = (const float*)d_in[1];
    const float* b_i2s = (const float*)d_in[2];
    const float* w_s2s = (const float*)d_in[3];
    const float* b_s2s = (const float*)d_in[4];
    const float* w_c2c = (const float*)d_in[5];
    const float* b_c2c = (const float*)d_in[6];
    const float* w_up = (const float*)d_in[7];
    const float* b_up = (const float*)d_in[8];
    float* out = (float*)d_out;
    char* ws = (char*)d_ws;

    // workspace layout (bytes):
    // [0, 69206016)             i2sP u16 (32*64*66*256, bias-padded slots)
    // [69206016, 85983232)      hh16 u16 (32*64*64*64)
    // [85983232, 86114304)      Wg fp32 (256*128, scaled -log2e)
    // [86114304, 86147072)      Wc fp32 (64*128)
    // [86147072, 86147584)      biasRow u16[256]
    // [86147584, 86163968)      w_upB u16 (128*64)
    u16* i2sP = (u16*)ws;
    u16* hh16 = (u16*)(ws + 69206016);
    float* Wg = (float*)(ws + 85983232);
    float* Wc = (float*)(ws + 86114304);
    u16* biasRow = (u16*)(ws + 86147072);
    u16* w_upB = (u16*)(ws + 86147584);

    hipLaunchKernelGGL(repack_w, dim3(193), dim3(256), 0, stream, w_s2s, w_c2c,
                       b_i2s, b_s2s, w_up, Wg, Wc, biasRow, w_upB);
    hipLaunchKernelGGL(i2s_kernel, dim3(2048), dim3(256), 0, stream, inputs,
                       w_i2s, b_i2s, b_s2s, (const u32*)biasRow, (u32*)i2sP);
    hipLaunchKernelGGL(scan_kernel, dim3(32), dim3(512), 0, stream, i2sP, Wg,
                       Wc, b_c2c, hh16);
    hipLaunchKernelGGL(up_kernel, dim3(2048), dim3(256), 0, stream, hh16,
                       w_upB, b_up, out);
}

// Round 7
// 427.197 us; speedup vs baseline: 1.3241x; 1.0206x over previous
//
#include <hip/hip_runtime.h>
#include <cstdint>
#include <cstddef>

// DiagonalLSTM B=32,C=64,H=64,W=64,h=64,4h=256,NW=127 — v11.
// v11 = v10 + ONE change: all f32->bf16 pair packing via v_cvt_pk_bf16_f32
// (single VOP3, RNE — bit-identical to the manual f2bf) in scan stage-B and
// in K1 staging/epilogue. Counters show the scan is ISSUE-BOUND
// (per-active-CU VALUBusy 63% + MfmaUtil 35% ~= 98%); manual f2bf is ~5 VALU
// ops per value, 16 values/thread/step in scan. This is also the final v5-NaN
// bisect: barrier (v7) and prefetch (v9/v10) are cleared; if v11 passes,
// unroll-2 was the v5 bug; if v11 NaNs, cvt_pk is convicted.

typedef unsigned int u32;
typedef unsigned short u16;
typedef __bf16 bf16x8 __attribute__((ext_vector_type(8)));
typedef float f32x4 __attribute__((ext_vector_type(4)));

#define NSTEP 127
#define MFMA(a, b, c) __builtin_amdgcn_mfma_f32_16x16x32_bf16(a, b, c, 0, 0, 0)
#define LOG2E 1.4426950408889634f
#define SCL (-1.4426950408889634f)
#define T2L 2.8853900817779268f
#define RHO(r) ((((r) ^ ((r) >> 3))) & 7)

static __device__ __forceinline__ u16 f2bf(float f) {
    u32 u = __builtin_bit_cast(u32, f);
    u32 r = u + 0x7FFFu + ((u >> 16) & 1u);
    return (u16)(r >> 16);
}
static __device__ __forceinline__ u32 cvt_pk_bf16(float a, float b) {
    // dst.lo = bf16(a), dst.hi = bf16(b); RNE — bit-identical to f2bf.
    u32 d;
    asm("v_cvt_pk_bf16_f32 %0, %1, %2" : "=v"(d) : "v"(a), "v"(b));
    return d;
}
static __device__ __forceinline__ float lo2f(u32 u) {
    return __builtin_bit_cast(float, u << 16);
}
static __device__ __forceinline__ float hi2f(u32 u) {
    return __builtin_bit_cast(float, u & 0xFFFF0000u);
}
static __device__ __forceinline__ float sigm2(float y) {  // y pre-scaled by -log2e
    return __builtin_amdgcn_rcpf(1.f + __builtin_amdgcn_exp2f(y));
}
static __device__ __forceinline__ float tanh_fast(float x) {
    float r = __builtin_amdgcn_rcpf(1.f + __builtin_amdgcn_exp2f(x * T2L));
    return __builtin_fmaf(-2.f, r, 1.f);
}

// ---------------- K0: weight repack ----------------
__global__ __launch_bounds__(256) void repack_w(
    const float* __restrict__ w_s2s, const float* __restrict__ w_c2c,
    const float* __restrict__ bi, const float* __restrict__ bs,
    const float* __restrict__ w_up, float* __restrict__ Wg,
    float* __restrict__ Wc, u16* __restrict__ biasRow,
    u16* __restrict__ w_upB) {
    int idx = blockIdx.x * 256 + threadIdx.x;
    if (idx < 32768) {
        int o = idx >> 7, kk = idx & 127, half = kk >> 6, k = kk & 63;
        Wg[idx] = SCL * w_s2s[(o * 64 + k) * 2 + half];
        return;
    }
    int j = idx - 32768;
    if (j < 8192) {
        int o = j >> 7, kk = j & 127, half = kk >> 6, k = kk & 63;
        Wc[j] = w_c2c[(o * 64 + k) * 2 + half];
        return;
    }
    j -= 8192;
    if (j < 256) {
        int m15 = j >> 4, nq = (j >> 2) & 3, nb = j & 3;
        int o = 64 * nq + 16 * nb + m15;
        biasRow[j] = f2bf(SCL * (bi[o] + bs[o]));
        return;
    }
    j -= 256;
    if (j < 8192) w_upB[j] = f2bf(w_up[j]);
}

// ---------------- K1: i2s conv via MFMA (cvt_pk packing) ----------
__global__ __launch_bounds__(256, 2) void i2s_kernel(
    const float* __restrict__ in, const float* __restrict__ w_i2s,
    const float* __restrict__ bi, const float* __restrict__ bs,
    const u32* __restrict__ biasU32, u32* __restrict__ out_u32) {
    const int bid = blockIdx.x;
    const int b = bid >> 6, r = bid & 63;
    const int tid = threadIdx.x;
    const int lane = tid & 63;
    const int wv = __builtin_amdgcn_readfirstlane(tid >> 6);
    const int m15 = lane & 15, g4 = lane >> 4;

    __shared__ __align__(16) u32 sT[64 * 129];  // u16 [w 64][o'' 256]
    __shared__ __align__(16) u32 Xt[64 * 32];   // bf16 [w 64][c 64], swizzled
    char* XtB = (char*)Xt;

    {
        const int w = tid & 63, cp = tid >> 6;
        const float* xp = in + (size_t)b * 262144 + r * 64 + w;
#pragma unroll
        for (int pass = 0; pass < 8; pass++) {
            int c = pass * 8 + cp * 2;
            float x0 = xp[(size_t)c * 4096];
            float x1 = xp[(size_t)(c + 1) * 4096];
            *(u32*)(XtB + ((w * 128 + c * 2) ^ ((w & 7) << 4))) =
                cvt_pk_bf16(x0, x1);
        }
    }

    bf16x8 Af[4][2];
#pragma unroll
    for (int m = 0; m < 4; m++)
#pragma unroll
        for (int kt = 0; kt < 2; kt++) {
            const float* p =
                w_i2s + (wv * 64 + m * 16 + m15) * 64 + kt * 32 + g4 * 8;
            bf16x8 f;
#pragma unroll
            for (int j = 0; j < 8; j++) f[j] = (__bf16)p[j];
            Af[m][kt] = f;
        }
    float bias[4][4];
#pragma unroll
    for (int m = 0; m < 4; m++)
#pragma unroll
        for (int reg = 0; reg < 4; reg++) {
            int o = wv * 64 + m * 16 + 4 * g4 + reg;
            bias[m][reg] = bi[o] + bs[o];
        }

    __syncthreads();

    f32x4 acc[4][4] = {};
#pragma unroll
    for (int nt = 0; nt < 4; nt++) {
        const int w = nt * 16 + m15;
        bf16x8 Bf[2];
#pragma unroll
        for (int kt = 0; kt < 2; kt++)
            Bf[kt] = __builtin_bit_cast(
                bf16x8, *(const uint4*)(XtB + ((w * 128 + kt * 64 + g4 * 16) ^
                                               ((w & 7) << 4))));
#pragma unroll
        for (int m = 0; m < 4; m++)
#pragma unroll
            for (int kt = 0; kt < 2; kt++)
                acc[m][nt] = MFMA(Af[m][kt], Bf[kt], acc[m][nt]);
    }

#pragma unroll
    for (int nt = 0; nt < 4; nt++) {
        const int w = nt * 16 + m15;
#pragma unroll
        for (int reg = 0; reg < 4; reg++)
#pragma unroll
            for (int mp = 0; mp < 2; mp++) {
                float v0 = SCL * (acc[2 * mp][nt][reg] + bias[2 * mp][reg]);
                float v1 =
                    SCL * (acc[2 * mp + 1][nt][reg] + bias[2 * mp + 1][reg]);
                sT[w * 129 + (4 * g4 + reg) * 8 + wv * 2 + mp] =
                    cvt_pk_bf16(v0, v1);
            }
    }
    __syncthreads();

    const size_t base = ((size_t)(b * 64 + r) * 66 + 1) * 128;
#pragma unroll
    for (int loop = 0; loop < 32; loop++) {
        int idx = loop * 256 + tid;
        int w = idx >> 7, cu = idx & 127;
        out_u32[base + idx] = sT[w * 129 + cu];
    }
    if (tid < 128) {
        u32 v = biasU32[tid];
        out_u32[base - 128 + tid] = v;
        out_u32[base + 8192 + tid] = v;
    }
}

// ---------------- K2: MFMA scan v11 ----------------
// 32 blocks x 512 threads (8 waves). LDS sM bytes: [0,8192) H par0;
// [8192,16384) H par1; [16384,32768) C par0/par1; ZH0@32768 ZC0@32896
// ZH1@40960 ZC1@41088. All addrs XOR 8192 per step; RHO chunk swizzle.
// v10 structure: own-tile c2c (reg0 via rotated A rows), ONE barrier/step,
// deferred hh16 stores, IV prefetch -> MFMA acc init.
// v11: h/c packed with one v_cvt_pk_bf16_f32 per (mi,nb).
__global__ __launch_bounds__(512, 2) void scan_kernel(
    const u16* __restrict__ i2sP, const float* __restrict__ Wg,
    const float* __restrict__ Wc, const float* __restrict__ b_c2c,
    u16* __restrict__ hh16) {
    const int b = blockIdx.x;
    const int tid = threadIdx.x;
    const int lane = tid & 63;
    const int wv = __builtin_amdgcn_readfirstlane(tid >> 6);
    const int mh = wv >> 2, nq = wv & 3;
    const int m15 = lane & 15, g4 = lane >> 4;

    __shared__ __align__(16) u32 sM[10304];  // 41216 B
    char* smB = (char*)sM;

    for (int i = tid; i < 10304; i += 512) sM[i] = 0;

    // ---- VGPR-resident weights ----
    bf16x8 BW[4][4];
    float bcc[4];
#pragma unroll
    for (int nb = 0; nb < 4; nb++) {
        int o = 64 * nq + 16 * nb + m15;
        bcc[nb] = b_c2c[16 * nb + m15];
#pragma unroll
        for (int kt = 0; kt < 4; kt++) {
            const float* p = Wg + o * 128 + kt * 32 + g4 * 8;
            bf16x8 f;
#pragma unroll
            for (int j = 0; j < 8; j++) f[j] = (__bf16)p[j];
            BW[nb][kt] = f;
        }
    }
    bf16x8 BC[4][4];  // all 4 chan-tiles (own-tile c2c needs every nb)
#pragma unroll
    for (int nb = 0; nb < 4; nb++) {
        int o2 = 16 * nb + m15;
#pragma unroll
        for (int kt = 0; kt < 4; kt++) {
            const float* p = Wc + o2 * 128 + kt * 32 + g4 * 8;
            bf16x8 f;
#pragma unroll
            for (int j = 0; j < 8; j++) f[j] = (__bf16)p[j];
            BC[nb][kt] = f;
        }
    }

    // ---- precomputed addresses ----
    int aG[2][4], aC[2][4], wOff[2][4], bOffB[2][4];
#pragma unroll
    for (int mi = 0; mi < 2; mi++) {
        int mt = 2 * mh + mi;
#pragma unroll
        for (int kt = 0; kt < 4; kt++) {
            int P = 16 * (m15 & 3) + 4 * mt + (m15 >> 2);
            int phys = P + (kt >> 1) - 1;
            int chunk = (kt & 1) * 4 + g4;
            aG[mi][kt] = (phys < 0) ? (32768 + chunk * 16)
                                    : (phys * 128 + ((chunk ^ RHO(phys)) * 16));
            // own-tile c2c: rotated rows so reg 0 = row 4g4+nq of the tile
            int crow = 16 * mt + ((m15 & 12) | ((m15 + nq) & 3));
            int cphys = crow + (kt >> 1) - 1;
            aC[mi][kt] = (cphys < 0)
                             ? (32896 + chunk * 16)
                             : (16384 + cphys * 128 +
                                ((chunk ^ RHO(cphys)) * 16));
        }
        int p2 = 16 * mt + 4 * g4 + nq;
#pragma unroll
        for (int nb = 0; nb < 4; nb++) {
            int k = 16 * nb + m15;
            wOff[mi][nb] =
                8192 + p2 * 128 + (((k >> 3) ^ RHO(p2)) * 16) + (k & 7) * 2;
            int prerow = 16 * nb + 4 * mt + g4;  // nb doubles as gate idx r
            bOffB[mi][nb] = (prerow * 66 + 1) * 512 + 32 * m15 + 8 * nq;
        }
    }

    const char* i2sB = (const char*)i2sP + (size_t)b * (64 * 66 * 512);
    u16* hp16[2];
    int p2s[2];
#pragma unroll
    for (int mi = 0; mi < 2; mi++) {
        int p2 = 16 * (2 * mh + mi) + 4 * g4 + nq;
        p2s[mi] = p2;
        hp16[mi] = hh16 + (size_t)b * 262144 + p2 * 4032 + m15;
    }

    // ---- initial IV load (t=0) ----
    uint2 IV[2][4];
#pragma unroll
    for (int mi = 0; mi < 2; mi++) {
        int mt = 2 * mh + mi;
#pragma unroll
        for (int r = 0; r < 4; r++) {
            int prerow = 16 * r + 4 * mt + g4;
            int w = min(max(0 - prerow, -1), 64);
            IV[mi][r] = *(const uint2*)(i2sB + (bOffB[mi][r] + (w << 9)));
        }
    }

    // ---- deferred-store carry state ----
    u16 hbKeep[2][4];
    u16* hpPrev[2];
    bool vstPrev[2];
#pragma unroll
    for (int mi = 0; mi < 2; mi++) {
        vstPrev[mi] = false;
        hpPrev[mi] = hp16[mi];
    }

    __syncthreads();

    for (int t = 0; t < NSTEP; t++) {
        // ---- deferred hh16 stores from step t-1 ----
#pragma unroll
        for (int mi = 0; mi < 2; mi++)
            if (vstPrev[mi]) {
#pragma unroll
                for (int nb = 0; nb < 4; nb++)
                    hpPrev[mi][nb * 16] = hbKeep[mi][nb];
            }

        // ---- per-mi fused: prefetch | acc-init+gates | c2c | LSTM+writes ----
#pragma unroll
        for (int mi = 0; mi < 2; mi++) {
            int mt = 2 * mh + mi;

            // prefetch IV for step t+1 into temporaries
            uint2 tn[4];
#pragma unroll
            for (int r = 0; r < 4; r++) {
                int prerow = 16 * r + 4 * mt + g4;
                int w = min(max(t + 1 - prerow, -1), 64);
                tn[r] = *(const uint2*)(i2sB + (bOffB[mi][r] + (w << 9)));
            }

            // gate MFMAs, acc initialized from current IV
            f32x4 accG[4];
#pragma unroll
            for (int r = 0; r < 4; r++) {
                accG[0][r] = lo2f(IV[mi][r].x);
                accG[1][r] = hi2f(IV[mi][r].x);
                accG[2][r] = lo2f(IV[mi][r].y);
                accG[3][r] = hi2f(IV[mi][r].y);
            }
            bf16x8 Ag[4];
#pragma unroll
            for (int kt = 0; kt < 4; kt++)
                Ag[kt] = __builtin_bit_cast(bf16x8,
                                            *(const uint4*)(smB + aG[mi][kt]));
#pragma unroll
            for (int nb = 0; nb < 4; nb++)
#pragma unroll
                for (int kt = 0; kt < 4; kt++)
                    accG[nb] = MFMA(Ag[kt], BW[nb][kt], accG[nb]);

            // own-tile c2c MFMAs (need only reg 0 of each acc)
            f32x4 accC[4] = {};
            {
                bf16x8 Ac[4];
#pragma unroll
                for (int kt = 0; kt < 4; kt++)
                    Ac[kt] = __builtin_bit_cast(
                        bf16x8, *(const uint4*)(smB + aC[mi][kt]));
#pragma unroll
                for (int nb = 0; nb < 4; nb++)
#pragma unroll
                    for (int kt = 0; kt < 4; kt++)
                        accC[nb] = MFMA(Ac[kt], BC[nb][kt], accC[nb]);
            }

            // LSTM update + LDS writes (par^1); capture hb for deferred store
            int p2 = p2s[mi];
            bool vst = (u32)(t - p2) < 64u;
#pragma unroll
            for (int nb = 0; nb < 4; nb++) {
                float cc = accC[nb][0] + bcc[nb];
                float si = sigm2(accG[nb][0]);
                float sg = sigm2(accG[nb][1]);
                float sf = sigm2(accG[nb][2]);
                float so = sigm2(accG[nb][3]);
                float c1 = __builtin_fmaf(sf, cc, si * sg);
                float h1 = so * tanh_fast(c1);
                u32 hc = cvt_pk_bf16(h1, c1);  // lo=bf16(h1), hi=bf16(c1)
                *(u16*)(smB + wOff[mi][nb]) = (u16)hc;
                *(u16*)(smB + wOff[mi][nb] + 16384) = (u16)(hc >> 16);
                hbKeep[mi][nb] = (u16)hc;
            }
            vstPrev[mi] = vst;
            hpPrev[mi] = hp16[mi];
            hp16[mi] += 64;

            // rotate prefetched IV
#pragma unroll
            for (int r = 0; r < 4; r++) IV[mi][r] = tn[r];
        }

        __syncthreads();  // single barrier per step

        // ---- toggle parity ----
#pragma unroll
        for (int mi = 0; mi < 2; mi++) {
#pragma unroll
            for (int kt = 0; kt < 4; kt++) {
                aG[mi][kt] ^= 8192;
                aC[mi][kt] ^= 8192;
            }
#pragma unroll
            for (int nb = 0; nb < 4; nb++) wOff[mi][nb] ^= 8192;
        }
    }

    // ---- epilogue: final deferred stores ----
#pragma unroll
    for (int mi = 0; mi < 2; mi++)
        if (vstPrev[mi]) {
#pragma unroll
            for (int nb = 0; nb < 4; nb++)
                hpPrev[mi][nb * 16] = hbKeep[mi][nb];
        }
}

// ---------------- K3: up-projection via MFMA (unchanged) ----------------
__global__ __launch_bounds__(256) void up_kernel(
    const u16* __restrict__ hh16, const u16* __restrict__ w_upB,
    const float* __restrict__ b_up, float* __restrict__ out) {
    const int bid = blockIdx.x;
    const int b = bid >> 6, r = bid & 63;
    const int lane = threadIdx.x & 63;
    const int wt = __builtin_amdgcn_readfirstlane(threadIdx.x >> 6);
    const int m15 = lane & 15, g4 = lane >> 4;

    const u16* hh_b = hh16 + (size_t)b * 262144;
    const int w = 16 * wt + m15;

    bf16x8 Bf[2];
#pragma unroll
    for (int kt = 0; kt < 2; kt++)
        Bf[kt] = __builtin_bit_cast(
            bf16x8,
            *(const uint4*)(hh_b + (r * 4096 + w * 64 + kt * 32 + g4 * 8)));

    f32x4 acc[8] = {};
#pragma unroll
    for (int nt = 0; nt < 8; nt++) {
#pragma unroll
        for (int kt = 0; kt < 2; kt++) {
            bf16x8 Af = __builtin_bit_cast(
                bf16x8, *(const uint4*)(w_upB + ((16 * nt + m15) * 64 +
                                                 kt * 32 + g4 * 8)));
            acc[nt] = MFMA(Af, Bf[kt], acc[nt]);
        }
    }
    float* outb = out + (size_t)b * 524288;
#pragma unroll
    for (int nt = 0; nt < 8; nt++) {
#pragma unroll
        for (int rr = 0; rr < 4; rr++) {
            int o2 = 16 * nt + 4 * g4 + rr;
            outb[(size_t)o2 * 4096 + r * 64 + w] = acc[nt][rr] + b_up[o2];
        }
    }
}

extern "C" void kernel_launch(void* const* d_in, const int* in_sizes, int n_in,
                              void* d_out, int out_size, void* d_ws,
                              size_t ws_size, hipStream_t stream) {
    (void)in_sizes; (void)n_in; (void)out_size; (void)ws_size;
    const float* inputs = (const float*)d_in[0];
    const float* w_i2s = (const float*)d_in[1];
    const float* b_i2s = (const float*)d_in[2];
    const float* w_s2s = (const float*)d_in[3];
    const float* b_s2s = (const float*)d_in[4];
    const float* w_c2c = (const float*)d_in[5];
    const float* b_c2c = (const float*)d_in[6];
    const float* w_up = (const float*)d_in[7];
    const float* b_up = (const float*)d_in[8];
    float* out = (float*)d_out;
    char* ws = (char*)d_ws;

    // workspace layout (bytes):
    // [0, 69206016)             i2sP u16 (32*64*66*256, bias-padded slots)
    // [69206016, 85983232)      hh16 u16 (32*64*64*64)
    // [85983232, 86114304)      Wg fp32 (256*128, scaled -log2e)
    // [86114304, 86147072)      Wc fp32 (64*128)
    // [86147072, 86147584)      biasRow u16[256]
    // [86147584, 86163968)      w_upB u16 (128*64)
    u16* i2sP = (u16*)ws;
    u16* hh16 = (u16*)(ws + 69206016);
    float* Wg = (float*)(ws + 85983232);
    float* Wc = (float*)(ws + 86114304);
    u16* biasRow = (u16*)(ws + 86147072);
    u16* w_upB = (u16*)(ws + 86147584);

    hipLaunchKernelGGL(repack_w, dim3(193), dim3(256), 0, stream, w_s2s, w_c2c,
                       b_i2s, b_s2s, w_up, Wg, Wc, biasRow, w_upB);
    hipLaunchKernelGGL(i2s_kernel, dim3(2048), dim3(256), 0, stream, inputs,
                       w_i2s, b_i2s, b_s2s, (const u32*)biasRow, (u32*)i2sP);
    hipLaunchKernelGGL(scan_kernel, dim3(32), dim3(512), 0, stream, i2sP, Wg,
                       Wc, b_c2c, hh16);
    hipLaunchKernelGGL(up_kernel, dim3(2048), dim3(256), 0, stream, hh16,
                       w_upB, b_up, out);
}

// Round 8
// 417.891 us; speedup vs baseline: 1.3536x; 1.0223x over previous
//
#include <hip/hip_runtime.h>
#include <cstdint>
#include <cstddef>

// DiagonalLSTM B=32,C=64,H=64,W=64,h=64,4h=256,NW=127 — v12.
// v12 = v11 + LSTM nonlinearity restructured to cut quarter-rate VALU ops
// (the measured bottleneck: VALU pipe ~60% busy per active CU, dominated by
// 5 exp2 + 5 rcp per cell):
//   c1 = [cc*pI*pG + pF] * rcp(pF*pI*pG)      (1 rcp instead of 3)
//   h1 = (E-1) * rcp((1+E)*pO), E=exp2(c1*T2L) (1 rcp instead of 2)
// where pX = 1+exp2(yX), y pre-scaled by -log2e. Algebraically identical.
// Also: IV prefetch offsets walked as u32 (+512/step, min/max clamp) instead
// of recomputed from t. v11 structure otherwise unchanged (own-tile c2c, one
// barrier/step, deferred hh16 stores, IV->acc-init, cvt_pk packing).
// NOTE: unroll-2 on the t-loop is the convicted v5-NaN suspect — do not
// reintroduce without a dedicated bisect.

typedef unsigned int u32;
typedef unsigned short u16;
typedef __bf16 bf16x8 __attribute__((ext_vector_type(8)));
typedef float f32x4 __attribute__((ext_vector_type(4)));

#define NSTEP 127
#define MFMA(a, b, c) __builtin_amdgcn_mfma_f32_16x16x32_bf16(a, b, c, 0, 0, 0)
#define LOG2E 1.4426950408889634f
#define SCL (-1.4426950408889634f)
#define T2L 2.8853900817779268f
#define RHO(r) ((((r) ^ ((r) >> 3))) & 7)

static __device__ __forceinline__ u16 f2bf(float f) {
    u32 u = __builtin_bit_cast(u32, f);
    u32 r = u + 0x7FFFu + ((u >> 16) & 1u);
    return (u16)(r >> 16);
}
static __device__ __forceinline__ u32 cvt_pk_bf16(float a, float b) {
    // dst.lo = bf16(a), dst.hi = bf16(b); RNE — bit-identical to f2bf.
    u32 d;
    asm("v_cvt_pk_bf16_f32 %0, %1, %2" : "=v"(d) : "v"(a), "v"(b));
    return d;
}
static __device__ __forceinline__ float lo2f(u32 u) {
    return __builtin_bit_cast(float, u << 16);
}
static __device__ __forceinline__ float hi2f(u32 u) {
    return __builtin_bit_cast(float, u & 0xFFFF0000u);
}

// ---------------- K0: weight repack ----------------
__global__ __launch_bounds__(256) void repack_w(
    const float* __restrict__ w_s2s, const float* __restrict__ w_c2c,
    const float* __restrict__ bi, const float* __restrict__ bs,
    const float* __restrict__ w_up, float* __restrict__ Wg,
    float* __restrict__ Wc, u16* __restrict__ biasRow,
    u16* __restrict__ w_upB) {
    int idx = blockIdx.x * 256 + threadIdx.x;
    if (idx < 32768) {
        int o = idx >> 7, kk = idx & 127, half = kk >> 6, k = kk & 63;
        Wg[idx] = SCL * w_s2s[(o * 64 + k) * 2 + half];
        return;
    }
    int j = idx - 32768;
    if (j < 8192) {
        int o = j >> 7, kk = j & 127, half = kk >> 6, k = kk & 63;
        Wc[j] = w_c2c[(o * 64 + k) * 2 + half];
        return;
    }
    j -= 8192;
    if (j < 256) {
        int m15 = j >> 4, nq = (j >> 2) & 3, nb = j & 3;
        int o = 64 * nq + 16 * nb + m15;
        biasRow[j] = f2bf(SCL * (bi[o] + bs[o]));
        return;
    }
    j -= 256;
    if (j < 8192) w_upB[j] = f2bf(w_up[j]);
}

// ---------------- K1: i2s conv via MFMA (unchanged from v11) ----------
__global__ __launch_bounds__(256, 2) void i2s_kernel(
    const float* __restrict__ in, const float* __restrict__ w_i2s,
    const float* __restrict__ bi, const float* __restrict__ bs,
    const u32* __restrict__ biasU32, u32* __restrict__ out_u32) {
    const int bid = blockIdx.x;
    const int b = bid >> 6, r = bid & 63;
    const int tid = threadIdx.x;
    const int lane = tid & 63;
    const int wv = __builtin_amdgcn_readfirstlane(tid >> 6);
    const int m15 = lane & 15, g4 = lane >> 4;

    __shared__ __align__(16) u32 sT[64 * 129];  // u16 [w 64][o'' 256]
    __shared__ __align__(16) u32 Xt[64 * 32];   // bf16 [w 64][c 64], swizzled
    char* XtB = (char*)Xt;

    {
        const int w = tid & 63, cp = tid >> 6;
        const float* xp = in + (size_t)b * 262144 + r * 64 + w;
#pragma unroll
        for (int pass = 0; pass < 8; pass++) {
            int c = pass * 8 + cp * 2;
            float x0 = xp[(size_t)c * 4096];
            float x1 = xp[(size_t)(c + 1) * 4096];
            *(u32*)(XtB + ((w * 128 + c * 2) ^ ((w & 7) << 4))) =
                cvt_pk_bf16(x0, x1);
        }
    }

    bf16x8 Af[4][2];
#pragma unroll
    for (int m = 0; m < 4; m++)
#pragma unroll
        for (int kt = 0; kt < 2; kt++) {
            const float* p =
                w_i2s + (wv * 64 + m * 16 + m15) * 64 + kt * 32 + g4 * 8;
            bf16x8 f;
#pragma unroll
            for (int j = 0; j < 8; j++) f[j] = (__bf16)p[j];
            Af[m][kt] = f;
        }
    float bias[4][4];
#pragma unroll
    for (int m = 0; m < 4; m++)
#pragma unroll
        for (int reg = 0; reg < 4; reg++) {
            int o = wv * 64 + m * 16 + 4 * g4 + reg;
            bias[m][reg] = bi[o] + bs[o];
        }

    __syncthreads();

    f32x4 acc[4][4] = {};
#pragma unroll
    for (int nt = 0; nt < 4; nt++) {
        const int w = nt * 16 + m15;
        bf16x8 Bf[2];
#pragma unroll
        for (int kt = 0; kt < 2; kt++)
            Bf[kt] = __builtin_bit_cast(
                bf16x8, *(const uint4*)(XtB + ((w * 128 + kt * 64 + g4 * 16) ^
                                               ((w & 7) << 4))));
#pragma unroll
        for (int m = 0; m < 4; m++)
#pragma unroll
            for (int kt = 0; kt < 2; kt++)
                acc[m][nt] = MFMA(Af[m][kt], Bf[kt], acc[m][nt]);
    }

#pragma unroll
    for (int nt = 0; nt < 4; nt++) {
        const int w = nt * 16 + m15;
#pragma unroll
        for (int reg = 0; reg < 4; reg++)
#pragma unroll
            for (int mp = 0; mp < 2; mp++) {
                float v0 = SCL * (acc[2 * mp][nt][reg] + bias[2 * mp][reg]);
                float v1 =
                    SCL * (acc[2 * mp + 1][nt][reg] + bias[2 * mp + 1][reg]);
                sT[w * 129 + (4 * g4 + reg) * 8 + wv * 2 + mp] =
                    cvt_pk_bf16(v0, v1);
            }
    }
    __syncthreads();

    const size_t base = ((size_t)(b * 64 + r) * 66 + 1) * 128;
#pragma unroll
    for (int loop = 0; loop < 32; loop++) {
        int idx = loop * 256 + tid;
        int w = idx >> 7, cu = idx & 127;
        out_u32[base + idx] = sT[w * 129 + cu];
    }
    if (tid < 128) {
        u32 v = biasU32[tid];
        out_u32[base - 128 + tid] = v;
        out_u32[base + 8192 + tid] = v;
    }
}

// ---------------- K2: MFMA scan v12 ----------------
// 32 blocks x 512 threads (8 waves). LDS sM bytes: [0,8192) H par0;
// [8192,16384) H par1; [16384,32768) C par0/par1; ZH0@32768 ZC0@32896
// ZH1@40960 ZC1@41088. All addrs XOR 8192 per step; RHO chunk swizzle.
// v10/v11 structure + rcp-fused LSTM cell + walked u32 IV offsets.
__global__ __launch_bounds__(512, 2) void scan_kernel(
    const u16* __restrict__ i2sP, const float* __restrict__ Wg,
    const float* __restrict__ Wc, const float* __restrict__ b_c2c,
    u16* __restrict__ hh16) {
    const int b = blockIdx.x;
    const int tid = threadIdx.x;
    const int lane = tid & 63;
    const int wv = __builtin_amdgcn_readfirstlane(tid >> 6);
    const int mh = wv >> 2, nq = wv & 3;
    const int m15 = lane & 15, g4 = lane >> 4;

    __shared__ __align__(16) u32 sM[10304];  // 41216 B
    char* smB = (char*)sM;

    for (int i = tid; i < 10304; i += 512) sM[i] = 0;

    // ---- VGPR-resident weights ----
    bf16x8 BW[4][4];
    float bcc[4];
#pragma unroll
    for (int nb = 0; nb < 4; nb++) {
        int o = 64 * nq + 16 * nb + m15;
        bcc[nb] = b_c2c[16 * nb + m15];
#pragma unroll
        for (int kt = 0; kt < 4; kt++) {
            const float* p = Wg + o * 128 + kt * 32 + g4 * 8;
            bf16x8 f;
#pragma unroll
            for (int j = 0; j < 8; j++) f[j] = (__bf16)p[j];
            BW[nb][kt] = f;
        }
    }
    bf16x8 BC[4][4];  // all 4 chan-tiles (own-tile c2c needs every nb)
#pragma unroll
    for (int nb = 0; nb < 4; nb++) {
        int o2 = 16 * nb + m15;
#pragma unroll
        for (int kt = 0; kt < 4; kt++) {
            const float* p = Wc + o2 * 128 + kt * 32 + g4 * 8;
            bf16x8 f;
#pragma unroll
            for (int j = 0; j < 8; j++) f[j] = (__bf16)p[j];
            BC[nb][kt] = f;
        }
    }

    // ---- precomputed addresses ----
    int aG[2][4], aC[2][4], wOff[2][4];
    u32 offW[2][4], offLo[2][4], offHi[2][4];
#pragma unroll
    for (int mi = 0; mi < 2; mi++) {
        int mt = 2 * mh + mi;
#pragma unroll
        for (int kt = 0; kt < 4; kt++) {
            int P = 16 * (m15 & 3) + 4 * mt + (m15 >> 2);
            int phys = P + (kt >> 1) - 1;
            int chunk = (kt & 1) * 4 + g4;
            aG[mi][kt] = (phys < 0) ? (32768 + chunk * 16)
                                    : (phys * 128 + ((chunk ^ RHO(phys)) * 16));
            // own-tile c2c: rotated rows so reg 0 = row 4g4+nq of the tile
            int crow = 16 * mt + ((m15 & 12) | ((m15 + nq) & 3));
            int cphys = crow + (kt >> 1) - 1;
            aC[mi][kt] = (cphys < 0)
                             ? (32896 + chunk * 16)
                             : (16384 + cphys * 128 +
                                ((chunk ^ RHO(cphys)) * 16));
        }
        int p2 = 16 * mt + 4 * g4 + nq;
#pragma unroll
        for (int nb = 0; nb < 4; nb++) {
            int k = 16 * nb + m15;
            wOff[mi][nb] =
                8192 + p2 * 128 + (((k >> 3) ^ RHO(p2)) * 16) + (k & 7) * 2;
            int prerow = 16 * nb + 4 * mt + g4;  // nb doubles as gate idx r
            int bOffB = (prerow * 66 + 1) * 512 + 32 * m15 + 8 * nq;
            // walked u32 offset for the t+1 prefetch (clamped to w in [-1,64])
            offW[mi][nb] = (u32)(bOffB + ((1 - prerow) << 9));
            offLo[mi][nb] = (u32)(bOffB - 512);
            offHi[mi][nb] = (u32)(bOffB + 32768);
        }
    }

    const char* i2sB = (const char*)i2sP + (size_t)b * (64 * 66 * 512);
    u16* hp16[2];
    int p2s[2];
#pragma unroll
    for (int mi = 0; mi < 2; mi++) {
        int p2 = 16 * (2 * mh + mi) + 4 * g4 + nq;
        p2s[mi] = p2;
        hp16[mi] = hh16 + (size_t)b * 262144 + p2 * 4032 + m15;
    }

    // ---- initial IV load (t=0): clamp(0 - prerow) = offW - 512 clamped ----
    uint2 IV[2][4];
#pragma unroll
    for (int mi = 0; mi < 2; mi++) {
#pragma unroll
        for (int r = 0; r < 4; r++) {
            u32 o0 = min(max(offW[mi][r] - 512u, offLo[mi][r]), offHi[mi][r]);
            IV[mi][r] = *(const uint2*)(i2sB + o0);
        }
    }

    // ---- deferred-store carry state ----
    u16 hbKeep[2][4];
    u16* hpPrev[2];
    bool vstPrev[2];
#pragma unroll
    for (int mi = 0; mi < 2; mi++) {
        vstPrev[mi] = false;
        hpPrev[mi] = hp16[mi];
    }

    __syncthreads();

    for (int t = 0; t < NSTEP; t++) {
        // ---- deferred hh16 stores from step t-1 ----
#pragma unroll
        for (int mi = 0; mi < 2; mi++)
            if (vstPrev[mi]) {
#pragma unroll
                for (int nb = 0; nb < 4; nb++)
                    hpPrev[mi][nb * 16] = hbKeep[mi][nb];
            }

        // ---- per-mi fused: prefetch | acc-init+gates | c2c | LSTM+writes ----
#pragma unroll
        for (int mi = 0; mi < 2; mi++) {
            // prefetch IV for step t+1 (walked offsets, clamped)
            uint2 tn[4];
#pragma unroll
            for (int r = 0; r < 4; r++) {
                u32 oc = min(max(offW[mi][r], offLo[mi][r]), offHi[mi][r]);
                tn[r] = *(const uint2*)(i2sB + oc);
            }

            // gate MFMAs, acc initialized from current IV
            f32x4 accG[4];
#pragma unroll
            for (int r = 0; r < 4; r++) {
                accG[0][r] = lo2f(IV[mi][r].x);
                accG[1][r] = hi2f(IV[mi][r].x);
                accG[2][r] = lo2f(IV[mi][r].y);
                accG[3][r] = hi2f(IV[mi][r].y);
            }
            bf16x8 Ag[4];
#pragma unroll
            for (int kt = 0; kt < 4; kt++)
                Ag[kt] = __builtin_bit_cast(bf16x8,
                                            *(const uint4*)(smB + aG[mi][kt]));
#pragma unroll
            for (int nb = 0; nb < 4; nb++)
#pragma unroll
                for (int kt = 0; kt < 4; kt++)
                    accG[nb] = MFMA(Ag[kt], BW[nb][kt], accG[nb]);

            // own-tile c2c MFMAs (need only reg 0 of each acc)
            f32x4 accC[4] = {};
            {
                bf16x8 Ac[4];
#pragma unroll
                for (int kt = 0; kt < 4; kt++)
                    Ac[kt] = __builtin_bit_cast(
                        bf16x8, *(const uint4*)(smB + aC[mi][kt]));
#pragma unroll
                for (int nb = 0; nb < 4; nb++)
#pragma unroll
                    for (int kt = 0; kt < 4; kt++)
                        accC[nb] = MFMA(Ac[kt], BC[nb][kt], accC[nb]);
            }

            // LSTM update, rcp-fused:
            //   pX = 1+exp2(yX); c1 = (cc*pI*pG + pF) / (pF*pI*pG)
            //   E = exp2(c1*T2L); h1 = (E-1) / ((1+E)*pO)
            int p2 = p2s[mi];
            bool vst = (u32)(t - p2) < 64u;
#pragma unroll
            for (int nb = 0; nb < 4; nb++) {
                float cc = accC[nb][0] + bcc[nb];
                float pI = 1.f + __builtin_amdgcn_exp2f(accG[nb][0]);
                float pG = 1.f + __builtin_amdgcn_exp2f(accG[nb][1]);
                float pF = 1.f + __builtin_amdgcn_exp2f(accG[nb][2]);
                float pO = 1.f + __builtin_amdgcn_exp2f(accG[nb][3]);
                float u = pI * pG;
                float num = __builtin_fmaf(cc, u, pF);
                float c1 = num * __builtin_amdgcn_rcpf(pF * u);
                float E = __builtin_amdgcn_exp2f(c1 * T2L);
                float h1 =
                    (E - 1.f) * __builtin_amdgcn_rcpf((1.f + E) * pO);
                u32 hc = cvt_pk_bf16(h1, c1);  // lo=bf16(h1), hi=bf16(c1)
                *(u16*)(smB + wOff[mi][nb]) = (u16)hc;
                *(u16*)(smB + wOff[mi][nb] + 16384) = (u16)(hc >> 16);
                hbKeep[mi][nb] = (u16)hc;
            }
            vstPrev[mi] = vst;
            hpPrev[mi] = hp16[mi];
            hp16[mi] += 64;

            // rotate prefetched IV
#pragma unroll
            for (int r = 0; r < 4; r++) IV[mi][r] = tn[r];
        }

        __syncthreads();  // single barrier per step

        // ---- toggle parity; walk IV offsets ----
#pragma unroll
        for (int mi = 0; mi < 2; mi++) {
#pragma unroll
            for (int kt = 0; kt < 4; kt++) {
                aG[mi][kt] ^= 8192;
                aC[mi][kt] ^= 8192;
            }
#pragma unroll
            for (int nb = 0; nb < 4; nb++) {
                wOff[mi][nb] ^= 8192;
                offW[mi][nb] += 512;
            }
        }
    }

    // ---- epilogue: final deferred stores ----
#pragma unroll
    for (int mi = 0; mi < 2; mi++)
        if (vstPrev[mi]) {
#pragma unroll
            for (int nb = 0; nb < 4; nb++)
                hpPrev[mi][nb * 16] = hbKeep[mi][nb];
        }
}

// ---------------- K3: up-projection via MFMA (unchanged) ----------------
__global__ __launch_bounds__(256) void up_kernel(
    const u16* __restrict__ hh16, const u16* __restrict__ w_upB,
    const float* __restrict__ b_up, float* __restrict__ out) {
    const int bid = blockIdx.x;
    const int b = bid >> 6, r = bid & 63;
    const int lane = threadIdx.x & 63;
    const int wt = __builtin_amdgcn_readfirstlane(threadIdx.x >> 6);
    const int m15 = lane & 15, g4 = lane >> 4;

    const u16* hh_b = hh16 + (size_t)b * 262144;
    const int w = 16 * wt + m15;

    bf16x8 Bf[2];
#pragma unroll
    for (int kt = 0; kt < 2; kt++)
        Bf[kt] = __builtin_bit_cast(
            bf16x8,
            *(const uint4*)(hh_b + (r * 4096 + w * 64 + kt * 32 + g4 * 8)));

    f32x4 acc[8] = {};
#pragma unroll
    for (int nt = 0; nt < 8; nt++) {
#pragma unroll
        for (int kt = 0; kt < 2; kt++) {
            bf16x8 Af = __builtin_bit_cast(
                bf16x8, *(const uint4*)(w_upB + ((16 * nt + m15) * 64 +
                                                 kt * 32 + g4 * 8)));
            acc[nt] = MFMA(Af, Bf[kt], acc[nt]);
        }
    }
    float* outb = out + (size_t)b * 524288;
#pragma unroll
    for (int nt = 0; nt < 8; nt++) {
#pragma unroll
        for (int rr = 0; rr < 4; rr++) {
            int o2 = 16 * nt + 4 * g4 + rr;
            outb[(size_t)o2 * 4096 + r * 64 + w] = acc[nt][rr] + b_up[o2];
        }
    }
}

extern "C" void kernel_launch(void* const* d_in, const int* in_sizes, int n_in,
                              void* d_out, int out_size, void* d_ws,
                              size_t ws_size, hipStream_t stream) {
    (void)in_sizes; (void)n_in; (void)out_size; (void)ws_size;
    const float* inputs = (const float*)d_in[0];
    const float* w_i2s = (const float*)d_in[1];
    const float* b_i2s = (const float*)d_in[2];
    const float* w_s2s = (const float*)d_in[3];
    const float* b_s2s = (const float*)d_in[4];
    const float* w_c2c = (const float*)d_in[5];
    const float* b_c2c = (const float*)d_in[6];
    const float* w_up = (const float*)d_in[7];
    const float* b_up = (const float*)d_in[8];
    float* out = (float*)d_out;
    char* ws = (char*)d_ws;

    // workspace layout (bytes):
    // [0, 69206016)             i2sP u16 (32*64*66*256, bias-padded slots)
    // [69206016, 85983232)      hh16 u16 (32*64*64*64)
    // [85983232, 86114304)      Wg fp32 (256*128, scaled -log2e)
    // [86114304, 86147072)      Wc fp32 (64*128)
    // [86147072, 86147584)      biasRow u16[256]
    // [86147584, 86163968)      w_upB u16 (128*64)
    u16* i2sP = (u16*)ws;
    u16* hh16 = (u16*)(ws + 69206016);
    float* Wg = (float*)(ws + 85983232);
    float* Wc = (float*)(ws + 86114304);
    u16* biasRow = (u16*)(ws + 86147072);
    u16* w_upB = (u16*)(ws + 86147584);

    hipLaunchKernelGGL(repack_w, dim3(193), dim3(256), 0, stream, w_s2s, w_c2c,
                       b_i2s, b_s2s, w_up, Wg, Wc, biasRow, w_upB);
    hipLaunchKernelGGL(i2s_kernel, dim3(2048), dim3(256), 0, stream, inputs,
                       w_i2s, b_i2s, b_s2s, (const u32*)biasRow, (u32*)i2sP);
    hipLaunchKernelGGL(scan_kernel, dim3(32), dim3(512), 0, stream, i2sP, Wg,
                       Wc, b_c2c, hh16);
    hipLaunchKernelGGL(up_kernel, dim3(2048), dim3(256), 0, stream, hh16,
                       w_upB, b_up, out);
}

// Round 9
// 417.662 us; speedup vs baseline: 1.3544x; 1.0005x over previous
//
#include <hip/hip_runtime.h>
#include <cstdint>
#include <cstddef>

// DiagonalLSTM B=32,C=64,H=64,W=64,h=64,4h=256,NW=127 — v13.
// v13 = v12 + occupancy bumps on the latency-bound helper kernels:
//  - i2s_kernel: __launch_bounds__(256,3)  (2->3 blocks/CU; 16 strided HBM
//    staging loads + 2 barriers need more TLP to hide ~900cy misses)
//  - up_kernel: __launch_bounds__(256,4)   (was unspecified; short dep-chain
//    kernel, ~70 VGPR, fits 128 cap at 4 blocks/CU)
//  - scan: accC initialized from bcc (drops the later +bcc add; only reg0
//    of accC is consumed, broadcast init is safe)
// scan v12 structure unchanged: own-tile c2c, one barrier/step, deferred
// hh16 stores, IV prefetch->acc init, cvt_pk packing, rcp-fused LSTM cell.

typedef unsigned int u32;
typedef unsigned short u16;
typedef __bf16 bf16x8 __attribute__((ext_vector_type(8)));
typedef float f32x4 __attribute__((ext_vector_type(4)));

#define NSTEP 127
#define MFMA(a, b, c) __builtin_amdgcn_mfma_f32_16x16x32_bf16(a, b, c, 0, 0, 0)
#define LOG2E 1.4426950408889634f
#define SCL (-1.4426950408889634f)
#define T2L 2.8853900817779268f
#define RHO(r) ((((r) ^ ((r) >> 3))) & 7)

static __device__ __forceinline__ u16 f2bf(float f) {
    u32 u = __builtin_bit_cast(u32, f);
    u32 r = u + 0x7FFFu + ((u >> 16) & 1u);
    return (u16)(r >> 16);
}
static __device__ __forceinline__ u32 cvt_pk_bf16(float a, float b) {
    // dst.lo = bf16(a), dst.hi = bf16(b); RNE — bit-identical to f2bf.
    u32 d;
    asm("v_cvt_pk_bf16_f32 %0, %1, %2" : "=v"(d) : "v"(a), "v"(b));
    return d;
}
static __device__ __forceinline__ float lo2f(u32 u) {
    return __builtin_bit_cast(float, u << 16);
}
static __device__ __forceinline__ float hi2f(u32 u) {
    return __builtin_bit_cast(float, u & 0xFFFF0000u);
}

// ---------------- K0: weight repack ----------------
__global__ __launch_bounds__(256) void repack_w(
    const float* __restrict__ w_s2s, const float* __restrict__ w_c2c,
    const float* __restrict__ bi, const float* __restrict__ bs,
    const float* __restrict__ w_up, float* __restrict__ Wg,
    float* __restrict__ Wc, u16* __restrict__ biasRow,
    u16* __restrict__ w_upB) {
    int idx = blockIdx.x * 256 + threadIdx.x;
    if (idx < 32768) {
        int o = idx >> 7, kk = idx & 127, half = kk >> 6, k = kk & 63;
        Wg[idx] = SCL * w_s2s[(o * 64 + k) * 2 + half];
        return;
    }
    int j = idx - 32768;
    if (j < 8192) {
        int o = j >> 7, kk = j & 127, half = kk >> 6, k = kk & 63;
        Wc[j] = w_c2c[(o * 64 + k) * 2 + half];
        return;
    }
    j -= 8192;
    if (j < 256) {
        int m15 = j >> 4, nq = (j >> 2) & 3, nb = j & 3;
        int o = 64 * nq + 16 * nb + m15;
        biasRow[j] = f2bf(SCL * (bi[o] + bs[o]));
        return;
    }
    j -= 256;
    if (j < 8192) w_upB[j] = f2bf(w_up[j]);
}

// ---------------- K1: i2s conv via MFMA ----------
__global__ __launch_bounds__(256, 3) void i2s_kernel(
    const float* __restrict__ in, const float* __restrict__ w_i2s,
    const float* __restrict__ bi, const float* __restrict__ bs,
    const u32* __restrict__ biasU32, u32* __restrict__ out_u32) {
    const int bid = blockIdx.x;
    const int b = bid >> 6, r = bid & 63;
    const int tid = threadIdx.x;
    const int lane = tid & 63;
    const int wv = __builtin_amdgcn_readfirstlane(tid >> 6);
    const int m15 = lane & 15, g4 = lane >> 4;

    __shared__ __align__(16) u32 sT[64 * 129];  // u16 [w 64][o'' 256]
    __shared__ __align__(16) u32 Xt[64 * 32];   // bf16 [w 64][c 64], swizzled
    char* XtB = (char*)Xt;

    {
        const int w = tid & 63, cp = tid >> 6;
        const float* xp = in + (size_t)b * 262144 + r * 64 + w;
#pragma unroll
        for (int pass = 0; pass < 8; pass++) {
            int c = pass * 8 + cp * 2;
            float x0 = xp[(size_t)c * 4096];
            float x1 = xp[(size_t)(c + 1) * 4096];
            *(u32*)(XtB + ((w * 128 + c * 2) ^ ((w & 7) << 4))) =
                cvt_pk_bf16(x0, x1);
        }
    }

    bf16x8 Af[4][2];
#pragma unroll
    for (int m = 0; m < 4; m++)
#pragma unroll
        for (int kt = 0; kt < 2; kt++) {
            const float* p =
                w_i2s + (wv * 64 + m * 16 + m15) * 64 + kt * 32 + g4 * 8;
            bf16x8 f;
#pragma unroll
            for (int j = 0; j < 8; j++) f[j] = (__bf16)p[j];
            Af[m][kt] = f;
        }
    float bias[4][4];
#pragma unroll
    for (int m = 0; m < 4; m++)
#pragma unroll
        for (int reg = 0; reg < 4; reg++) {
            int o = wv * 64 + m * 16 + 4 * g4 + reg;
            bias[m][reg] = bi[o] + bs[o];
        }

    __syncthreads();

    f32x4 acc[4][4] = {};
#pragma unroll
    for (int nt = 0; nt < 4; nt++) {
        const int w = nt * 16 + m15;
        bf16x8 Bf[2];
#pragma unroll
        for (int kt = 0; kt < 2; kt++)
            Bf[kt] = __builtin_bit_cast(
                bf16x8, *(const uint4*)(XtB + ((w * 128 + kt * 64 + g4 * 16) ^
                                               ((w & 7) << 4))));
#pragma unroll
        for (int m = 0; m < 4; m++)
#pragma unroll
            for (int kt = 0; kt < 2; kt++)
                acc[m][nt] = MFMA(Af[m][kt], Bf[kt], acc[m][nt]);
    }

#pragma unroll
    for (int nt = 0; nt < 4; nt++) {
        const int w = nt * 16 + m15;
#pragma unroll
        for (int reg = 0; reg < 4; reg++)
#pragma unroll
            for (int mp = 0; mp < 2; mp++) {
                float v0 = SCL * (acc[2 * mp][nt][reg] + bias[2 * mp][reg]);
                float v1 =
                    SCL * (acc[2 * mp + 1][nt][reg] + bias[2 * mp + 1][reg]);
                sT[w * 129 + (4 * g4 + reg) * 8 + wv * 2 + mp] =
                    cvt_pk_bf16(v0, v1);
            }
    }
    __syncthreads();

    const size_t base = ((size_t)(b * 64 + r) * 66 + 1) * 128;
#pragma unroll
    for (int loop = 0; loop < 32; loop++) {
        int idx = loop * 256 + tid;
        int w = idx >> 7, cu = idx & 127;
        out_u32[base + idx] = sT[w * 129 + cu];
    }
    if (tid < 128) {
        u32 v = biasU32[tid];
        out_u32[base - 128 + tid] = v;
        out_u32[base + 8192 + tid] = v;
    }
}

// ---------------- K2: MFMA scan v13 ----------------
// 32 blocks x 512 threads (8 waves). LDS sM bytes: [0,8192) H par0;
// [8192,16384) H par1; [16384,32768) C par0/par1; ZH0@32768 ZC0@32896
// ZH1@40960 ZC1@41088. All addrs XOR 8192 per step; RHO chunk swizzle.
__global__ __launch_bounds__(512, 2) void scan_kernel(
    const u16* __restrict__ i2sP, const float* __restrict__ Wg,
    const float* __restrict__ Wc, const float* __restrict__ b_c2c,
    u16* __restrict__ hh16) {
    const int b = blockIdx.x;
    const int tid = threadIdx.x;
    const int lane = tid & 63;
    const int wv = __builtin_amdgcn_readfirstlane(tid >> 6);
    const int mh = wv >> 2, nq = wv & 3;
    const int m15 = lane & 15, g4 = lane >> 4;

    __shared__ __align__(16) u32 sM[10304];  // 41216 B
    char* smB = (char*)sM;

    for (int i = tid; i < 10304; i += 512) sM[i] = 0;

    // ---- VGPR-resident weights ----
    bf16x8 BW[4][4];
    float bcc[4];
#pragma unroll
    for (int nb = 0; nb < 4; nb++) {
        int o = 64 * nq + 16 * nb + m15;
        bcc[nb] = b_c2c[16 * nb + m15];
#pragma unroll
        for (int kt = 0; kt < 4; kt++) {
            const float* p = Wg + o * 128 + kt * 32 + g4 * 8;
            bf16x8 f;
#pragma unroll
            for (int j = 0; j < 8; j++) f[j] = (__bf16)p[j];
            BW[nb][kt] = f;
        }
    }
    bf16x8 BC[4][4];  // all 4 chan-tiles (own-tile c2c needs every nb)
#pragma unroll
    for (int nb = 0; nb < 4; nb++) {
        int o2 = 16 * nb + m15;
#pragma unroll
        for (int kt = 0; kt < 4; kt++) {
            const float* p = Wc + o2 * 128 + kt * 32 + g4 * 8;
            bf16x8 f;
#pragma unroll
            for (int j = 0; j < 8; j++) f[j] = (__bf16)p[j];
            BC[nb][kt] = f;
        }
    }

    // ---- precomputed addresses ----
    int aG[2][4], aC[2][4], wOff[2][4];
    u32 offW[2][4], offLo[2][4], offHi[2][4];
#pragma unroll
    for (int mi = 0; mi < 2; mi++) {
        int mt = 2 * mh + mi;
#pragma unroll
        for (int kt = 0; kt < 4; kt++) {
            int P = 16 * (m15 & 3) + 4 * mt + (m15 >> 2);
            int phys = P + (kt >> 1) - 1;
            int chunk = (kt & 1) * 4 + g4;
            aG[mi][kt] = (phys < 0) ? (32768 + chunk * 16)
                                    : (phys * 128 + ((chunk ^ RHO(phys)) * 16));
            // own-tile c2c: rotated rows so reg 0 = row 4g4+nq of the tile
            int crow = 16 * mt + ((m15 & 12) | ((m15 + nq) & 3));
            int cphys = crow + (kt >> 1) - 1;
            aC[mi][kt] = (cphys < 0)
                             ? (32896 + chunk * 16)
                             : (16384 + cphys * 128 +
                                ((chunk ^ RHO(cphys)) * 16));
        }
        int p2 = 16 * mt + 4 * g4 + nq;
#pragma unroll
        for (int nb = 0; nb < 4; nb++) {
            int k = 16 * nb + m15;
            wOff[mi][nb] =
                8192 + p2 * 128 + (((k >> 3) ^ RHO(p2)) * 16) + (k & 7) * 2;
            int prerow = 16 * nb + 4 * mt + g4;  // nb doubles as gate idx r
            int bOffB = (prerow * 66 + 1) * 512 + 32 * m15 + 8 * nq;
            // walked u32 offset for the t+1 prefetch (clamped to w in [-1,64])
            offW[mi][nb] = (u32)(bOffB + ((1 - prerow) << 9));
            offLo[mi][nb] = (u32)(bOffB - 512);
            offHi[mi][nb] = (u32)(bOffB + 32768);
        }
    }

    const char* i2sB = (const char*)i2sP + (size_t)b * (64 * 66 * 512);
    u16* hp16[2];
    int p2s[2];
#pragma unroll
    for (int mi = 0; mi < 2; mi++) {
        int p2 = 16 * (2 * mh + mi) + 4 * g4 + nq;
        p2s[mi] = p2;
        hp16[mi] = hh16 + (size_t)b * 262144 + p2 * 4032 + m15;
    }

    // ---- initial IV load (t=0): clamp(0 - prerow) = offW - 512 clamped ----
    uint2 IV[2][4];
#pragma unroll
    for (int mi = 0; mi < 2; mi++) {
#pragma unroll
        for (int r = 0; r < 4; r++) {
            u32 o0 = min(max(offW[mi][r] - 512u, offLo[mi][r]), offHi[mi][r]);
            IV[mi][r] = *(const uint2*)(i2sB + o0);
        }
    }

    // ---- deferred-store carry state ----
    u16 hbKeep[2][4];
    u16* hpPrev[2];
    bool vstPrev[2];
#pragma unroll
    for (int mi = 0; mi < 2; mi++) {
        vstPrev[mi] = false;
        hpPrev[mi] = hp16[mi];
    }

    __syncthreads();

    for (int t = 0; t < NSTEP; t++) {
        // ---- deferred hh16 stores from step t-1 ----
#pragma unroll
        for (int mi = 0; mi < 2; mi++)
            if (vstPrev[mi]) {
#pragma unroll
                for (int nb = 0; nb < 4; nb++)
                    hpPrev[mi][nb * 16] = hbKeep[mi][nb];
            }

        // ---- per-mi fused: prefetch | acc-init+gates | c2c | LSTM+writes ----
#pragma unroll
        for (int mi = 0; mi < 2; mi++) {
            // prefetch IV for step t+1 (walked offsets, clamped)
            uint2 tn[4];
#pragma unroll
            for (int r = 0; r < 4; r++) {
                u32 oc = min(max(offW[mi][r], offLo[mi][r]), offHi[mi][r]);
                tn[r] = *(const uint2*)(i2sB + oc);
            }

            // gate MFMAs, acc initialized from current IV
            f32x4 accG[4];
#pragma unroll
            for (int r = 0; r < 4; r++) {
                accG[0][r] = lo2f(IV[mi][r].x);
                accG[1][r] = hi2f(IV[mi][r].x);
                accG[2][r] = lo2f(IV[mi][r].y);
                accG[3][r] = hi2f(IV[mi][r].y);
            }
            bf16x8 Ag[4];
#pragma unroll
            for (int kt = 0; kt < 4; kt++)
                Ag[kt] = __builtin_bit_cast(bf16x8,
                                            *(const uint4*)(smB + aG[mi][kt]));
#pragma unroll
            for (int nb = 0; nb < 4; nb++)
#pragma unroll
                for (int kt = 0; kt < 4; kt++)
                    accG[nb] = MFMA(Ag[kt], BW[nb][kt], accG[nb]);

            // own-tile c2c MFMAs, acc init = bcc broadcast (only reg0 used;
            // folds the later +bcc add into the accumulator init)
            f32x4 accC[4];
#pragma unroll
            for (int nb = 0; nb < 4; nb++) {
                accC[nb][0] = bcc[nb];
                accC[nb][1] = bcc[nb];
                accC[nb][2] = bcc[nb];
                accC[nb][3] = bcc[nb];
            }
            {
                bf16x8 Ac[4];
#pragma unroll
                for (int kt = 0; kt < 4; kt++)
                    Ac[kt] = __builtin_bit_cast(
                        bf16x8, *(const uint4*)(smB + aC[mi][kt]));
#pragma unroll
                for (int nb = 0; nb < 4; nb++)
#pragma unroll
                    for (int kt = 0; kt < 4; kt++)
                        accC[nb] = MFMA(Ac[kt], BC[nb][kt], accC[nb]);
            }

            // LSTM update, rcp-fused:
            //   pX = 1+exp2(yX); c1 = (cc*pI*pG + pF) / (pF*pI*pG)
            //   E = exp2(c1*T2L); h1 = (E-1) / ((1+E)*pO)
            int p2 = p2s[mi];
            bool vst = (u32)(t - p2) < 64u;
#pragma unroll
            for (int nb = 0; nb < 4; nb++) {
                float cc = accC[nb][0];
                float pI = 1.f + __builtin_amdgcn_exp2f(accG[nb][0]);
                float pG = 1.f + __builtin_amdgcn_exp2f(accG[nb][1]);
                float pF = 1.f + __builtin_amdgcn_exp2f(accG[nb][2]);
                float pO = 1.f + __builtin_amdgcn_exp2f(accG[nb][3]);
                float u = pI * pG;
                float num = __builtin_fmaf(cc, u, pF);
                float c1 = num * __builtin_amdgcn_rcpf(pF * u);
                float E = __builtin_amdgcn_exp2f(c1 * T2L);
                float h1 =
                    (E - 1.f) * __builtin_amdgcn_rcpf((1.f + E) * pO);
                u32 hc = cvt_pk_bf16(h1, c1);  // lo=bf16(h1), hi=bf16(c1)
                *(u16*)(smB + wOff[mi][nb]) = (u16)hc;
                *(u16*)(smB + wOff[mi][nb] + 16384) = (u16)(hc >> 16);
                hbKeep[mi][nb] = (u16)hc;
            }
            vstPrev[mi] = vst;
            hpPrev[mi] = hp16[mi];
            hp16[mi] += 64;

            // rotate prefetched IV
#pragma unroll
            for (int r = 0; r < 4; r++) IV[mi][r] = tn[r];
        }

        __syncthreads();  // single barrier per step

        // ---- toggle parity; walk IV offsets ----
#pragma unroll
        for (int mi = 0; mi < 2; mi++) {
#pragma unroll
            for (int kt = 0; kt < 4; kt++) {
                aG[mi][kt] ^= 8192;
                aC[mi][kt] ^= 8192;
            }
#pragma unroll
            for (int nb = 0; nb < 4; nb++) {
                wOff[mi][nb] ^= 8192;
                offW[mi][nb] += 512;
            }
        }
    }

    // ---- epilogue: final deferred stores ----
#pragma unroll
    for (int mi = 0; mi < 2; mi++)
        if (vstPrev[mi]) {
#pragma unroll
            for (int nb = 0; nb < 4; nb++)
                hpPrev[mi][nb * 16] = hbKeep[mi][nb];
        }
}

// ---------------- K3: up-projection via MFMA ----------------
__global__ __launch_bounds__(256, 4) void up_kernel(
    const u16* __restrict__ hh16, const u16* __restrict__ w_upB,
    const float* __restrict__ b_up, float* __restrict__ out) {
    const int bid = blockIdx.x;
    const int b = bid >> 6, r = bid & 63;
    const int lane = threadIdx.x & 63;
    const int wt = __builtin_amdgcn_readfirstlane(threadIdx.x >> 6);
    const int m15 = lane & 15, g4 = lane >> 4;

    const u16* hh_b = hh16 + (size_t)b * 262144;
    const int w = 16 * wt + m15;

    bf16x8 Bf[2];
#pragma unroll
    for (int kt = 0; kt < 2; kt++)
        Bf[kt] = __builtin_bit_cast(
            bf16x8,
            *(const uint4*)(hh_b + (r * 4096 + w * 64 + kt * 32 + g4 * 8)));

    f32x4 acc[8] = {};
#pragma unroll
    for (int nt = 0; nt < 8; nt++) {
#pragma unroll
        for (int kt = 0; kt < 2; kt++) {
            bf16x8 Af = __builtin_bit_cast(
                bf16x8, *(const uint4*)(w_upB + ((16 * nt + m15) * 64 +
                                                 kt * 32 + g4 * 8)));
            acc[nt] = MFMA(Af, Bf[kt], acc[nt]);
        }
    }
    float* outb = out + (size_t)b * 524288;
#pragma unroll
    for (int nt = 0; nt < 8; nt++) {
#pragma unroll
        for (int rr = 0; rr < 4; rr++) {
            int o2 = 16 * nt + 4 * g4 + rr;
            outb[(size_t)o2 * 4096 + r * 64 + w] = acc[nt][rr] + b_up[o2];
        }
    }
}

extern "C" void kernel_launch(void* const* d_in, const int* in_sizes, int n_in,
                              void* d_out, int out_size, void* d_ws,
                              size_t ws_size, hipStream_t stream) {
    (void)in_sizes; (void)n_in; (void)out_size; (void)ws_size;
    const float* inputs = (const float*)d_in[0];
    const float* w_i2s = (const float*)d_in[1];
    const float* b_i2s = (const float*)d_in[2];
    const float* w_s2s = (const float*)d_in[3];
    const float* b_s2s = (const float*)d_in[4];
    const float* w_c2c = (const float*)d_in[5];
    const float* b_c2c = (const float*)d_in[6];
    const float* w_up = (const float*)d_in[7];
    const float* b_up = (const float*)d_in[8];
    float* out = (float*)d_out;
    char* ws = (char*)d_ws;

    // workspace layout (bytes):
    // [0, 69206016)             i2sP u16 (32*64*66*256, bias-padded slots)
    // [69206016, 85983232)      hh16 u16 (32*64*64*64)
    // [85983232, 86114304)      Wg fp32 (256*128, scaled -log2e)
    // [86114304, 86147072)      Wc fp32 (64*128)
    // [86147072, 86147584)      biasRow u16[256]
    // [86147584, 86163968)      w_upB u16 (128*64)
    u16* i2sP = (u16*)ws;
    u16* hh16 = (u16*)(ws + 69206016);
    float* Wg = (float*)(ws + 85983232);
    float* Wc = (float*)(ws + 86114304);
    u16* biasRow = (u16*)(ws + 86147072);
    u16* w_upB = (u16*)(ws + 86147584);

    hipLaunchKernelGGL(repack_w, dim3(193), dim3(256), 0, stream, w_s2s, w_c2c,
                       b_i2s, b_s2s, w_up, Wg, Wc, biasRow, w_upB);
    hipLaunchKernelGGL(i2s_kernel, dim3(2048), dim3(256), 0, stream, inputs,
                       w_i2s, b_i2s, b_s2s, (const u32*)biasRow, (u32*)i2sP);
    hipLaunchKernelGGL(scan_kernel, dim3(32), dim3(512), 0, stream, i2sP, Wg,
                       Wc, b_c2c, hh16);
    hipLaunchKernelGGL(up_kernel, dim3(2048), dim3(256), 0, stream, hh16,
                       w_upB, b_up, out);
}

// Round 10
// 404.267 us; speedup vs baseline: 1.3992x; 1.0331x over previous
//
#include <hip/hip_runtime.h>
#include <cstdint>
#include <cstddef>

// DiagonalLSTM B=32,C=64,H=64,W=64,h=64,4h=256,NW=127 — v14.
// v14 = v13 + c2c MFMA redundancy halved via ROW-INTERLEAVED A tiles:
// A-tile-row i is supplied by lanes with m15==i, and reg r delivers C-row
// 4g4+r, so the 16 A rows are freely programmable per m15. Interleave:
//   crow(m15) = 16*(2mh + (m15&1)) + (m15&12) + nq
// => reg0 = cc(mt0 row 4g4+nq), reg1 = cc(mt1 row 4g4+nq).
// One 16-MFMA set serves BOTH mi (was 2x16). MFMA/wave/step 64->48,
// Ac ds_reads 8->4, accC init movs halved. Bit-identical arithmetic.
// v13 kept: own-tile rotation idea, one barrier/step, deferred hh16 stores,
// IV prefetch->acc init, cvt_pk, rcp-fused LSTM, K1/K3 launch bounds.

typedef unsigned int u32;
typedef unsigned short u16;
typedef __bf16 bf16x8 __attribute__((ext_vector_type(8)));
typedef float f32x4 __attribute__((ext_vector_type(4)));

#define NSTEP 127
#define MFMA(a, b, c) __builtin_amdgcn_mfma_f32_16x16x32_bf16(a, b, c, 0, 0, 0)
#define LOG2E 1.4426950408889634f
#define SCL (-1.4426950408889634f)
#define T2L 2.8853900817779268f
#define RHO(r) ((((r) ^ ((r) >> 3))) & 7)

static __device__ __forceinline__ u16 f2bf(float f) {
    u32 u = __builtin_bit_cast(u32, f);
    u32 r = u + 0x7FFFu + ((u >> 16) & 1u);
    return (u16)(r >> 16);
}
static __device__ __forceinline__ u32 cvt_pk_bf16(float a, float b) {
    // dst.lo = bf16(a), dst.hi = bf16(b); RNE — bit-identical to f2bf.
    u32 d;
    asm("v_cvt_pk_bf16_f32 %0, %1, %2" : "=v"(d) : "v"(a), "v"(b));
    return d;
}
static __device__ __forceinline__ float lo2f(u32 u) {
    return __builtin_bit_cast(float, u << 16);
}
static __device__ __forceinline__ float hi2f(u32 u) {
    return __builtin_bit_cast(float, u & 0xFFFF0000u);
}

// ---------------- K0: weight repack ----------------
__global__ __launch_bounds__(256) void repack_w(
    const float* __restrict__ w_s2s, const float* __restrict__ w_c2c,
    const float* __restrict__ bi, const float* __restrict__ bs,
    const float* __restrict__ w_up, float* __restrict__ Wg,
    float* __restrict__ Wc, u16* __restrict__ biasRow,
    u16* __restrict__ w_upB) {
    int idx = blockIdx.x * 256 + threadIdx.x;
    if (idx < 32768) {
        int o = idx >> 7, kk = idx & 127, half = kk >> 6, k = kk & 63;
        Wg[idx] = SCL * w_s2s[(o * 64 + k) * 2 + half];
        return;
    }
    int j = idx - 32768;
    if (j < 8192) {
        int o = j >> 7, kk = j & 127, half = kk >> 6, k = kk & 63;
        Wc[j] = w_c2c[(o * 64 + k) * 2 + half];
        return;
    }
    j -= 8192;
    if (j < 256) {
        int m15 = j >> 4, nq = (j >> 2) & 3, nb = j & 3;
        int o = 64 * nq + 16 * nb + m15;
        biasRow[j] = f2bf(SCL * (bi[o] + bs[o]));
        return;
    }
    j -= 256;
    if (j < 8192) w_upB[j] = f2bf(w_up[j]);
}

// ---------------- K1: i2s conv via MFMA (unchanged from v13) ----------
__global__ __launch_bounds__(256, 3) void i2s_kernel(
    const float* __restrict__ in, const float* __restrict__ w_i2s,
    const float* __restrict__ bi, const float* __restrict__ bs,
    const u32* __restrict__ biasU32, u32* __restrict__ out_u32) {
    const int bid = blockIdx.x;
    const int b = bid >> 6, r = bid & 63;
    const int tid = threadIdx.x;
    const int lane = tid & 63;
    const int wv = __builtin_amdgcn_readfirstlane(tid >> 6);
    const int m15 = lane & 15, g4 = lane >> 4;

    __shared__ __align__(16) u32 sT[64 * 129];  // u16 [w 64][o'' 256]
    __shared__ __align__(16) u32 Xt[64 * 32];   // bf16 [w 64][c 64], swizzled
    char* XtB = (char*)Xt;

    {
        const int w = tid & 63, cp = tid >> 6;
        const float* xp = in + (size_t)b * 262144 + r * 64 + w;
#pragma unroll
        for (int pass = 0; pass < 8; pass++) {
            int c = pass * 8 + cp * 2;
            float x0 = xp[(size_t)c * 4096];
            float x1 = xp[(size_t)(c + 1) * 4096];
            *(u32*)(XtB + ((w * 128 + c * 2) ^ ((w & 7) << 4))) =
                cvt_pk_bf16(x0, x1);
        }
    }

    bf16x8 Af[4][2];
#pragma unroll
    for (int m = 0; m < 4; m++)
#pragma unroll
        for (int kt = 0; kt < 2; kt++) {
            const float* p =
                w_i2s + (wv * 64 + m * 16 + m15) * 64 + kt * 32 + g4 * 8;
            bf16x8 f;
#pragma unroll
            for (int j = 0; j < 8; j++) f[j] = (__bf16)p[j];
            Af[m][kt] = f;
        }
    float bias[4][4];
#pragma unroll
    for (int m = 0; m < 4; m++)
#pragma unroll
        for (int reg = 0; reg < 4; reg++) {
            int o = wv * 64 + m * 16 + 4 * g4 + reg;
            bias[m][reg] = bi[o] + bs[o];
        }

    __syncthreads();

    f32x4 acc[4][4] = {};
#pragma unroll
    for (int nt = 0; nt < 4; nt++) {
        const int w = nt * 16 + m15;
        bf16x8 Bf[2];
#pragma unroll
        for (int kt = 0; kt < 2; kt++)
            Bf[kt] = __builtin_bit_cast(
                bf16x8, *(const uint4*)(XtB + ((w * 128 + kt * 64 + g4 * 16) ^
                                               ((w & 7) << 4))));
#pragma unroll
        for (int m = 0; m < 4; m++)
#pragma unroll
            for (int kt = 0; kt < 2; kt++)
                acc[m][nt] = MFMA(Af[m][kt], Bf[kt], acc[m][nt]);
    }

#pragma unroll
    for (int nt = 0; nt < 4; nt++) {
        const int w = nt * 16 + m15;
#pragma unroll
        for (int reg = 0; reg < 4; reg++)
#pragma unroll
            for (int mp = 0; mp < 2; mp++) {
                float v0 = SCL * (acc[2 * mp][nt][reg] + bias[2 * mp][reg]);
                float v1 =
                    SCL * (acc[2 * mp + 1][nt][reg] + bias[2 * mp + 1][reg]);
                sT[w * 129 + (4 * g4 + reg) * 8 + wv * 2 + mp] =
                    cvt_pk_bf16(v0, v1);
            }
    }
    __syncthreads();

    const size_t base = ((size_t)(b * 64 + r) * 66 + 1) * 128;
#pragma unroll
    for (int loop = 0; loop < 32; loop++) {
        int idx = loop * 256 + tid;
        int w = idx >> 7, cu = idx & 127;
        out_u32[base + idx] = sT[w * 129 + cu];
    }
    if (tid < 128) {
        u32 v = biasU32[tid];
        out_u32[base - 128 + tid] = v;
        out_u32[base + 8192 + tid] = v;
    }
}

// ---------------- K2: MFMA scan v14 ----------------
// 32 blocks x 512 threads (8 waves). LDS sM bytes: [0,8192) H par0;
// [8192,16384) H par1; [16384,32768) C par0/par1; ZH0@32768 ZC0@32896
// ZH1@40960 ZC1@41088. All addrs XOR 8192 per step; RHO chunk swizzle.
__global__ __launch_bounds__(512, 2) void scan_kernel(
    const u16* __restrict__ i2sP, const float* __restrict__ Wg,
    const float* __restrict__ Wc, const float* __restrict__ b_c2c,
    u16* __restrict__ hh16) {
    const int b = blockIdx.x;
    const int tid = threadIdx.x;
    const int lane = tid & 63;
    const int wv = __builtin_amdgcn_readfirstlane(tid >> 6);
    const int mh = wv >> 2, nq = wv & 3;
    const int m15 = lane & 15, g4 = lane >> 4;

    __shared__ __align__(16) u32 sM[10304];  // 41216 B
    char* smB = (char*)sM;

    for (int i = tid; i < 10304; i += 512) sM[i] = 0;

    // ---- VGPR-resident weights ----
    bf16x8 BW[4][4];
    float bcc[4];
#pragma unroll
    for (int nb = 0; nb < 4; nb++) {
        int o = 64 * nq + 16 * nb + m15;
        bcc[nb] = b_c2c[16 * nb + m15];
#pragma unroll
        for (int kt = 0; kt < 4; kt++) {
            const float* p = Wg + o * 128 + kt * 32 + g4 * 8;
            bf16x8 f;
#pragma unroll
            for (int j = 0; j < 8; j++) f[j] = (__bf16)p[j];
            BW[nb][kt] = f;
        }
    }
    bf16x8 BC[4][4];  // all 4 chan-tiles
#pragma unroll
    for (int nb = 0; nb < 4; nb++) {
        int o2 = 16 * nb + m15;
#pragma unroll
        for (int kt = 0; kt < 4; kt++) {
            const float* p = Wc + o2 * 128 + kt * 32 + g4 * 8;
            bf16x8 f;
#pragma unroll
            for (int j = 0; j < 8; j++) f[j] = (__bf16)p[j];
            BC[nb][kt] = f;
        }
    }

    // ---- precomputed addresses ----
    int aG[2][4], aC[4], wOff[2][4];
    u32 offW[2][4], offLo[2][4], offHi[2][4];
#pragma unroll
    for (int mi = 0; mi < 2; mi++) {
        int mt = 2 * mh + mi;
#pragma unroll
        for (int kt = 0; kt < 4; kt++) {
            int P = 16 * (m15 & 3) + 4 * mt + (m15 >> 2);
            int phys = P + (kt >> 1) - 1;
            int chunk = (kt & 1) * 4 + g4;
            aG[mi][kt] = (phys < 0) ? (32768 + chunk * 16)
                                    : (phys * 128 + ((chunk ^ RHO(phys)) * 16));
        }
        int p2 = 16 * mt + 4 * g4 + nq;
#pragma unroll
        for (int nb = 0; nb < 4; nb++) {
            int k = 16 * nb + m15;
            wOff[mi][nb] =
                8192 + p2 * 128 + (((k >> 3) ^ RHO(p2)) * 16) + (k & 7) * 2;
            int prerow = 16 * nb + 4 * mt + g4;  // nb doubles as gate idx r
            int bOffB = (prerow * 66 + 1) * 512 + 32 * m15 + 8 * nq;
            // walked u32 offset for the t+1 prefetch (clamped to w in [-1,64])
            offW[mi][nb] = (u32)(bOffB + ((1 - prerow) << 9));
            offLo[mi][nb] = (u32)(bOffB - 512);
            offHi[mi][nb] = (u32)(bOffB + 32768);
        }
    }
    // c2c: ROW-INTERLEAVED tile — even tile-rows = mt0, odd = mt1:
    //   crow(m15) = 16*(2mh + (m15&1)) + (m15&12) + nq
    // reg0 -> mi=0 row (16*mt0 + 4g4 + nq), reg1 -> mi=1 row.
#pragma unroll
    for (int kt = 0; kt < 4; kt++) {
        int crow = 16 * (2 * mh + (m15 & 1)) + (m15 & 12) + nq;
        int cphys = crow + (kt >> 1) - 1;
        int chunk = (kt & 1) * 4 + g4;
        aC[kt] = (cphys < 0)
                     ? (32896 + chunk * 16)
                     : (16384 + cphys * 128 + ((chunk ^ RHO(cphys)) * 16));
    }

    const char* i2sB = (const char*)i2sP + (size_t)b * (64 * 66 * 512);
    u16* hp16[2];
    int p2s[2];
#pragma unroll
    for (int mi = 0; mi < 2; mi++) {
        int p2 = 16 * (2 * mh + mi) + 4 * g4 + nq;
        p2s[mi] = p2;
        hp16[mi] = hh16 + (size_t)b * 262144 + p2 * 4032 + m15;
    }

    // ---- initial IV load (t=0) ----
    uint2 IV[2][4];
#pragma unroll
    for (int mi = 0; mi < 2; mi++) {
#pragma unroll
        for (int r = 0; r < 4; r++) {
            u32 o0 = min(max(offW[mi][r] - 512u, offLo[mi][r]), offHi[mi][r]);
            IV[mi][r] = *(const uint2*)(i2sB + o0);
        }
    }

    // ---- deferred-store carry state ----
    u16 hbKeep[2][4];
    u16* hpPrev[2];
    bool vstPrev[2];
#pragma unroll
    for (int mi = 0; mi < 2; mi++) {
        vstPrev[mi] = false;
        hpPrev[mi] = hp16[mi];
    }

    __syncthreads();

    for (int t = 0; t < NSTEP; t++) {
        // ---- deferred hh16 stores from step t-1 ----
#pragma unroll
        for (int mi = 0; mi < 2; mi++)
            if (vstPrev[mi]) {
#pragma unroll
                for (int nb = 0; nb < 4; nb++)
                    hpPrev[mi][nb * 16] = hbKeep[mi][nb];
            }

        // ---- c2c ONCE per step (row-interleaved tile serves both mi) ----
        f32x4 accC[4];
#pragma unroll
        for (int nb = 0; nb < 4; nb++) {
            accC[nb][0] = bcc[nb];
            accC[nb][1] = bcc[nb];
            accC[nb][2] = bcc[nb];
            accC[nb][3] = bcc[nb];
        }
        {
            bf16x8 Ac[4];
#pragma unroll
            for (int kt = 0; kt < 4; kt++)
                Ac[kt] = __builtin_bit_cast(bf16x8,
                                            *(const uint4*)(smB + aC[kt]));
#pragma unroll
            for (int nb = 0; nb < 4; nb++)
#pragma unroll
                for (int kt = 0; kt < 4; kt++)
                    accC[nb] = MFMA(Ac[kt], BC[nb][kt], accC[nb]);
        }

        // ---- per-mi: prefetch | acc-init+gates | LSTM+writes ----
#pragma unroll
        for (int mi = 0; mi < 2; mi++) {
            // prefetch IV for step t+1 (walked offsets, clamped)
            uint2 tn[4];
#pragma unroll
            for (int r = 0; r < 4; r++) {
                u32 oc = min(max(offW[mi][r], offLo[mi][r]), offHi[mi][r]);
                tn[r] = *(const uint2*)(i2sB + oc);
            }

            // gate MFMAs, acc initialized from current IV
            f32x4 accG[4];
#pragma unroll
            for (int r = 0; r < 4; r++) {
                accG[0][r] = lo2f(IV[mi][r].x);
                accG[1][r] = hi2f(IV[mi][r].x);
                accG[2][r] = lo2f(IV[mi][r].y);
                accG[3][r] = hi2f(IV[mi][r].y);
            }
            bf16x8 Ag[4];
#pragma unroll
            for (int kt = 0; kt < 4; kt++)
                Ag[kt] = __builtin_bit_cast(bf16x8,
                                            *(const uint4*)(smB + aG[mi][kt]));
#pragma unroll
            for (int nb = 0; nb < 4; nb++)
#pragma unroll
                for (int kt = 0; kt < 4; kt++)
                    accG[nb] = MFMA(Ag[kt], BW[nb][kt], accG[nb]);

            // LSTM update, rcp-fused; cc = accC[nb][mi] (static under unroll)
            int p2 = p2s[mi];
            bool vst = (u32)(t - p2) < 64u;
#pragma unroll
            for (int nb = 0; nb < 4; nb++) {
                float cc = accC[nb][mi];
                float pI = 1.f + __builtin_amdgcn_exp2f(accG[nb][0]);
                float pG = 1.f + __builtin_amdgcn_exp2f(accG[nb][1]);
                float pF = 1.f + __builtin_amdgcn_exp2f(accG[nb][2]);
                float pO = 1.f + __builtin_amdgcn_exp2f(accG[nb][3]);
                float u = pI * pG;
                float num = __builtin_fmaf(cc, u, pF);
                float c1 = num * __builtin_amdgcn_rcpf(pF * u);
                float E = __builtin_amdgcn_exp2f(c1 * T2L);
                float h1 =
                    (E - 1.f) * __builtin_amdgcn_rcpf((1.f + E) * pO);
                u32 hc = cvt_pk_bf16(h1, c1);  // lo=bf16(h1), hi=bf16(c1)
                *(u16*)(smB + wOff[mi][nb]) = (u16)hc;
                *(u16*)(smB + wOff[mi][nb] + 16384) = (u16)(hc >> 16);
                hbKeep[mi][nb] = (u16)hc;
            }
            vstPrev[mi] = vst;
            hpPrev[mi] = hp16[mi];
            hp16[mi] += 64;

            // rotate prefetched IV
#pragma unroll
            for (int r = 0; r < 4; r++) IV[mi][r] = tn[r];
        }

        __syncthreads();  // single barrier per step

        // ---- toggle parity; walk IV offsets ----
#pragma unroll
        for (int kt = 0; kt < 4; kt++) aC[kt] ^= 8192;
#pragma unroll
        for (int mi = 0; mi < 2; mi++) {
#pragma unroll
            for (int kt = 0; kt < 4; kt++) aG[mi][kt] ^= 8192;
#pragma unroll
            for (int nb = 0; nb < 4; nb++) {
                wOff[mi][nb] ^= 8192;
                offW[mi][nb] += 512;
            }
        }
    }

    // ---- epilogue: final deferred stores ----
#pragma unroll
    for (int mi = 0; mi < 2; mi++)
        if (vstPrev[mi]) {
#pragma unroll
            for (int nb = 0; nb < 4; nb++)
                hpPrev[mi][nb * 16] = hbKeep[mi][nb];
        }
}

// ---------------- K3: up-projection via MFMA (unchanged) ----------------
__global__ __launch_bounds__(256, 4) void up_kernel(
    const u16* __restrict__ hh16, const u16* __restrict__ w_upB,
    const float* __restrict__ b_up, float* __restrict__ out) {
    const int bid = blockIdx.x;
    const int b = bid >> 6, r = bid & 63;
    const int lane = threadIdx.x & 63;
    const int wt = __builtin_amdgcn_readfirstlane(threadIdx.x >> 6);
    const int m15 = lane & 15, g4 = lane >> 4;

    const u16* hh_b = hh16 + (size_t)b * 262144;
    const int w = 16 * wt + m15;

    bf16x8 Bf[2];
#pragma unroll
    for (int kt = 0; kt < 2; kt++)
        Bf[kt] = __builtin_bit_cast(
            bf16x8,
            *(const uint4*)(hh_b + (r * 4096 + w * 64 + kt * 32 + g4 * 8)));

    f32x4 acc[8] = {};
#pragma unroll
    for (int nt = 0; nt < 8; nt++) {
#pragma unroll
        for (int kt = 0; kt < 2; kt++) {
            bf16x8 Af = __builtin_bit_cast(
                bf16x8, *(const uint4*)(w_upB + ((16 * nt + m15) * 64 +
                                                 kt * 32 + g4 * 8)));
            acc[nt] = MFMA(Af, Bf[kt], acc[nt]);
        }
    }
    float* outb = out + (size_t)b * 524288;
#pragma unroll
    for (int nt = 0; nt < 8; nt++) {
#pragma unroll
        for (int rr = 0; rr < 4; rr++) {
            int o2 = 16 * nt + 4 * g4 + rr;
            outb[(size_t)o2 * 4096 + r * 64 + w] = acc[nt][rr] + b_up[o2];
        }
    }
}

extern "C" void kernel_launch(void* const* d_in, const int* in_sizes, int n_in,
                              void* d_out, int out_size, void* d_ws,
                              size_t ws_size, hipStream_t stream) {
    (void)in_sizes; (void)n_in; (void)out_size; (void)ws_size;
    const float* inputs = (const float*)d_in[0];
    const float* w_i2s = (const float*)d_in[1];
    const float* b_i2s = (const float*)d_in[2];
    const float* w_s2s = (const float*)d_in[3];
    const float* b_s2s = (const float*)d_in[4];
    const float* w_c2c = (const float*)d_in[5];
    const float* b_c2c = (const float*)d_in[6];
    const float* w_up = (const float*)d_in[7];
    const float* b_up = (const float*)d_in[8];
    float* out = (float*)d_out;
    char* ws = (char*)d_ws;

    // workspace layout (bytes):
    // [0, 69206016)             i2sP u16 (32*64*66*256, bias-padded slots)
    // [69206016, 85983232)      hh16 u16 (32*64*64*64)
    // [85983232, 86114304)      Wg fp32 (256*128, scaled -log2e)
    // [86114304, 86147072)      Wc fp32 (64*128)
    // [86147072, 86147584)      biasRow u16[256]
    // [86147584, 86163968)      w_upB u16 (128*64)
    u16* i2sP = (u16*)ws;
    u16* hh16 = (u16*)(ws + 69206016);
    float* Wg = (float*)(ws + 85983232);
    float* Wc = (float*)(ws + 86114304);
    u16* biasRow = (u16*)(ws + 86147072);
    u16* w_upB = (u16*)(ws + 86147584);

    hipLaunchKernelGGL(repack_w, dim3(193), dim3(256), 0, stream, w_s2s, w_c2c,
                       b_i2s, b_s2s, w_up, Wg, Wc, biasRow, w_upB);
    hipLaunchKernelGGL(i2s_kernel, dim3(2048), dim3(256), 0, stream, inputs,
                       w_i2s, b_i2s, b_s2s, (const u32*)biasRow, (u32*)i2sP);
    hipLaunchKernelGGL(scan_kernel, dim3(32), dim3(512), 0, stream, i2sP, Wg,
                       Wc, b_c2c, hh16);
    hipLaunchKernelGGL(up_kernel, dim3(2048), dim3(256), 0, stream, hh16,
                       w_upB, b_up, out);
}

// Round 11
// 403.051 us; speedup vs baseline: 1.4035x; 1.0030x over previous
//
#include <hip/hip_runtime.h>
#include <cstdint>
#include <cstddef>

// DiagonalLSTM B=32,C=64,H=64,W=64,h=64,4h=256,NW=127 — v16.
// v16 = v14 + vectorized parameter loads in the helper kernels (scan is
// untouched — it matched prediction at 265us and is ~85% issue-saturated):
//  - K1: Af fragments via 2x float4 + 4x v_cvt_pk_bf16_f32 per frag
//    (was 64 scalar f32 loads + 64 scalar converts per thread) and float4
//    bias loads (was 32 scalar). K1 was VMEM-instruction-bound, not HBM.
//  - K3: b_up via 8 float4 loads (was 32 scalar), statically indexed f32x4.
// All conversions RNE -> bit-identical results.

typedef unsigned int u32;
typedef unsigned short u16;
typedef __bf16 bf16x8 __attribute__((ext_vector_type(8)));
typedef float f32x4 __attribute__((ext_vector_type(4)));

#define NSTEP 127
#define MFMA(a, b, c) __builtin_amdgcn_mfma_f32_16x16x32_bf16(a, b, c, 0, 0, 0)
#define LOG2E 1.4426950408889634f
#define SCL (-1.4426950408889634f)
#define T2L 2.8853900817779268f
#define RHO(r) ((((r) ^ ((r) >> 3))) & 7)

static __device__ __forceinline__ u16 f2bf(float f) {
    u32 u = __builtin_bit_cast(u32, f);
    u32 r = u + 0x7FFFu + ((u >> 16) & 1u);
    return (u16)(r >> 16);
}
static __device__ __forceinline__ u32 cvt_pk_bf16(float a, float b) {
    // dst.lo = bf16(a), dst.hi = bf16(b); RNE — bit-identical to f2bf.
    u32 d;
    asm("v_cvt_pk_bf16_f32 %0, %1, %2" : "=v"(d) : "v"(a), "v"(b));
    return d;
}
static __device__ __forceinline__ float lo2f(u32 u) {
    return __builtin_bit_cast(float, u << 16);
}
static __device__ __forceinline__ float hi2f(u32 u) {
    return __builtin_bit_cast(float, u & 0xFFFF0000u);
}

// ---------------- K0: weight repack ----------------
__global__ __launch_bounds__(256) void repack_w(
    const float* __restrict__ w_s2s, const float* __restrict__ w_c2c,
    const float* __restrict__ bi, const float* __restrict__ bs,
    const float* __restrict__ w_up, float* __restrict__ Wg,
    float* __restrict__ Wc, u16* __restrict__ biasRow,
    u16* __restrict__ w_upB) {
    int idx = blockIdx.x * 256 + threadIdx.x;
    if (idx < 32768) {
        int o = idx >> 7, kk = idx & 127, half = kk >> 6, k = kk & 63;
        Wg[idx] = SCL * w_s2s[(o * 64 + k) * 2 + half];
        return;
    }
    int j = idx - 32768;
    if (j < 8192) {
        int o = j >> 7, kk = j & 127, half = kk >> 6, k = kk & 63;
        Wc[j] = w_c2c[(o * 64 + k) * 2 + half];
        return;
    }
    j -= 8192;
    if (j < 256) {
        int m15 = j >> 4, nq = (j >> 2) & 3, nb = j & 3;
        int o = 64 * nq + 16 * nb + m15;
        biasRow[j] = f2bf(SCL * (bi[o] + bs[o]));
        return;
    }
    j -= 256;
    if (j < 8192) w_upB[j] = f2bf(w_up[j]);
}

// ---------------- K1: i2s conv via MFMA (vectorized param loads) ----------
__global__ __launch_bounds__(256, 3) void i2s_kernel(
    const float* __restrict__ in, const float* __restrict__ w_i2s,
    const float* __restrict__ bi, const float* __restrict__ bs,
    const u32* __restrict__ biasU32, u32* __restrict__ out_u32) {
    const int bid = blockIdx.x;
    const int b = bid >> 6, r = bid & 63;
    const int tid = threadIdx.x;
    const int lane = tid & 63;
    const int wv = __builtin_amdgcn_readfirstlane(tid >> 6);
    const int m15 = lane & 15, g4 = lane >> 4;

    __shared__ __align__(16) u32 sT[64 * 129];  // u16 [w 64][o'' 256]
    __shared__ __align__(16) u32 Xt[64 * 32];   // bf16 [w 64][c 64], swizzled
    char* XtB = (char*)Xt;

    {
        const int w = tid & 63, cp = tid >> 6;
        const float* xp = in + (size_t)b * 262144 + r * 64 + w;
#pragma unroll
        for (int pass = 0; pass < 8; pass++) {
            int c = pass * 8 + cp * 2;
            float x0 = xp[(size_t)c * 4096];
            float x1 = xp[(size_t)(c + 1) * 4096];
            *(u32*)(XtB + ((w * 128 + c * 2) ^ ((w & 7) << 4))) =
                cvt_pk_bf16(x0, x1);
        }
    }

    // A fragments: 2x float4 + 4x cvt_pk per frag (was 8 scalar loads+cvts)
    bf16x8 Af[4][2];
#pragma unroll
    for (int m = 0; m < 4; m++)
#pragma unroll
        for (int kt = 0; kt < 2; kt++) {
            const float4* p = (const float4*)(w_i2s +
                                              (wv * 64 + m * 16 + m15) * 64 +
                                              kt * 32 + g4 * 8);
            float4 a = p[0], bq = p[1];
            uint4 u;
            u.x = cvt_pk_bf16(a.x, a.y);
            u.y = cvt_pk_bf16(a.z, a.w);
            u.z = cvt_pk_bf16(bq.x, bq.y);
            u.w = cvt_pk_bf16(bq.z, bq.w);
            Af[m][kt] = __builtin_bit_cast(bf16x8, u);
        }
    // bias via float4 (o = wv*64 + m*16 + 4g4 + rr, rr 0..3 contiguous)
    float bias[4][4];
#pragma unroll
    for (int m = 0; m < 4; m++) {
        int o = wv * 64 + m * 16 + 4 * g4;
        float4 vb = *(const float4*)(bi + o);
        float4 vs = *(const float4*)(bs + o);
        bias[m][0] = vb.x + vs.x;
        bias[m][1] = vb.y + vs.y;
        bias[m][2] = vb.z + vs.z;
        bias[m][3] = vb.w + vs.w;
    }

    __syncthreads();

    f32x4 acc[4][4] = {};
#pragma unroll
    for (int nt = 0; nt < 4; nt++) {
        const int w = nt * 16 + m15;
        bf16x8 Bf[2];
#pragma unroll
        for (int kt = 0; kt < 2; kt++)
            Bf[kt] = __builtin_bit_cast(
                bf16x8, *(const uint4*)(XtB + ((w * 128 + kt * 64 + g4 * 16) ^
                                               ((w & 7) << 4))));
#pragma unroll
        for (int m = 0; m < 4; m++)
#pragma unroll
            for (int kt = 0; kt < 2; kt++)
                acc[m][nt] = MFMA(Af[m][kt], Bf[kt], acc[m][nt]);
    }

#pragma unroll
    for (int nt = 0; nt < 4; nt++) {
        const int w = nt * 16 + m15;
#pragma unroll
        for (int reg = 0; reg < 4; reg++)
#pragma unroll
            for (int mp = 0; mp < 2; mp++) {
                float v0 = SCL * (acc[2 * mp][nt][reg] + bias[2 * mp][reg]);
                float v1 =
                    SCL * (acc[2 * mp + 1][nt][reg] + bias[2 * mp + 1][reg]);
                sT[w * 129 + (4 * g4 + reg) * 8 + wv * 2 + mp] =
                    cvt_pk_bf16(v0, v1);
            }
    }
    __syncthreads();

    const size_t base = ((size_t)(b * 64 + r) * 66 + 1) * 128;
#pragma unroll
    for (int loop = 0; loop < 32; loop++) {
        int idx = loop * 256 + tid;
        int w = idx >> 7, cu = idx & 127;
        out_u32[base + idx] = sT[w * 129 + cu];
    }
    if (tid < 128) {
        u32 v = biasU32[tid];
        out_u32[base - 128 + tid] = v;
        out_u32[base + 8192 + tid] = v;
    }
}

// ---------------- K2: MFMA scan (v14, unchanged) ----------------
// 32 blocks x 512 threads (8 waves). LDS sM bytes: [0,8192) H par0;
// [8192,16384) H par1; [16384,32768) C par0/par1; ZH0@32768 ZC0@32896
// ZH1@40960 ZC1@41088. All addrs XOR 8192 per step; RHO chunk swizzle.
__global__ __launch_bounds__(512, 2) void scan_kernel(
    const u16* __restrict__ i2sP, const float* __restrict__ Wg,
    const float* __restrict__ Wc, const float* __restrict__ b_c2c,
    u16* __restrict__ hh16) {
    const int b = blockIdx.x;
    const int tid = threadIdx.x;
    const int lane = tid & 63;
    const int wv = __builtin_amdgcn_readfirstlane(tid >> 6);
    const int mh = wv >> 2, nq = wv & 3;
    const int m15 = lane & 15, g4 = lane >> 4;

    __shared__ __align__(16) u32 sM[10304];  // 41216 B
    char* smB = (char*)sM;

    for (int i = tid; i < 10304; i += 512) sM[i] = 0;

    // ---- VGPR-resident weights ----
    bf16x8 BW[4][4];
    float bcc[4];
#pragma unroll
    for (int nb = 0; nb < 4; nb++) {
        int o = 64 * nq + 16 * nb + m15;
        bcc[nb] = b_c2c[16 * nb + m15];
#pragma unroll
        for (int kt = 0; kt < 4; kt++) {
            const float* p = Wg + o * 128 + kt * 32 + g4 * 8;
            bf16x8 f;
#pragma unroll
            for (int j = 0; j < 8; j++) f[j] = (__bf16)p[j];
            BW[nb][kt] = f;
        }
    }
    bf16x8 BC[4][4];  // all 4 chan-tiles
#pragma unroll
    for (int nb = 0; nb < 4; nb++) {
        int o2 = 16 * nb + m15;
#pragma unroll
        for (int kt = 0; kt < 4; kt++) {
            const float* p = Wc + o2 * 128 + kt * 32 + g4 * 8;
            bf16x8 f;
#pragma unroll
            for (int j = 0; j < 8; j++) f[j] = (__bf16)p[j];
            BC[nb][kt] = f;
        }
    }

    // ---- precomputed addresses ----
    int aG[2][4], aC[4], wOff[2][4];
    u32 offW[2][4], offLo[2][4], offHi[2][4];
#pragma unroll
    for (int mi = 0; mi < 2; mi++) {
        int mt = 2 * mh + mi;
#pragma unroll
        for (int kt = 0; kt < 4; kt++) {
            int P = 16 * (m15 & 3) + 4 * mt + (m15 >> 2);
            int phys = P + (kt >> 1) - 1;
            int chunk = (kt & 1) * 4 + g4;
            aG[mi][kt] = (phys < 0) ? (32768 + chunk * 16)
                                    : (phys * 128 + ((chunk ^ RHO(phys)) * 16));
        }
        int p2 = 16 * mt + 4 * g4 + nq;
#pragma unroll
        for (int nb = 0; nb < 4; nb++) {
            int k = 16 * nb + m15;
            wOff[mi][nb] =
                8192 + p2 * 128 + (((k >> 3) ^ RHO(p2)) * 16) + (k & 7) * 2;
            int prerow = 16 * nb + 4 * mt + g4;  // nb doubles as gate idx r
            int bOffB = (prerow * 66 + 1) * 512 + 32 * m15 + 8 * nq;
            // walked u32 offset for the t+1 prefetch (clamped to w in [-1,64])
            offW[mi][nb] = (u32)(bOffB + ((1 - prerow) << 9));
            offLo[mi][nb] = (u32)(bOffB - 512);
            offHi[mi][nb] = (u32)(bOffB + 32768);
        }
    }
    // c2c: ROW-INTERLEAVED tile — even tile-rows = mt0, odd = mt1:
    //   crow(m15) = 16*(2mh + (m15&1)) + (m15&12) + nq
    // reg0 -> mi=0 row (16*mt0 + 4g4 + nq), reg1 -> mi=1 row.
#pragma unroll
    for (int kt = 0; kt < 4; kt++) {
        int crow = 16 * (2 * mh + (m15 & 1)) + (m15 & 12) + nq;
        int cphys = crow + (kt >> 1) - 1;
        int chunk = (kt & 1) * 4 + g4;
        aC[kt] = (cphys < 0)
                     ? (32896 + chunk * 16)
                     : (16384 + cphys * 128 + ((chunk ^ RHO(cphys)) * 16));
    }

    const char* i2sB = (const char*)i2sP + (size_t)b * (64 * 66 * 512);
    u16* hp16[2];
    int p2s[2];
#pragma unroll
    for (int mi = 0; mi < 2; mi++) {
        int p2 = 16 * (2 * mh + mi) + 4 * g4 + nq;
        p2s[mi] = p2;
        hp16[mi] = hh16 + (size_t)b * 262144 + p2 * 4032 + m15;
    }

    // ---- initial IV load (t=0) ----
    uint2 IV[2][4];
#pragma unroll
    for (int mi = 0; mi < 2; mi++) {
#pragma unroll
        for (int r = 0; r < 4; r++) {
            u32 o0 = min(max(offW[mi][r] - 512u, offLo[mi][r]), offHi[mi][r]);
            IV[mi][r] = *(const uint2*)(i2sB + o0);
        }
    }

    // ---- deferred-store carry state ----
    u16 hbKeep[2][4];
    u16* hpPrev[2];
    bool vstPrev[2];
#pragma unroll
    for (int mi = 0; mi < 2; mi++) {
        vstPrev[mi] = false;
        hpPrev[mi] = hp16[mi];
    }

    __syncthreads();

    for (int t = 0; t < NSTEP; t++) {
        // ---- deferred hh16 stores from step t-1 ----
#pragma unroll
        for (int mi = 0; mi < 2; mi++)
            if (vstPrev[mi]) {
#pragma unroll
                for (int nb = 0; nb < 4; nb++)
                    hpPrev[mi][nb * 16] = hbKeep[mi][nb];
            }

        // ---- c2c ONCE per step (row-interleaved tile serves both mi) ----
        f32x4 accC[4];
#pragma unroll
        for (int nb = 0; nb < 4; nb++) {
            accC[nb][0] = bcc[nb];
            accC[nb][1] = bcc[nb];
            accC[nb][2] = bcc[nb];
            accC[nb][3] = bcc[nb];
        }
        {
            bf16x8 Ac[4];
#pragma unroll
            for (int kt = 0; kt < 4; kt++)
                Ac[kt] = __builtin_bit_cast(bf16x8,
                                            *(const uint4*)(smB + aC[kt]));
#pragma unroll
            for (int nb = 0; nb < 4; nb++)
#pragma unroll
                for (int kt = 0; kt < 4; kt++)
                    accC[nb] = MFMA(Ac[kt], BC[nb][kt], accC[nb]);
        }

        // ---- per-mi: prefetch | acc-init+gates | LSTM+writes ----
#pragma unroll
        for (int mi = 0; mi < 2; mi++) {
            // prefetch IV for step t+1 (walked offsets, clamped)
            uint2 tn[4];
#pragma unroll
            for (int r = 0; r < 4; r++) {
                u32 oc = min(max(offW[mi][r], offLo[mi][r]), offHi[mi][r]);
                tn[r] = *(const uint2*)(i2sB + oc);
            }

            // gate MFMAs, acc initialized from current IV
            f32x4 accG[4];
#pragma unroll
            for (int r = 0; r < 4; r++) {
                accG[0][r] = lo2f(IV[mi][r].x);
                accG[1][r] = hi2f(IV[mi][r].x);
                accG[2][r] = lo2f(IV[mi][r].y);
                accG[3][r] = hi2f(IV[mi][r].y);
            }
            bf16x8 Ag[4];
#pragma unroll
            for (int kt = 0; kt < 4; kt++)
                Ag[kt] = __builtin_bit_cast(bf16x8,
                                            *(const uint4*)(smB + aG[mi][kt]));
#pragma unroll
            for (int nb = 0; nb < 4; nb++)
#pragma unroll
                for (int kt = 0; kt < 4; kt++)
                    accG[nb] = MFMA(Ag[kt], BW[nb][kt], accG[nb]);

            // LSTM update, rcp-fused; cc = accC[nb][mi] (static under unroll)
            int p2 = p2s[mi];
            bool vst = (u32)(t - p2) < 64u;
#pragma unroll
            for (int nb = 0; nb < 4; nb++) {
                float cc = accC[nb][mi];
                float pI = 1.f + __builtin_amdgcn_exp2f(accG[nb][0]);
                float pG = 1.f + __builtin_amdgcn_exp2f(accG[nb][1]);
                float pF = 1.f + __builtin_amdgcn_exp2f(accG[nb][2]);
                float pO = 1.f + __builtin_amdgcn_exp2f(accG[nb][3]);
                float u = pI * pG;
                float num = __builtin_fmaf(cc, u, pF);
                float c1 = num * __builtin_amdgcn_rcpf(pF * u);
                float E = __builtin_amdgcn_exp2f(c1 * T2L);
                float h1 =
                    (E - 1.f) * __builtin_amdgcn_rcpf((1.f + E) * pO);
                u32 hc = cvt_pk_bf16(h1, c1);  // lo=bf16(h1), hi=bf16(c1)
                *(u16*)(smB + wOff[mi][nb]) = (u16)hc;
                *(u16*)(smB + wOff[mi][nb] + 16384) = (u16)(hc >> 16);
                hbKeep[mi][nb] = (u16)hc;
            }
            vstPrev[mi] = vst;
            hpPrev[mi] = hp16[mi];
            hp16[mi] += 64;

            // rotate prefetched IV
#pragma unroll
            for (int r = 0; r < 4; r++) IV[mi][r] = tn[r];
        }

        __syncthreads();  // single barrier per step

        // ---- toggle parity; walk IV offsets ----
#pragma unroll
        for (int kt = 0; kt < 4; kt++) aC[kt] ^= 8192;
#pragma unroll
        for (int mi = 0; mi < 2; mi++) {
#pragma unroll
            for (int kt = 0; kt < 4; kt++) aG[mi][kt] ^= 8192;
#pragma unroll
            for (int nb = 0; nb < 4; nb++) {
                wOff[mi][nb] ^= 8192;
                offW[mi][nb] += 512;
            }
        }
    }

    // ---- epilogue: final deferred stores ----
#pragma unroll
    for (int mi = 0; mi < 2; mi++)
        if (vstPrev[mi]) {
#pragma unroll
            for (int nb = 0; nb < 4; nb++)
                hpPrev[mi][nb * 16] = hbKeep[mi][nb];
        }
}

// ---------------- K3: up-projection via MFMA (vectorized b_up) ----------
__global__ __launch_bounds__(256, 4) void up_kernel(
    const u16* __restrict__ hh16, const u16* __restrict__ w_upB,
    const float* __restrict__ b_up, float* __restrict__ out) {
    const int bid = blockIdx.x;
    const int b = bid >> 6, r = bid & 63;
    const int lane = threadIdx.x & 63;
    const int wt = __builtin_amdgcn_readfirstlane(threadIdx.x >> 6);
    const int m15 = lane & 15, g4 = lane >> 4;

    const u16* hh_b = hh16 + (size_t)b * 262144;
    const int w = 16 * wt + m15;

    bf16x8 Bf[2];
#pragma unroll
    for (int kt = 0; kt < 2; kt++)
        Bf[kt] = __builtin_bit_cast(
            bf16x8,
            *(const uint4*)(hh_b + (r * 4096 + w * 64 + kt * 32 + g4 * 8)));

    // b_up via float4 (o2 = 16nt + 4g4 + rr, rr 0..3 contiguous)
    f32x4 bup[8];
#pragma unroll
    for (int nt = 0; nt < 8; nt++)
        bup[nt] =
            __builtin_bit_cast(f32x4, *(const float4*)(b_up + 16 * nt + 4 * g4));

    f32x4 acc[8] = {};
#pragma unroll
    for (int nt = 0; nt < 8; nt++) {
#pragma unroll
        for (int kt = 0; kt < 2; kt++) {
            bf16x8 Af = __builtin_bit_cast(
                bf16x8, *(const uint4*)(w_upB + ((16 * nt + m15) * 64 +
                                                 kt * 32 + g4 * 8)));
            acc[nt] = MFMA(Af, Bf[kt], acc[nt]);
        }
    }
    float* outb = out + (size_t)b * 524288;
#pragma unroll
    for (int nt = 0; nt < 8; nt++) {
#pragma unroll
        for (int rr = 0; rr < 4; rr++) {
            int o2 = 16 * nt + 4 * g4 + rr;
            outb[(size_t)o2 * 4096 + r * 64 + w] = acc[nt][rr] + bup[nt][rr];
        }
    }
}

extern "C" void kernel_launch(void* const* d_in, const int* in_sizes, int n_in,
                              void* d_out, int out_size, void* d_ws,
                              size_t ws_size, hipStream_t stream) {
    (void)in_sizes; (void)n_in; (void)out_size; (void)ws_size;
    const float* inputs = (const float*)d_in[0];
    const float* w_i2s = (const float*)d_in[1];
    const float* b_i2s = (const float*)d_in[2];
    const float* w_s2s = (const float*)d_in[3];
    const float* b_s2s = (const float*)d_in[4];
    const float* w_c2c = (const float*)d_in[5];
    const float* b_c2c = (const float*)d_in[6];
    const float* w_up = (const float*)d_in[7];
    const float* b_up = (const float*)d_in[8];
    float* out = (float*)d_out;
    char* ws = (char*)d_ws;

    // workspace layout (bytes):
    // [0, 69206016)             i2sP u16 (32*64*66*256, bias-padded slots)
    // [69206016, 85983232)      hh16 u16 (32*64*64*64)
    // [85983232, 86114304)      Wg fp32 (256*128, scaled -log2e)
    // [86114304, 86147072)      Wc fp32 (64*128)
    // [86147072, 86147584)      biasRow u16[256]
    // [86147584, 86163968)      w_upB u16 (128*64)
    u16* i2sP = (u16*)ws;
    u16* hh16 = (u16*)(ws + 69206016);
    float* Wg = (float*)(ws + 85983232);
    float* Wc = (float*)(ws + 86114304);
    u16* biasRow = (u16*)(ws + 86147072);
    u16* w_upB = (u16*)(ws + 86147584);

    hipLaunchKernelGGL(repack_w, dim3(193), dim3(256), 0, stream, w_s2s, w_c2c,
                       b_i2s, b_s2s, w_up, Wg, Wc, biasRow, w_upB);
    hipLaunchKernelGGL(i2s_kernel, dim3(2048), dim3(256), 0, stream, inputs,
                       w_i2s, b_i2s, b_s2s, (const u32*)biasRow, (u32*)i2sP);
    hipLaunchKernelGGL(scan_kernel, dim3(32), dim3(512), 0, stream, i2sP, Wg,
                       Wc, b_c2c, hh16);
    hipLaunchKernelGGL(up_kernel, dim3(2048), dim3(256), 0, stream, hh16,
                       w_upB, b_up, out);
}

// Round 12
// 400.114 us; speedup vs baseline: 1.4138x; 1.0073x over previous
//
#include <hip/hip_runtime.h>
#include <cstdint>
#include <cstddef>

// DiagonalLSTM B=32,C=64,H=64,W=64,h=64,4h=256,NW=127 — v17.
// v17 = v16 + K1 LDS union: Xt (8KB staging) aliases sT's storage (33KB).
// Xt is consumed (MFMA B-frag reads) strictly before sT is produced
// (epilogue), made safe across waves by one added __syncthreads. K1 LDS
// 41.2KB -> 33KB: 3 -> 4 blocks/CU (160KB pool), 16 waves/CU, and exactly
// 2 dispatch rounds (2048/1024). This is the mechanism both v13 (launch-
// bounds was a no-op at the 41KB LDS ceiling) and v16 (instruction count
// irrelevant when latency-bound) missed. Scan and K3 untouched.

typedef unsigned int u32;
typedef unsigned short u16;
typedef __bf16 bf16x8 __attribute__((ext_vector_type(8)));
typedef float f32x4 __attribute__((ext_vector_type(4)));

#define NSTEP 127
#define MFMA(a, b, c) __builtin_amdgcn_mfma_f32_16x16x32_bf16(a, b, c, 0, 0, 0)
#define LOG2E 1.4426950408889634f
#define SCL (-1.4426950408889634f)
#define T2L 2.8853900817779268f
#define RHO(r) ((((r) ^ ((r) >> 3))) & 7)

static __device__ __forceinline__ u16 f2bf(float f) {
    u32 u = __builtin_bit_cast(u32, f);
    u32 r = u + 0x7FFFu + ((u >> 16) & 1u);
    return (u16)(r >> 16);
}
static __device__ __forceinline__ u32 cvt_pk_bf16(float a, float b) {
    // dst.lo = bf16(a), dst.hi = bf16(b); RNE — bit-identical to f2bf.
    u32 d;
    asm("v_cvt_pk_bf16_f32 %0, %1, %2" : "=v"(d) : "v"(a), "v"(b));
    return d;
}
static __device__ __forceinline__ float lo2f(u32 u) {
    return __builtin_bit_cast(float, u << 16);
}
static __device__ __forceinline__ float hi2f(u32 u) {
    return __builtin_bit_cast(float, u & 0xFFFF0000u);
}

// ---------------- K0: weight repack ----------------
__global__ __launch_bounds__(256) void repack_w(
    const float* __restrict__ w_s2s, const float* __restrict__ w_c2c,
    const float* __restrict__ bi, const float* __restrict__ bs,
    const float* __restrict__ w_up, float* __restrict__ Wg,
    float* __restrict__ Wc, u16* __restrict__ biasRow,
    u16* __restrict__ w_upB) {
    int idx = blockIdx.x * 256 + threadIdx.x;
    if (idx < 32768) {
        int o = idx >> 7, kk = idx & 127, half = kk >> 6, k = kk & 63;
        Wg[idx] = SCL * w_s2s[(o * 64 + k) * 2 + half];
        return;
    }
    int j = idx - 32768;
    if (j < 8192) {
        int o = j >> 7, kk = j & 127, half = kk >> 6, k = kk & 63;
        Wc[j] = w_c2c[(o * 64 + k) * 2 + half];
        return;
    }
    j -= 8192;
    if (j < 256) {
        int m15 = j >> 4, nq = (j >> 2) & 3, nb = j & 3;
        int o = 64 * nq + 16 * nb + m15;
        biasRow[j] = f2bf(SCL * (bi[o] + bs[o]));
        return;
    }
    j -= 256;
    if (j < 8192) w_upB[j] = f2bf(w_up[j]);
}

// ---------------- K1: i2s conv via MFMA (LDS union: Xt aliases sT) --------
__global__ __launch_bounds__(256, 4) void i2s_kernel(
    const float* __restrict__ in, const float* __restrict__ w_i2s,
    const float* __restrict__ bi, const float* __restrict__ bs,
    const u32* __restrict__ biasU32, u32* __restrict__ out_u32) {
    const int bid = blockIdx.x;
    const int b = bid >> 6, r = bid & 63;
    const int tid = threadIdx.x;
    const int lane = tid & 63;
    const int wv = __builtin_amdgcn_readfirstlane(tid >> 6);
    const int m15 = lane & 15, g4 = lane >> 4;

    // Union: first 8192 B double as Xt (bf16 [w 64][c 64], swizzled) during
    // staging+MFMA; whole buffer is sT (u16 [w 64][o'' 256], u32 stride 129)
    // during the epilogue. Barrier between the two phases.
    __shared__ __align__(16) u32 sT[64 * 129];  // 33024 B -> 4 blocks/CU
    char* XtB = (char*)sT;

    {
        const int w = tid & 63, cp = tid >> 6;
        const float* xp = in + (size_t)b * 262144 + r * 64 + w;
#pragma unroll
        for (int pass = 0; pass < 8; pass++) {
            int c = pass * 8 + cp * 2;
            float x0 = xp[(size_t)c * 4096];
            float x1 = xp[(size_t)(c + 1) * 4096];
            *(u32*)(XtB + ((w * 128 + c * 2) ^ ((w & 7) << 4))) =
                cvt_pk_bf16(x0, x1);
        }
    }

    // A fragments: 2x float4 + 4x cvt_pk per frag
    bf16x8 Af[4][2];
#pragma unroll
    for (int m = 0; m < 4; m++)
#pragma unroll
        for (int kt = 0; kt < 2; kt++) {
            const float4* p = (const float4*)(w_i2s +
                                              (wv * 64 + m * 16 + m15) * 64 +
                                              kt * 32 + g4 * 8);
            float4 a = p[0], bq = p[1];
            uint4 u;
            u.x = cvt_pk_bf16(a.x, a.y);
            u.y = cvt_pk_bf16(a.z, a.w);
            u.z = cvt_pk_bf16(bq.x, bq.y);
            u.w = cvt_pk_bf16(bq.z, bq.w);
            Af[m][kt] = __builtin_bit_cast(bf16x8, u);
        }
    // bias via float4 (o = wv*64 + m*16 + 4g4 + rr, rr 0..3 contiguous)
    float bias[4][4];
#pragma unroll
    for (int m = 0; m < 4; m++) {
        int o = wv * 64 + m * 16 + 4 * g4;
        float4 vb = *(const float4*)(bi + o);
        float4 vs = *(const float4*)(bs + o);
        bias[m][0] = vb.x + vs.x;
        bias[m][1] = vb.y + vs.y;
        bias[m][2] = vb.z + vs.z;
        bias[m][3] = vb.w + vs.w;
    }

    __syncthreads();

    f32x4 acc[4][4] = {};
#pragma unroll
    for (int nt = 0; nt < 4; nt++) {
        const int w = nt * 16 + m15;
        bf16x8 Bf[2];
#pragma unroll
        for (int kt = 0; kt < 2; kt++)
            Bf[kt] = __builtin_bit_cast(
                bf16x8, *(const uint4*)(XtB + ((w * 128 + kt * 64 + g4 * 16) ^
                                               ((w & 7) << 4))));
#pragma unroll
        for (int m = 0; m < 4; m++)
#pragma unroll
            for (int kt = 0; kt < 2; kt++)
                acc[m][nt] = MFMA(Af[m][kt], Bf[kt], acc[m][nt]);
    }

    __syncthreads();  // all Xt reads complete before sT overwrites its bytes

#pragma unroll
    for (int nt = 0; nt < 4; nt++) {
        const int w = nt * 16 + m15;
#pragma unroll
        for (int reg = 0; reg < 4; reg++)
#pragma unroll
            for (int mp = 0; mp < 2; mp++) {
                float v0 = SCL * (acc[2 * mp][nt][reg] + bias[2 * mp][reg]);
                float v1 =
                    SCL * (acc[2 * mp + 1][nt][reg] + bias[2 * mp + 1][reg]);
                sT[w * 129 + (4 * g4 + reg) * 8 + wv * 2 + mp] =
                    cvt_pk_bf16(v0, v1);
            }
    }
    __syncthreads();

    const size_t base = ((size_t)(b * 64 + r) * 66 + 1) * 128;
#pragma unroll
    for (int loop = 0; loop < 32; loop++) {
        int idx = loop * 256 + tid;
        int w = idx >> 7, cu = idx & 127;
        out_u32[base + idx] = sT[w * 129 + cu];
    }
    if (tid < 128) {
        u32 v = biasU32[tid];
        out_u32[base - 128 + tid] = v;
        out_u32[base + 8192 + tid] = v;
    }
}

// ---------------- K2: MFMA scan (v14, unchanged) ----------------
// 32 blocks x 512 threads (8 waves). LDS sM bytes: [0,8192) H par0;
// [8192,16384) H par1; [16384,32768) C par0/par1; ZH0@32768 ZC0@32896
// ZH1@40960 ZC1@41088. All addrs XOR 8192 per step; RHO chunk swizzle.
__global__ __launch_bounds__(512, 2) void scan_kernel(
    const u16* __restrict__ i2sP, const float* __restrict__ Wg,
    const float* __restrict__ Wc, const float* __restrict__ b_c2c,
    u16* __restrict__ hh16) {
    const int b = blockIdx.x;
    const int tid = threadIdx.x;
    const int lane = tid & 63;
    const int wv = __builtin_amdgcn_readfirstlane(tid >> 6);
    const int mh = wv >> 2, nq = wv & 3;
    const int m15 = lane & 15, g4 = lane >> 4;

    __shared__ __align__(16) u32 sM[10304];  // 41216 B
    char* smB = (char*)sM;

    for (int i = tid; i < 10304; i += 512) sM[i] = 0;

    // ---- VGPR-resident weights ----
    bf16x8 BW[4][4];
    float bcc[4];
#pragma unroll
    for (int nb = 0; nb < 4; nb++) {
        int o = 64 * nq + 16 * nb + m15;
        bcc[nb] = b_c2c[16 * nb + m15];
#pragma unroll
        for (int kt = 0; kt < 4; kt++) {
            const float* p = Wg + o * 128 + kt * 32 + g4 * 8;
            bf16x8 f;
#pragma unroll
            for (int j = 0; j < 8; j++) f[j] = (__bf16)p[j];
            BW[nb][kt] = f;
        }
    }
    bf16x8 BC[4][4];  // all 4 chan-tiles
#pragma unroll
    for (int nb = 0; nb < 4; nb++) {
        int o2 = 16 * nb + m15;
#pragma unroll
        for (int kt = 0; kt < 4; kt++) {
            const float* p = Wc + o2 * 128 + kt * 32 + g4 * 8;
            bf16x8 f;
#pragma unroll
            for (int j = 0; j < 8; j++) f[j] = (__bf16)p[j];
            BC[nb][kt] = f;
        }
    }

    // ---- precomputed addresses ----
    int aG[2][4], aC[4], wOff[2][4];
    u32 offW[2][4], offLo[2][4], offHi[2][4];
#pragma unroll
    for (int mi = 0; mi < 2; mi++) {
        int mt = 2 * mh + mi;
#pragma unroll
        for (int kt = 0; kt < 4; kt++) {
            int P = 16 * (m15 & 3) + 4 * mt + (m15 >> 2);
            int phys = P + (kt >> 1) - 1;
            int chunk = (kt & 1) * 4 + g4;
            aG[mi][kt] = (phys < 0) ? (32768 + chunk * 16)
                                    : (phys * 128 + ((chunk ^ RHO(phys)) * 16));
        }
        int p2 = 16 * mt + 4 * g4 + nq;
#pragma unroll
        for (int nb = 0; nb < 4; nb++) {
            int k = 16 * nb + m15;
            wOff[mi][nb] =
                8192 + p2 * 128 + (((k >> 3) ^ RHO(p2)) * 16) + (k & 7) * 2;
            int prerow = 16 * nb + 4 * mt + g4;  // nb doubles as gate idx r
            int bOffB = (prerow * 66 + 1) * 512 + 32 * m15 + 8 * nq;
            // walked u32 offset for the t+1 prefetch (clamped to w in [-1,64])
            offW[mi][nb] = (u32)(bOffB + ((1 - prerow) << 9));
            offLo[mi][nb] = (u32)(bOffB - 512);
            offHi[mi][nb] = (u32)(bOffB + 32768);
        }
    }
    // c2c: ROW-INTERLEAVED tile — even tile-rows = mt0, odd = mt1:
    //   crow(m15) = 16*(2mh + (m15&1)) + (m15&12) + nq
    // reg0 -> mi=0 row (16*mt0 + 4g4 + nq), reg1 -> mi=1 row.
#pragma unroll
    for (int kt = 0; kt < 4; kt++) {
        int crow = 16 * (2 * mh + (m15 & 1)) + (m15 & 12) + nq;
        int cphys = crow + (kt >> 1) - 1;
        int chunk = (kt & 1) * 4 + g4;
        aC[kt] = (cphys < 0)
                     ? (32896 + chunk * 16)
                     : (16384 + cphys * 128 + ((chunk ^ RHO(cphys)) * 16));
    }

    const char* i2sB = (const char*)i2sP + (size_t)b * (64 * 66 * 512);
    u16* hp16[2];
    int p2s[2];
#pragma unroll
    for (int mi = 0; mi < 2; mi++) {
        int p2 = 16 * (2 * mh + mi) + 4 * g4 + nq;
        p2s[mi] = p2;
        hp16[mi] = hh16 + (size_t)b * 262144 + p2 * 4032 + m15;
    }

    // ---- initial IV load (t=0) ----
    uint2 IV[2][4];
#pragma unroll
    for (int mi = 0; mi < 2; mi++) {
#pragma unroll
        for (int r = 0; r < 4; r++) {
            u32 o0 = min(max(offW[mi][r] - 512u, offLo[mi][r]), offHi[mi][r]);
            IV[mi][r] = *(const uint2*)(i2sB + o0);
        }
    }

    // ---- deferred-store carry state ----
    u16 hbKeep[2][4];
    u16* hpPrev[2];
    bool vstPrev[2];
#pragma unroll
    for (int mi = 0; mi < 2; mi++) {
        vstPrev[mi] = false;
        hpPrev[mi] = hp16[mi];
    }

    __syncthreads();

    for (int t = 0; t < NSTEP; t++) {
        // ---- deferred hh16 stores from step t-1 ----
#pragma unroll
        for (int mi = 0; mi < 2; mi++)
            if (vstPrev[mi]) {
#pragma unroll
                for (int nb = 0; nb < 4; nb++)
                    hpPrev[mi][nb * 16] = hbKeep[mi][nb];
            }

        // ---- c2c ONCE per step (row-interleaved tile serves both mi) ----
        f32x4 accC[4];
#pragma unroll
        for (int nb = 0; nb < 4; nb++) {
            accC[nb][0] = bcc[nb];
            accC[nb][1] = bcc[nb];
            accC[nb][2] = bcc[nb];
            accC[nb][3] = bcc[nb];
        }
        {
            bf16x8 Ac[4];
#pragma unroll
            for (int kt = 0; kt < 4; kt++)
                Ac[kt] = __builtin_bit_cast(bf16x8,
                                            *(const uint4*)(smB + aC[kt]));
#pragma unroll
            for (int nb = 0; nb < 4; nb++)
#pragma unroll
                for (int kt = 0; kt < 4; kt++)
                    accC[nb] = MFMA(Ac[kt], BC[nb][kt], accC[nb]);
        }

        // ---- per-mi: prefetch | acc-init+gates | LSTM+writes ----
#pragma unroll
        for (int mi = 0; mi < 2; mi++) {
            // prefetch IV for step t+1 (walked offsets, clamped)
            uint2 tn[4];
#pragma unroll
            for (int r = 0; r < 4; r++) {
                u32 oc = min(max(offW[mi][r], offLo[mi][r]), offHi[mi][r]);
                tn[r] = *(const uint2*)(i2sB + oc);
            }

            // gate MFMAs, acc initialized from current IV
            f32x4 accG[4];
#pragma unroll
            for (int r = 0; r < 4; r++) {
                accG[0][r] = lo2f(IV[mi][r].x);
                accG[1][r] = hi2f(IV[mi][r].x);
                accG[2][r] = lo2f(IV[mi][r].y);
                accG[3][r] = hi2f(IV[mi][r].y);
            }
            bf16x8 Ag[4];
#pragma unroll
            for (int kt = 0; kt < 4; kt++)
                Ag[kt] = __builtin_bit_cast(bf16x8,
                                            *(const uint4*)(smB + aG[mi][kt]));
#pragma unroll
            for (int nb = 0; nb < 4; nb++)
#pragma unroll
                for (int kt = 0; kt < 4; kt++)
                    accG[nb] = MFMA(Ag[kt], BW[nb][kt], accG[nb]);

            // LSTM update, rcp-fused; cc = accC[nb][mi] (static under unroll)
            int p2 = p2s[mi];
            bool vst = (u32)(t - p2) < 64u;
#pragma unroll
            for (int nb = 0; nb < 4; nb++) {
                float cc = accC[nb][mi];
                float pI = 1.f + __builtin_amdgcn_exp2f(accG[nb][0]);
                float pG = 1.f + __builtin_amdgcn_exp2f(accG[nb][1]);
                float pF = 1.f + __builtin_amdgcn_exp2f(accG[nb][2]);
                float pO = 1.f + __builtin_amdgcn_exp2f(accG[nb][3]);
                float u = pI * pG;
                float num = __builtin_fmaf(cc, u, pF);
                float c1 = num * __builtin_amdgcn_rcpf(pF * u);
                float E = __builtin_amdgcn_exp2f(c1 * T2L);
                float h1 =
                    (E - 1.f) * __builtin_amdgcn_rcpf((1.f + E) * pO);
                u32 hc = cvt_pk_bf16(h1, c1);  // lo=bf16(h1), hi=bf16(c1)
                *(u16*)(smB + wOff[mi][nb]) = (u16)hc;
                *(u16*)(smB + wOff[mi][nb] + 16384) = (u16)(hc >> 16);
                hbKeep[mi][nb] = (u16)hc;
            }
            vstPrev[mi] = vst;
            hpPrev[mi] = hp16[mi];
            hp16[mi] += 64;

            // rotate prefetched IV
#pragma unroll
            for (int r = 0; r < 4; r++) IV[mi][r] = tn[r];
        }

        __syncthreads();  // single barrier per step

        // ---- toggle parity; walk IV offsets ----
#pragma unroll
        for (int kt = 0; kt < 4; kt++) aC[kt] ^= 8192;
#pragma unroll
        for (int mi = 0; mi < 2; mi++) {
#pragma unroll
            for (int kt = 0; kt < 4; kt++) aG[mi][kt] ^= 8192;
#pragma unroll
            for (int nb = 0; nb < 4; nb++) {
                wOff[mi][nb] ^= 8192;
                offW[mi][nb] += 512;
            }
        }
    }

    // ---- epilogue: final deferred stores ----
#pragma unroll
    for (int mi = 0; mi < 2; mi++)
        if (vstPrev[mi]) {
#pragma unroll
            for (int nb = 0; nb < 4; nb++)
                hpPrev[mi][nb * 16] = hbKeep[mi][nb];
        }
}

// ---------------- K3: up-projection via MFMA (unchanged) ----------
__global__ __launch_bounds__(256, 4) void up_kernel(
    const u16* __restrict__ hh16, const u16* __restrict__ w_upB,
    const float* __restrict__ b_up, float* __restrict__ out) {
    const int bid = blockIdx.x;
    const int b = bid >> 6, r = bid & 63;
    const int lane = threadIdx.x & 63;
    const int wt = __builtin_amdgcn_readfirstlane(threadIdx.x >> 6);
    const int m15 = lane & 15, g4 = lane >> 4;

    const u16* hh_b = hh16 + (size_t)b * 262144;
    const int w = 16 * wt + m15;

    bf16x8 Bf[2];
#pragma unroll
    for (int kt = 0; kt < 2; kt++)
        Bf[kt] = __builtin_bit_cast(
            bf16x8,
            *(const uint4*)(hh_b + (r * 4096 + w * 64 + kt * 32 + g4 * 8)));

    // b_up via float4 (o2 = 16nt + 4g4 + rr, rr 0..3 contiguous)
    f32x4 bup[8];
#pragma unroll
    for (int nt = 0; nt < 8; nt++)
        bup[nt] =
            __builtin_bit_cast(f32x4, *(const float4*)(b_up + 16 * nt + 4 * g4));

    f32x4 acc[8] = {};
#pragma unroll
    for (int nt = 0; nt < 8; nt++) {
#pragma unroll
        for (int kt = 0; kt < 2; kt++) {
            bf16x8 Af = __builtin_bit_cast(
                bf16x8, *(const uint4*)(w_upB + ((16 * nt + m15) * 64 +
                                                 kt * 32 + g4 * 8)));
            acc[nt] = MFMA(Af, Bf[kt], acc[nt]);
        }
    }
    float* outb = out + (size_t)b * 524288;
#pragma unroll
    for (int nt = 0; nt < 8; nt++) {
#pragma unroll
        for (int rr = 0; rr < 4; rr++) {
            int o2 = 16 * nt + 4 * g4 + rr;
            outb[(size_t)o2 * 4096 + r * 64 + w] = acc[nt][rr] + bup[nt][rr];
        }
    }
}

extern "C" void kernel_launch(void* const* d_in, const int* in_sizes, int n_in,
                              void* d_out, int out_size, void* d_ws,
                              size_t ws_size, hipStream_t stream) {
    (void)in_sizes; (void)n_in; (void)out_size; (void)ws_size;
    const float* inputs = (const float*)d_in[0];
    const float* w_i2s = (const float*)d_in[1];
    const float* b_i2s = (const float*)d_in[2];
    const float* w_s2s = (const float*)d_in[3];
    const float* b_s2s = (const float*)d_in[4];
    const float* w_c2c = (const float*)d_in[5];
    const float* b_c2c = (const float*)d_in[6];
    const float* w_up = (const float*)d_in[7];
    const float* b_up = (const float*)d_in[8];
    float* out = (float*)d_out;
    char* ws = (char*)d_ws;

    // workspace layout (bytes):
    // [0, 69206016)             i2sP u16 (32*64*66*256, bias-padded slots)
    // [69206016, 85983232)      hh16 u16 (32*64*64*64)
    // [85983232, 86114304)      Wg fp32 (256*128, scaled -log2e)
    // [86114304, 86147072)      Wc fp32 (64*128)
    // [86147072, 86147584)      biasRow u16[256]
    // [86147584, 86163968)      w_upB u16 (128*64)
    u16* i2sP = (u16*)ws;
    u16* hh16 = (u16*)(ws + 69206016);
    float* Wg = (float*)(ws + 85983232);
    float* Wc = (float*)(ws + 86114304);
    u16* biasRow = (u16*)(ws + 86147072);
    u16* w_upB = (u16*)(ws + 86147584);

    hipLaunchKernelGGL(repack_w, dim3(193), dim3(256), 0, stream, w_s2s, w_c2c,
                       b_i2s, b_s2s, w_up, Wg, Wc, biasRow, w_upB);
    hipLaunchKernelGGL(i2s_kernel, dim3(2048), dim3(256), 0, stream, inputs,
                       w_i2s, b_i2s, b_s2s, (const u32*)biasRow, (u32*)i2sP);
    hipLaunchKernelGGL(scan_kernel, dim3(32), dim3(512), 0, stream, i2sP, Wg,
                       Wc, b_c2c, hh16);
    hipLaunchKernelGGL(up_kernel, dim3(2048), dim3(256), 0, stream, hh16,
                       w_upB, b_up, out);
}